// Round 11
// baseline (847.557 us; speedup 1.0000x reference)
//
#include <hip/hip_runtime.h>
#include <hip/hip_bf16.h>

typedef unsigned short u16;
typedef unsigned int u32;
typedef __attribute__((ext_vector_type(8))) short short8;
typedef __attribute__((ext_vector_type(4))) float floatx4;

#define BB 32
#define CC 512
#define LL 16
#define DD 256
#define HH 1024
#define PP 16
#define NLAY 4

__device__ __forceinline__ float bf2f(u16 u) {
  u32 x = ((u32)u) << 16; float f; __builtin_memcpy(&f, &x, 4); return f;
}
__device__ __forceinline__ u16 f2bf(float f) {
  __hip_bfloat16 h = __float2bfloat16(f);
  u16 r; __builtin_memcpy(&r, &h, 2); return r;
}
__device__ __forceinline__ void gload_lds16(const u16* g, u16* l) {
  __builtin_amdgcn_global_load_lds(
      (const __attribute__((address_space(1))) void*)g,
      (__attribute__((address_space(3))) void*)l, 16, 0, 0);
}

// ---------------- fp32 -> bf16 conversion: 8 weight tensors + 4 embedding tables ----------------
__global__ __launch_bounds__(256) void cvt_kernel(
    const float* __restrict__ s0, const float* __restrict__ s1,
    const float* __restrict__ s2, const float* __restrict__ s3,
    const float* __restrict__ s4, const float* __restrict__ s5,
    const float* __restrict__ s6, const float* __restrict__ s7,
    const float* __restrict__ s8, const float* __restrict__ s9,
    const float* __restrict__ s10, const float* __restrict__ s11,
    u16* __restrict__ dst)
{
  const float* srcs[12] = {s0, s1, s2, s3, s4, s5, s6, s7, s8, s9, s10, s11};
  const int pfx[12] = {786432, 1048576, 2097152, 3145728, 3407872, 6553600, 7602176,
                       7618560, 7749888, 7750656, 7754752, 7885824};
  int e = (blockIdx.x * 256 + threadIdx.x) * 4;
  int seg = 0;
  while (e >= pfx[seg]) seg++;
  int start = seg ? pfx[seg - 1] : 0;
  float4 f = *(const float4*)(srcs[seg] + (e - start));
  u16 o[4] = {f2bf(f.x), f2bf(f.y), f2bf(f.z), f2bf(f.w)};
  *(uint2*)(dst + e) = *(const uint2*)o;
}

// ---------------- th_w [1024,256] fp32 -> bf16 transposed [256,1024] (K-major for fold GEMM) ---
__global__ __launch_bounds__(256) void thwT_kernel(
    const float* __restrict__ thw, u16* __restrict__ out)
{
  __shared__ float tile[32][33];
  int bx = blockIdx.x & 7, by = blockIdx.x >> 3;   // bx: d-tile (8), by: h-tile (32)
  int tx = threadIdx.x & 31, ty = threadIdx.x >> 5;
  #pragma unroll
  for (int i = 0; i < 4; ++i) {
    int h = by * 32 + ty + i * 8, d = bx * 32 + tx;
    tile[ty + i * 8][tx] = thw[h * 256 + d];
  }
  __syncthreads();
  #pragma unroll
  for (int i = 0; i < 4; ++i) {
    int d = bx * 32 + ty + i * 8, h = by * 32 + tx;
    out[d * 1024 + h] = f2bf(tile[tx][ty + i * 8]);
  }
}

// ---------------- bf16 transpose [1024,256] -> [256,1024] (Wck^T for Qc fold) ----------------
__global__ __launch_bounds__(256) void bT_kernel(
    const u16* __restrict__ in, u16* __restrict__ out)
{
  __shared__ u16 tile[32][33];
  int bx = blockIdx.x & 7, by = blockIdx.x >> 3;   // bx: c-tile (8), by: hd-tile (32)
  int tx = threadIdx.x & 31, ty = threadIdx.x >> 5;
  #pragma unroll
  for (int i = 0; i < 4; ++i) {
    int hd = by * 32 + ty + i * 8, c = bx * 32 + tx;
    tile[ty + i * 8][tx] = in[hd * 256 + c];
  }
  __syncthreads();
  #pragma unroll
  for (int i = 0; i < 4; ++i) {
    int c = bx * 32 + ty + i * 8, hd = by * 32 + tx;
    out[c * 1024 + hd] = tile[tx][ty + i * 8];
  }
}

// ---------------- Qc fold: Qc[h][q][c] = sum_d qh[q, h*128+d] * Wck[h*128+d, c] ------------
__global__ __launch_bounds__(256) void qc_kernel(
    const u16* __restrict__ qh, const u16* __restrict__ wckT, u16* __restrict__ qcg)
{
  int h = blockIdx.x;
  int t = threadIdx.x, lane = t & 63, w = t >> 6;
  int mrow = lane & 15, quad = lane >> 4;
  const floatx4 zf = (floatx4){0.f, 0.f, 0.f, 0.f};
  floatx4 acc[4] = {zf, zf, zf, zf};
  #pragma unroll
  for (int kk = 0; kk < 4; ++kk) {
    short8 af = *(const short8*)(qh + (size_t)mrow * 1024 + h * 128 + kk * 32 + quad * 8);
    #pragma unroll
    for (int ct = 0; ct < 4; ++ct) {
      int c = w * 64 + ct * 16 + mrow;
      short8 bf = *(const short8*)(wckT + (size_t)c * 1024 + h * 128 + kk * 32 + quad * 8);
      acc[ct] = __builtin_amdgcn_mfma_f32_16x16x32_bf16(af, bf, acc[ct], 0, 0, 0);
    }
  }
  #pragma unroll
  for (int ct = 0; ct < 4; ++ct)
    #pragma unroll
    for (int r = 0; r < 4; ++r)
      qcg[((size_t)h * 16 + quad * 4 + r) * 256 + w * 64 + ct * 16 + mrow] = f2bf(acc[ct][r]);
}

// ---------------- folded KV bias: bkv[n] = Wkv[n,:]·th_b + pa_in_b[1024+n], one wave/row ------
__global__ __launch_bounds__(256) void biasfold_kernel(
    const u16* __restrict__ Wkv, const float* __restrict__ thb,
    const float* __restrict__ paib, float* __restrict__ out)
{
  int wv = threadIdx.x >> 6, lane = threadIdx.x & 63;
  int n = blockIdx.x * 4 + wv;
  const u16* wr = Wkv + (size_t)n * 1024;
  float s = 0.f;
  #pragma unroll
  for (int i = 0; i < 16; ++i) {
    int h = i * 64 + lane;
    s += bf2f(wr[h]) * thb[h];
  }
  #pragma unroll
  for (int off = 32; off; off >>= 1) s += __shfl_xor(s, off);
  if (!lane) out[n] = s + paib[1024 + n];
}

// ---------------- split-K reduce: sum nz f32 partials + bias/res, write f32 or bf16 ----------
__global__ __launch_bounds__(256) void redk_kernel(
    const float* __restrict__ part, const float* __restrict__ bias,
    const float* __restrict__ res, float* __restrict__ outf, u16* __restrict__ outb,
    int N, int nz, int total, int flags)   // flags&4: res row index is (row&15)
{
  int idx = (blockIdx.x * 256 + threadIdx.x) * 4;
  if (idx >= total) return;
  float4 a = *(const float4*)(part + idx);
  for (int z = 1; z < nz; ++z) {
    float4 b = *(const float4*)(part + (size_t)z * total + idx);
    a.x += b.x; a.y += b.y; a.z += b.z; a.w += b.w;
  }
  int row = idx / N, col = idx - row * N;   // 4 consecutive cols, same row (N % 4 == 0)
  float v4[4] = {a.x, a.y, a.z, a.w};
  #pragma unroll
  for (int i = 0; i < 4; ++i) {
    if (bias) v4[i] += bias[col + i];
    if (res) v4[i] += res[(size_t)((flags & 4) ? (row & 15) : row) * N + col + i];
  }
  if (outf) {
    *(float4*)(outf + idx) = *(const float4*)v4;
  } else {
    u16 o[4] = {f2bf(v4[0]), f2bf(v4[1]), f2bf(v4[2]), f2bf(v4[3])};
    *(uint2*)(outb + idx) = *(const uint2*)o;
  }
}

// ---------------- embed + masked mean pool (bf16 tables, 2 clauses/block, u32 loads) --------
__global__ __launch_bounds__(256) void embed_kernel(
    const int* __restrict__ vi, const int* __restrict__ si, const int* __restrict__ mk,
    const u16* __restrict__ veb, const u16* __restrict__ seb,
    const u16* __restrict__ lpeb, const u16* __restrict__ cpeb,
    u16* __restrict__ xb)
{
  int t = threadIdx.x;
  int bc = blockIdx.x * 2 + (t >> 7);
  int c = bc & (CC - 1);
  int dl = (t & 127) * 2;
  int base = bc * LL;
  float a0 = 0.f, a1 = 0.f; int cnt = 0;
  #pragma unroll
  for (int l = 0; l < LL; ++l) {
    if (mk[base + l]) {
      int v = vi[base + l], s = si[base + l];
      u32 vv = *(const u32*)&veb[v * DD + dl];
      u32 sv = *(const u32*)&seb[s * DD + dl];
      u32 lv = *(const u32*)&lpeb[l * DD + dl];
      a0 += bf2f((u16)vv) + bf2f((u16)sv) + bf2f((u16)lv);
      a1 += bf2f((u16)(vv >> 16)) + bf2f((u16)(sv >> 16)) + bf2f((u16)(lv >> 16));
      cnt++;
    }
  }
  u32 cv = *(const u32*)&cpeb[c * DD + dl];
  float inv = 1.f / (float)cnt;
  u32 pk = (u32)f2bf(a0 * inv + bf2f((u16)cv)) | ((u32)f2bf(a1 * inv + bf2f((u16)(cv >> 16))) << 16);
  *(u32*)&xb[(size_t)bc * DD + dl] = pk;
}

// ---------------- wide-N GEMM 32 rows (v2 warp mapping; QKV and attn-out-LN call-sites) ----
template<int NC, bool GELU, bool LN, bool DLN>
__global__ __launch_bounds__(256) void gwide_kernel(
    const u16* __restrict__ A, const u16* __restrict__ W, const float* __restrict__ bias,
    const u16* __restrict__ resb, const float* __restrict__ gam, const float* __restrict__ bet,
    const float* __restrict__ gam2, const float* __restrict__ bet2,
    u16* __restrict__ out, int N, int K)
{
  constexpr int NT = NC / 32;    // staging tile count
  constexpr int NT4 = NC / 64;   // col tiles per warp
  __shared__ __align__(16) u16 As[32 * 64];
  __shared__ __align__(16) u16 Ws[NC * 64];
  __shared__ float sred[32][4][2];
  __shared__ float sred2[32][4][2];
  int t = threadIdx.x, lane = t & 63, w = t >> 6;
  int mrow = lane & 15, quad = lane >> 4;
  int bn0 = blockIdx.x * NC, bm0 = blockIdx.y * 32;

  int rA = t >> 3, gcA = (t & 7) ^ (rA & 7);
  const u16* gAp = A + (size_t)(bm0 + rA) * K + gcA * 8;
  u16* lAp = As + (w * 64) * 8;
  const u16* gW0 = W + (size_t)(bn0 + rA) * K + gcA * 8;
  u16* lW0 = Ws + (w * 64) * 8;

  floatx4 acc[2][NT4];
  #pragma unroll
  for (int mi = 0; mi < 2; ++mi)
    #pragma unroll
    for (int nt = 0; nt < NT4; ++nt) acc[mi][nt] = (floatx4){0.f, 0.f, 0.f, 0.f};

  for (int k0 = 0; k0 < K; k0 += 64) {
    __syncthreads();
    gload_lds16(gAp, lAp); gAp += 64;
    #pragma unroll
    for (int i = 0; i < NT; ++i)
      gload_lds16(gW0 + (size_t)i * 32 * K, lW0 + i * 2048);
    gW0 += 64;
    __syncthreads();
    #pragma unroll
    for (int ks = 0; ks < 2; ++ks) {
      int sw = ((ks * 4 + quad) ^ (mrow & 7)) * 8;
      short8 af0 = *(const short8*)&As[mrow * 64 + sw];
      short8 af1 = *(const short8*)&As[(16 + mrow) * 64 + sw];
      #pragma unroll
      for (int nt = 0; nt < NT4; ++nt) {
        int rw = w * (NC / 4) + nt * 16 + mrow;
        short8 bf = *(const short8*)&Ws[rw * 64 + sw];
        acc[0][nt] = __builtin_amdgcn_mfma_f32_16x16x32_bf16(af0, bf, acc[0][nt], 0, 0, 0);
        acc[1][nt] = __builtin_amdgcn_mfma_f32_16x16x32_bf16(af1, bf, acc[1][nt], 0, 0, 0);
      }
    }
  }

  if constexpr (LN) {
    float val[2][NT4][4];
    float bv[NT4];
    #pragma unroll
    for (int nt = 0; nt < NT4; ++nt) bv[nt] = bias[w * 64 + nt * 16 + mrow];
    #pragma unroll
    for (int mi = 0; mi < 2; ++mi) {
      #pragma unroll
      for (int r = 0; r < 4; ++r) {
        int gm = bm0 + mi * 16 + quad * 4 + r;
        float sr = 0.f, s2r = 0.f;
        #pragma unroll
        for (int nt = 0; nt < NT4; ++nt) {
          int gn = w * 64 + nt * 16 + mrow;
          float v = acc[mi][nt][r] + bv[nt] + bf2f(resb[(size_t)gm * 256 + gn]);
          val[mi][nt][r] = v; sr += v; s2r += v * v;
        }
        sr += __shfl_xor(sr, 1); s2r += __shfl_xor(s2r, 1);
        sr += __shfl_xor(sr, 2); s2r += __shfl_xor(s2r, 2);
        sr += __shfl_xor(sr, 4); s2r += __shfl_xor(s2r, 4);
        sr += __shfl_xor(sr, 8); s2r += __shfl_xor(s2r, 8);
        if (mrow == 0) { sred[mi * 16 + quad * 4 + r][w][0] = sr; sred[mi * 16 + quad * 4 + r][w][1] = s2r; }
      }
    }
    __syncthreads();
    #pragma unroll
    for (int mi = 0; mi < 2; ++mi) {
      #pragma unroll
      for (int r = 0; r < 4; ++r) {
        int lrow = mi * 16 + quad * 4 + r;
        float S  = sred[lrow][0][0] + sred[lrow][1][0] + sred[lrow][2][0] + sred[lrow][3][0];
        float S2 = sred[lrow][0][1] + sred[lrow][1][1] + sred[lrow][2][1] + sred[lrow][3][1];
        float mean = S * (1.f / 256.f);
        float var = S2 * (1.f / 256.f) - mean * mean;
        float inv = rsqrtf(var + 1e-5f);
        float sr2 = 0.f, s2r2 = 0.f;
        #pragma unroll
        for (int nt = 0; nt < NT4; ++nt) {
          int gn = w * 64 + nt * 16 + mrow;
          float y = (val[mi][nt][r] - mean) * inv * gam[gn] + bet[gn];
          val[mi][nt][r] = y;
          if constexpr (DLN) { sr2 += y; s2r2 += y * y; }
          else out[(size_t)(bm0 + lrow) * 256 + gn] = f2bf(y);
        }
        if constexpr (DLN) {
          sr2 += __shfl_xor(sr2, 1); s2r2 += __shfl_xor(s2r2, 1);
          sr2 += __shfl_xor(sr2, 2); s2r2 += __shfl_xor(s2r2, 2);
          sr2 += __shfl_xor(sr2, 4); s2r2 += __shfl_xor(s2r2, 4);
          sr2 += __shfl_xor(sr2, 8); s2r2 += __shfl_xor(s2r2, 8);
          if (mrow == 0) { sred2[lrow][w][0] = sr2; sred2[lrow][w][1] = s2r2; }
        }
      }
    }
    if constexpr (DLN) {
      __syncthreads();
      #pragma unroll
      for (int mi = 0; mi < 2; ++mi) {
        #pragma unroll
        for (int r = 0; r < 4; ++r) {
          int lrow = mi * 16 + quad * 4 + r;
          float S  = sred2[lrow][0][0] + sred2[lrow][1][0] + sred2[lrow][2][0] + sred2[lrow][3][0];
          float S2 = sred2[lrow][0][1] + sred2[lrow][1][1] + sred2[lrow][2][1] + sred2[lrow][3][1];
          float mean = S * (1.f / 256.f);
          float var = S2 * (1.f / 256.f) - mean * mean;
          float inv = rsqrtf(var + 1e-5f);
          #pragma unroll
          for (int nt = 0; nt < NT4; ++nt) {
            int gn = w * 64 + nt * 16 + mrow;
            float z = (val[mi][nt][r] - mean) * inv * gam2[gn] + bet2[gn];
            out[(size_t)(bm0 + lrow) * 256 + gn] = f2bf(z);
          }
        }
      }
    }
  } else {
    #pragma unroll
    for (int nt = 0; nt < NT4; ++nt) {
      int gn = bn0 + w * (NC / 4) + nt * 16 + mrow;
      float bv = bias[gn];
      #pragma unroll
      for (int mi = 0; mi < 2; ++mi) {
        #pragma unroll
        for (int r = 0; r < 4; ++r) {
          int gm = bm0 + mi * 16 + quad * 4 + r;
          float v = acc[mi][nt][r] + bv;
          if (GELU) v = 0.5f * v * (1.f + erff(v * 0.70710678118654752f));
          out[(size_t)gm * N + gn] = f2bf(v);
        }
      }
    }
  }
}

// ---------------- fused FFN v2: 64 rows/block (grid 256 = 1/CU), x staged ONCE, Ws stage
//  amortized over 2x rows (per-CU staged bytes halved). Warp = 32-row-half x 128-col-half.
//  LDS 96KB: Xs 32 + Ws 32 + Hs 32. As-format invariant: off = row*64+((k>>3)^(row&7))*8+(k&7).
template<bool DLN>
__global__ __launch_bounds__(256) void ffu_kernel(
    const u16* __restrict__ A, const u16* __restrict__ W1, const float* __restrict__ b1,
    const u16* __restrict__ W2, const float* __restrict__ b2,
    const u16* __restrict__ resb,
    const float* __restrict__ gam, const float* __restrict__ bet,
    const float* __restrict__ gam2, const float* __restrict__ bet2,
    u16* __restrict__ out)
{
  __shared__ __align__(16) u16 Xs[4 * 4096];   // 32 KB: x tile [64r][256k], 4 k-tiles As-format
  __shared__ __align__(16) u16 Ws[8 * 2048];   // 32 KB: W1/W2 staging (256 out-cols x 64 k)
  __shared__ __align__(16) u16 Hs[4 * 4096];   // 32 KB: gelu(h) quarter [64r][256k] As-format
  int t = threadIdx.x, lane = t & 63, w = t >> 6;
  int mrow = lane & 15, quad = lane >> 4;
  int rh = w & 1, ch = w >> 1;               // row-half (32), col-half (128)
  int bm0 = blockIdx.x * 64;
  int rA = t >> 3, gcA = (t & 7) ^ (rA & 7);

  // stage full x tile once: 4 k-tiles x 2 iters (512 x 16B each k-tile)
  #pragma unroll
  for (int kt = 0; kt < 4; ++kt) {
    #pragma unroll
    for (int i = 0; i < 2; ++i) {
      int idx = i * 256 + t;
      int r = idx >> 3, gc = (idx & 7) ^ (r & 7);
      gload_lds16(A + (size_t)(bm0 + r) * 256 + kt * 64 + gc * 8,
                  Xs + kt * 4096 + (i * 256 + w * 64) * 8);
    }
  }

  floatx4 yacc[2][8];
  #pragma unroll
  for (int mi = 0; mi < 2; ++mi)
    #pragma unroll
    for (int nt = 0; nt < 8; ++nt) yacc[mi][nt] = (floatx4){0.f, 0.f, 0.f, 0.f};

  for (int nq = 0; nq < 4; ++nq) {
    floatx4 hacc[2][8];
    #pragma unroll
    for (int mi = 0; mi < 2; ++mi)
      #pragma unroll
      for (int nt = 0; nt < 8; ++nt) hacc[mi][nt] = (floatx4){0.f, 0.f, 0.f, 0.f};
    // FF1: h[:, nq*256 .. +256) = x @ W1_q^T  (K = 256, 4 k-steps; x already in Xs)
    for (int kt = 0; kt < 4; ++kt) {
      __syncthreads();   // WAR on Ws
      #pragma unroll
      for (int i = 0; i < 8; ++i)
        gload_lds16(W1 + (size_t)(nq * 256 + i * 32 + rA) * 256 + kt * 64 + gcA * 8,
                    Ws + i * 2048 + (w * 64) * 8);
      __syncthreads();   // drains vmcnt (incl. Xs on first pass)
      #pragma unroll
      for (int ks = 0; ks < 2; ++ks) {
        int sw = ((ks * 4 + quad) ^ (mrow & 7)) * 8;
        short8 af0 = *(const short8*)&Xs[kt * 4096 + (rh * 32 + mrow) * 64 + sw];
        short8 af1 = *(const short8*)&Xs[kt * 4096 + (rh * 32 + 16 + mrow) * 64 + sw];
        #pragma unroll
        for (int nt = 0; nt < 8; ++nt) {
          short8 bf = *(const short8*)&Ws[(ch * 128 + nt * 16 + mrow) * 64 + sw];
          hacc[0][nt] = __builtin_amdgcn_mfma_f32_16x16x32_bf16(af0, bf, hacc[0][nt], 0, 0, 0);
          hacc[1][nt] = __builtin_amdgcn_mfma_f32_16x16x32_bf16(af1, bf, hacc[1][nt], 0, 0, 0);
        }
      }
    }
    // gelu + bias1, write quarter into Hs (As-format): cc = ch*128 + nt*16 + mrow
    {
      float bv1[8];
      #pragma unroll
      for (int nt = 0; nt < 8; ++nt) bv1[nt] = b1[nq * 256 + ch * 128 + nt * 16 + mrow];
      #pragma unroll
      for (int mi = 0; mi < 2; ++mi) {
        #pragma unroll
        for (int nt = 0; nt < 8; ++nt) {
          int kt2 = ch * 2 + (nt >> 2);
          int g = (nt & 3) * 2 + (mrow >> 3);
          #pragma unroll
          for (int r = 0; r < 4; ++r) {
            int row = rh * 32 + mi * 16 + quad * 4 + r;
            float v = hacc[mi][nt][r] + bv1[nt];
            v = 0.5f * v * (1.f + erff(v * 0.70710678118654752f));
            Hs[kt2 * 4096 + row * 64 + (g ^ (row & 7)) * 8 + (mrow & 7)] = f2bf(v);
          }
        }
      }
    }
    // FF2 partial: yacc += gelu_h_q @ W2[:, nq*256 .. +256)^T  (4 k-steps over Hs)
    for (int kt2 = 0; kt2 < 4; ++kt2) {
      __syncthreads();   // Hs RAW (lgkm) + Ws WAR
      #pragma unroll
      for (int i = 0; i < 8; ++i)
        gload_lds16(W2 + (size_t)(i * 32 + rA) * 1024 + nq * 256 + kt2 * 64 + gcA * 8,
                    Ws + i * 2048 + (w * 64) * 8);
      __syncthreads();
      #pragma unroll
      for (int ks = 0; ks < 2; ++ks) {
        int sw = ((ks * 4 + quad) ^ (mrow & 7)) * 8;
        short8 af0 = *(const short8*)&Hs[kt2 * 4096 + (rh * 32 + mrow) * 64 + sw];
        short8 af1 = *(const short8*)&Hs[kt2 * 4096 + (rh * 32 + 16 + mrow) * 64 + sw];
        #pragma unroll
        for (int nt = 0; nt < 8; ++nt) {
          short8 bf = *(const short8*)&Ws[(ch * 128 + nt * 16 + mrow) * 64 + sw];
          yacc[0][nt] = __builtin_amdgcn_mfma_f32_16x16x32_bf16(af0, bf, yacc[0][nt], 0, 0, 0);
          yacc[1][nt] = __builtin_amdgcn_mfma_f32_16x16x32_bf16(af1, bf, yacc[1][nt], 0, 0, 0);
        }
      }
    }
  }
  // epilogue: residual + LN (+DLN). sred aliased into Xs (dead; guarded by barrier).
  __syncthreads();
  float* sred  = (float*)Xs;        // [64 rows][2 ch][2]
  float* sred2 = sred + 256;
  float val[2][8][4];
  float bv[8];
  #pragma unroll
  for (int nt = 0; nt < 8; ++nt) bv[nt] = b2[ch * 128 + nt * 16 + mrow];
  #pragma unroll
  for (int mi = 0; mi < 2; ++mi) {
    #pragma unroll
    for (int r = 0; r < 4; ++r) {
      int row = rh * 32 + mi * 16 + quad * 4 + r;
      int gm = bm0 + row;
      float sr = 0.f, s2r = 0.f;
      #pragma unroll
      for (int nt = 0; nt < 8; ++nt) {
        int gn = ch * 128 + nt * 16 + mrow;
        float v = yacc[mi][nt][r] + bv[nt] + bf2f(resb[(size_t)gm * 256 + gn]);
        val[mi][nt][r] = v; sr += v; s2r += v * v;
      }
      sr += __shfl_xor(sr, 1); s2r += __shfl_xor(s2r, 1);
      sr += __shfl_xor(sr, 2); s2r += __shfl_xor(s2r, 2);
      sr += __shfl_xor(sr, 4); s2r += __shfl_xor(s2r, 4);
      sr += __shfl_xor(sr, 8); s2r += __shfl_xor(s2r, 8);
      if (mrow == 0) { sred[row * 4 + ch * 2 + 0] = sr; sred[row * 4 + ch * 2 + 1] = s2r; }
    }
  }
  __syncthreads();
  #pragma unroll
  for (int mi = 0; mi < 2; ++mi) {
    #pragma unroll
    for (int r = 0; r < 4; ++r) {
      int row = rh * 32 + mi * 16 + quad * 4 + r;
      float S  = sred[row * 4 + 0] + sred[row * 4 + 2];
      float S2 = sred[row * 4 + 1] + sred[row * 4 + 3];
      float mean = S * (1.f / 256.f);
      float var = S2 * (1.f / 256.f) - mean * mean;
      float inv = rsqrtf(var + 1e-5f);
      float sr2 = 0.f, s2r2 = 0.f;
      #pragma unroll
      for (int nt = 0; nt < 8; ++nt) {
        int gn = ch * 128 + nt * 16 + mrow;
        float y = (val[mi][nt][r] - mean) * inv * gam[gn] + bet[gn];
        val[mi][nt][r] = y;
        if constexpr (DLN) { sr2 += y; s2r2 += y * y; }
        else out[(size_t)(bm0 + row) * 256 + gn] = f2bf(y);
      }
      if constexpr (DLN) {
        sr2 += __shfl_xor(sr2, 1); s2r2 += __shfl_xor(s2r2, 1);
        sr2 += __shfl_xor(sr2, 2); s2r2 += __shfl_xor(s2r2, 2);
        sr2 += __shfl_xor(sr2, 4); s2r2 += __shfl_xor(s2r2, 4);
        sr2 += __shfl_xor(sr2, 8); s2r2 += __shfl_xor(s2r2, 8);
        if (mrow == 0) { sred2[row * 4 + ch * 2 + 0] = sr2; sred2[row * 4 + ch * 2 + 1] = s2r2; }
      }
    }
  }
  if constexpr (DLN) {
    __syncthreads();
    #pragma unroll
    for (int mi = 0; mi < 2; ++mi) {
      #pragma unroll
      for (int r = 0; r < 4; ++r) {
        int row = rh * 32 + mi * 16 + quad * 4 + r;
        float S  = sred2[row * 4 + 0] + sred2[row * 4 + 2];
        float S2 = sred2[row * 4 + 1] + sred2[row * 4 + 3];
        float mean = S * (1.f / 256.f);
        float var = S2 * (1.f / 256.f) - mean * mean;
        float inv = rsqrtf(var + 1e-5f);
        #pragma unroll
        for (int nt = 0; nt < 8; ++nt) {
          int gn = ch * 128 + nt * 16 + mrow;
          float z = (val[mi][nt][r] - mean) * inv * gam2[gn] + bet2[gn];
          out[(size_t)(bm0 + row) * 256 + gn] = f2bf(z);
        }
      }
    }
  }
}

// ---- MFMA GEMM 128x128, optional split-K via blockIdx.z (z>1: raw f32 partials out) -------
//      flags: 1=gelu, 2=f32 out, 4=pq-broadcast res
__global__ __launch_bounds__(256) void gemm128_kernel(
    const u16* __restrict__ A, const u16* __restrict__ W, const float* __restrict__ bias,
    const float* __restrict__ res, void* __restrict__ out,
    int M, int N, int K, int flags)
{
  __shared__ __align__(16) u16 As[128 * 64];
  __shared__ __align__(16) u16 Bs[128 * 64];
  int t = threadIdx.x;
  int lane = t & 63, w = t >> 6;
  int wm = w & 1, wn = w >> 1;
  int bn0 = blockIdx.x * 128, bm0 = blockIdx.y * 128;
  int mrow = lane & 15, quad = lane >> 4;
  int z = blockIdx.z, NZ = gridDim.z;
  int Kc = K / NZ, kbase = z * Kc;

  const u16* gA[4]; const u16* gB[4];
  u16* lA[4]; u16* lB[4];
  #pragma unroll
  for (int it = 0; it < 4; ++it) {
    int c = w * 256 + it * 64 + lane;
    int r = c >> 3;
    int gc = (c & 7) ^ (r & 7);
    gA[it] = A + (size_t)(bm0 + r) * K + kbase + gc * 8;
    gB[it] = W + (size_t)(bn0 + r) * K + kbase + gc * 8;
    lA[it] = As + (w * 256 + it * 64) * 8;
    lB[it] = Bs + (w * 256 + it * 64) * 8;
  }
  floatx4 acc[4][4];
  #pragma unroll
  for (int i = 0; i < 4; ++i)
    #pragma unroll
    for (int j = 0; j < 4; ++j)
      acc[i][j] = (floatx4){0.f, 0.f, 0.f, 0.f};
  int sw0 = ((0 * 4 + quad) ^ (mrow & 7)) * 8;
  int sw1 = ((1 * 4 + quad) ^ (mrow & 7)) * 8;

  for (int k0 = 0; k0 < Kc; k0 += 64) {
    __syncthreads();
    #pragma unroll
    for (int it = 0; it < 4; ++it) { gload_lds16(gA[it], lA[it]); gA[it] += 64; }
    #pragma unroll
    for (int it = 0; it < 4; ++it) { gload_lds16(gB[it], lB[it]); gB[it] += 64; }
    __syncthreads();
    #pragma unroll
    for (int ks = 0; ks < 2; ++ks) {
      int sw = ks ? sw1 : sw0;
      short8 af[4], bfr[4];
      #pragma unroll
      for (int mi = 0; mi < 4; ++mi)
        af[mi] = *(const short8*)&As[(wm * 64 + mi * 16 + mrow) * 64 + sw];
      #pragma unroll
      for (int nj = 0; nj < 4; ++nj)
        bfr[nj] = *(const short8*)&Bs[(wn * 64 + nj * 16 + mrow) * 64 + sw];
      #pragma unroll
      for (int mi = 0; mi < 4; ++mi)
        #pragma unroll
        for (int nj = 0; nj < 4; ++nj)
          acc[mi][nj] = __builtin_amdgcn_mfma_f32_16x16x32_bf16(af[mi], bfr[nj], acc[mi][nj], 0, 0, 0);
    }
  }
  if (NZ > 1) {
    // raw partial accumulators -> f32 buffer at out + z*M*N
    float* po = (float*)out + (size_t)z * M * N;
    #pragma unroll
    for (int nj = 0; nj < 4; ++nj) {
      int gn = bn0 + wn * 64 + nj * 16 + mrow;
      #pragma unroll
      for (int mi = 0; mi < 4; ++mi)
        #pragma unroll
        for (int r = 0; r < 4; ++r) {
          int gm = bm0 + wm * 64 + mi * 16 + quad * 4 + r;
          po[(size_t)gm * N + gn] = acc[mi][nj][r];
        }
    }
    return;
  }
  bool do_gelu = (flags & 1) != 0, of32 = (flags & 2) != 0;
  #pragma unroll
  for (int nj = 0; nj < 4; ++nj) {
    int gn = bn0 + wn * 64 + nj * 16 + mrow;
    float bv = bias ? bias[gn] : 0.f;
    #pragma unroll
    for (int mi = 0; mi < 4; ++mi) {
      #pragma unroll
      for (int r = 0; r < 4; ++r) {
        int gm = bm0 + wm * 64 + mi * 16 + quad * 4 + r;
        float v = acc[mi][nj][r] + bv;
        if (do_gelu) v = 0.5f * v * (1.f + erff(v * 0.70710678118654752f));
        if (flags & 4) v += res[(size_t)(gm & 15) * N + gn];
        else if (res) v += res[(size_t)gm * N + gn];
        if (of32) ((float*)out)[(size_t)gm * N + gn] = v;
        else      ((u16*)out)[(size_t)gm * N + gn] = f2bf(v);
      }
    }
  }
}

// ---------------- LayerNorm: one wave per row, 4 rows/block (final output) ----------------
template<int D>
__global__ __launch_bounds__(256) void lnw_kernel(
    const float* __restrict__ in, const float* __restrict__ w, const float* __restrict__ b,
    float* __restrict__ outf, u16* __restrict__ outb)
{
  constexpr int NV = D / 64;
  int lane = threadIdx.x & 63, wv = threadIdx.x >> 6;
  int row = blockIdx.x * 4 + wv;
  const float* xr = in + (size_t)row * D;
  float v[NV];
  float s = 0.f, s2 = 0.f;
  #pragma unroll
  for (int i = 0; i < NV; ++i) {
    v[i] = xr[lane + i * 64];
    s += v[i]; s2 += v[i] * v[i];
  }
  #pragma unroll
  for (int off = 32; off > 0; off >>= 1) { s += __shfl_xor(s, off); s2 += __shfl_xor(s2, off); }
  float mean = s / (float)D;
  float var = s2 / (float)D - mean * mean;
  float inv = rsqrtf(var + 1e-5f);
  #pragma unroll
  for (int i = 0; i < NV; ++i) {
    int col = lane + i * 64;
    float y = (v[i] - mean) * inv * w[col] + b[col];
    size_t o = (size_t)row * D + col;
    if (outf) outf[o] = y;
    if (outb) outb[o] = f2bf(y);
  }
}

// ---------------- encoder self-attention v6: enc5 body (28KB LDS, 5 blocks/CU) with
//                  XCD-affine 1D grid: the 4 qt-blocks of each (b,h) land on one XCD L2 ------
__global__ __launch_bounds__(256, 5) void attn_enc6_kernel(
    const u16* __restrict__ qkv, u16* __restrict__ out)
{
  __shared__ __align__(16) u16 Ks[64 * 40];       // 5120 B
  __shared__ __align__(16) u16 Vt[32 * 72];       // 4608 B
  __shared__ __align__(16) u16 Pl[4 * 32 * 72];   // 18432 B  (total 28160 -> 5 blocks/CU)
  int F = blockIdx.x;
  int xcd = F & 7, jj = F >> 3;
  int pair = xcd * 32 + (jj >> 2), qt = jj & 3;
  int b = pair >> 3, h = pair & 7;
  int t = threadIdx.x, lane = t & 63, w = t >> 6;
  int mrow = lane & 15, quad = lane >> 4;
  int q0 = qt * 128 + w * 32;
  short8 qf[2];
  #pragma unroll
  for (int mi = 0; mi < 2; ++mi)
    qf[mi] = *(const short8*)(qkv + (size_t)(b * CC + q0 + mi * 16 + mrow) * 768 + h * 32 + quad * 8);
  floatx4 o[2][2];
  #pragma unroll
  for (int mi = 0; mi < 2; ++mi)
    #pragma unroll
    for (int di = 0; di < 2; ++di) o[mi][di] = (floatx4){0.f, 0.f, 0.f, 0.f};
  float lst[2][4] = {{0.f,0.f,0.f,0.f},{0.f,0.f,0.f,0.f}};
  const float sc = 0.17677669529663687f * 1.4426950408889634f;
  const floatx4 zf = (floatx4){0.f, 0.f, 0.f, 0.f};
  for (int jt = 0; jt < 8; ++jt) {
    if (jt) __syncthreads();
    {  // K tile: 64 j x 32 d (one u16x8 per thread)
      int j = t >> 2, q4 = (t & 3) * 8;
      uint4 kk = *(const uint4*)(qkv + (size_t)(b * CC + jt * 64 + j) * 768 + 256 + h * 32 + q4);
      *(uint4*)&Ks[j * 40 + q4] = kk;
      // V tile: transpose+permute into Vt[d][jp], jp=(j&15)*4+(j>>4)
      uint4 vv = *(const uint4*)(qkv + (size_t)(b * CC + jt * 64 + j) * 768 + 512 + h * 32 + q4);
      u16 tmp[8]; *(uint4*)tmp = vv;
      int jp = (j & 15) * 4 + (j >> 4);
      #pragma unroll
      for (int i = 0; i < 8; ++i) Vt[(q4 + i) * 72 + jp] = tmp[i];
    }
    __syncthreads();
    floatx4 s[2][4];
    #pragma unroll
    for (int nj = 0; nj < 4; ++nj) {
      short8 bf = *(const short8*)&Ks[(nj * 16 + mrow) * 40 + quad * 8];
      s[0][nj] = __builtin_amdgcn_mfma_f32_16x16x32_bf16(qf[0], bf, zf, 0, 0, 0);
      s[1][nj] = __builtin_amdgcn_mfma_f32_16x16x32_bf16(qf[1], bf, zf, 0, 0, 0);
    }
    #pragma unroll
    for (int mi = 0; mi < 2; ++mi) {
      #pragma unroll
      for (int r = 0; r < 4; ++r) {
        float ps = 0.f; u16 hv[4];
        #pragma unroll
        for (int nj = 0; nj < 4; ++nj) {
          float p = exp2f(s[mi][nj][r] * sc);
          ps += p; hv[nj] = f2bf(p);
        }
        lst[mi][r] += ps;
        *(uint2*)&Pl[(w * 32 + mi * 16 + quad * 4 + r) * 72 + mrow * 4] = *(uint2*)hv;
      }
    }
    #pragma unroll
    for (int ks = 0; ks < 2; ++ks) {
      short8 a0 = *(const short8*)&Pl[(w * 32 + mrow) * 72 + ks * 32 + quad * 8];
      short8 a1 = *(const short8*)&Pl[(w * 32 + 16 + mrow) * 72 + ks * 32 + quad * 8];
      short8 b0 = *(const short8*)&Vt[mrow * 72 + ks * 32 + quad * 8];
      short8 b1 = *(const short8*)&Vt[(16 + mrow) * 72 + ks * 32 + quad * 8];
      o[0][0] = __builtin_amdgcn_mfma_f32_16x16x32_bf16(a0, b0, o[0][0], 0, 0, 0);
      o[0][1] = __builtin_amdgcn_mfma_f32_16x16x32_bf16(a0, b1, o[0][1], 0, 0, 0);
      o[1][0] = __builtin_amdgcn_mfma_f32_16x16x32_bf16(a1, b0, o[1][0], 0, 0, 0);
      o[1][1] = __builtin_amdgcn_mfma_f32_16x16x32_bf16(a1, b1, o[1][1], 0, 0, 0);
    }
  }
  #pragma unroll
  for (int mi = 0; mi < 2; ++mi) {
    #pragma unroll
    for (int r = 0; r < 4; ++r) {
      float l = lst[mi][r];
      l += __shfl_xor(l, 1); l += __shfl_xor(l, 2);
      l += __shfl_xor(l, 4); l += __shfl_xor(l, 8);
      float inv = 1.f / l;
      int row = b * CC + q0 + mi * 16 + quad * 4 + r;
      #pragma unroll
      for (int di = 0; di < 2; ++di)
        out[(size_t)row * DD + h * 32 + di * 16 + mrow] = f2bf(o[mi][di][r] * inv);
    }
  }
}

// ---------------- fused prefix cross-attention: K/V projections folded through the
//  attention contractions (S = Qc·tln, T = P·tln, O = (T/l)·Wcv^T + bv).
//  Grid is (b, h) so XCD = b&7: each XCD L2 holds 4 tln batches (1MB) reused by 8 heads. ----
__global__ __launch_bounds__(256) void attn_preff_kernel(
    const u16* __restrict__ tln, const u16* __restrict__ wcb,
    const u16* __restrict__ qcg, const float* __restrict__ bkv,
    u16* __restrict__ out)
{
  __shared__ __align__(16) u16 Ajc[64 * 264];   // tln tile [j][c]      33792 B
  __shared__ __align__(16) u16 Acj[256 * 72];   // tln^T tile [c][j]    36864 B
  __shared__ __align__(16) u16 Qs[16 * 264];    // Qc_h [q][c]           8448 B
  __shared__ __align__(16) u16 Ps[16 * 72];     // P tile [q][j]         2304 B
  __shared__ __align__(16) u16 Ts[16 * 264];    // T/l [q][c]            8448 B
  __shared__ float Lred[4][16];
  int b = blockIdx.x, h = blockIdx.y;
  int t = threadIdx.x, lane = t & 63, w = t >> 6;
  int mrow = lane & 15, quad = lane >> 4;
  const float sc = 0.08838834764831845f * 1.4426950408889634f;
  const floatx4 zf = (floatx4){0.f, 0.f, 0.f, 0.f};
  {  // stage Qc_h: 16 x 256, thread t -> row t>>4, 16 cols
    int q = t >> 4, c0 = (t & 15) * 16;
    *(uint4*)&Qs[q * 264 + c0]     = *(const uint4*)(qcg + ((size_t)h * 16 + q) * 256 + c0);
    *(uint4*)&Qs[q * 264 + c0 + 8] = *(const uint4*)(qcg + ((size_t)h * 16 + q) * 256 + c0 + 8);
  }
  floatx4 Tacc[4] = {zf, zf, zf, zf};   // T[q][c], warp owns c in [w*64, w*64+64)
  float lacc = 0.f;
  const u16* tb = tln + (size_t)b * 512 * 256;
  for (int jt = 0; jt < 8; ++jt) {
    __syncthreads();   // WAR vs prev tile's reads; covers Qs staging on iter 0
    {  // stage tln tile [64 j][256 c] both orientations; thread: row j=t>>2, cols (t&3)*64..+64
      int j = t >> 2, c0 = (t & 3) * 64;
      #pragma unroll
      for (int u = 0; u < 8; ++u) {
        uint4 v = *(const uint4*)(tb + (size_t)(jt * 64 + j) * 256 + c0 + u * 8);
        *(uint4*)&Ajc[j * 264 + c0 + u * 8] = v;
        u16 tmp[8]; *(uint4*)tmp = v;
        #pragma unroll
        for (int i = 0; i < 8; ++i) Acj[(c0 + u * 8 + i) * 72 + j] = tmp[i];
      }
    }
    __syncthreads();
    // S^T[j,q]: warp w handles j in [w*16, w*16+16); K = 256 c
    floatx4 s = zf;
    #pragma unroll
    for (int kk = 0; kk < 8; ++kk) {
      short8 af = *(const short8*)&Ajc[(w * 16 + mrow) * 264 + kk * 32 + quad * 8];
      short8 bf = *(const short8*)&Qs[mrow * 264 + kk * 32 + quad * 8];
      s = __builtin_amdgcn_mfma_f32_16x16x32_bf16(af, bf, s, 0, 0, 0);
    }
    // lane holds s[r] for j = w*16 + quad*4 + r, q = mrow
    u16 hv[4]; float ps = 0.f;
    #pragma unroll
    for (int r = 0; r < 4; ++r) {
      float p = exp2f(s[r] * sc);
      ps += p; hv[r] = f2bf(p);
    }
    ps += __shfl_xor(ps, 16); ps += __shfl_xor(ps, 32);  // sum over warp's 16 j (per q=mrow)
    lacc += ps;
    *(uint2*)&Ps[mrow * 72 + w * 16 + quad * 4] = *(uint2*)hv;
    __syncthreads();
    // T += P @ tln_tile: warp w owns c-tiles [w*64..); K = 64 j
    #pragma unroll
    for (int kk = 0; kk < 2; ++kk) {
      short8 af = *(const short8*)&Ps[mrow * 72 + kk * 32 + quad * 8];
      #pragma unroll
      for (int ct = 0; ct < 4; ++ct) {
        short8 bf = *(const short8*)&Acj[(w * 64 + ct * 16 + mrow) * 72 + kk * 32 + quad * 8];
        Tacc[ct] = __builtin_amdgcn_mfma_f32_16x16x32_bf16(af, bf, Tacc[ct], 0, 0, 0);
      }
    }
  }
  if (lane < 16) Lred[w][lane] = lacc;   // lacc valid for q = mrow = lane
  __syncthreads();
  // normalize T, write Ts[q][c] (lane: q = quad*4+r, c = w*64 + ct*16 + mrow)
  #pragma unroll
  for (int r = 0; r < 4; ++r) {
    int q = quad * 4 + r;
    float l = Lred[0][q] + Lred[1][q] + Lred[2][q] + Lred[3][q];
    float inv = 1.f / l;
    #pragma unroll
    for (int ct = 0; ct < 4; ++ct)
      Ts[q * 264 + w * 64 + ct * 16 + mrow] = f2bf(Tacc[ct][r] * inv);
  }
  __syncthreads();
  // O = Ts @ Wcv_h^T + bv: warp w owns d-tiles [w*32, w*32+32); K = 256 c
  const u16* wv = wcb + (size_t)(1024 + h * 128) * 256;
  floatx4 oacc[2] = {zf, zf};
  #pragma unroll
  for (int kk = 0; kk < 8; ++kk) {
    short8 af = *(const short8*)&Ts[mrow * 264 + kk * 32 + quad * 8];
    #pragma unroll
    for (int dt = 0; dt < 2; ++dt) {
      short8 bf = *(const short8*)(wv + (size_t)(w * 32 + dt * 16 + mrow) * 256 + kk * 32 + quad * 8);
      oacc[dt] = __builtin_amdgcn_mfma_f32_16x16x32_bf16(af, bf, oacc[dt], 0, 0, 0);
    }
  }
  #pragma unroll
  for (int dt = 0; dt < 2; ++dt) {
    int d = w * 32 + dt * 16 + mrow;
    float bv = bkv[1024 + h * 128 + d];
    #pragma unroll
    for (int r = 0; r < 4; ++r) {
      int q = quad * 4 + r;
      out[((size_t)(b * 16 + q)) * 1024 + h * 128 + d] = f2bf(oacc[dt][r] + bv);
    }
  }
}

extern "C" void kernel_launch(void* const* d_in, const int* in_sizes, int n_in,
                              void* d_out, int out_size, void* d_ws, size_t ws_size,
                              hipStream_t stream)
{
  const int* vi = (const int*)d_in[0];
  const int* si = (const int*)d_in[1];
  const int* mk = (const int*)d_in[2];
  const float* ve   = (const float*)d_in[3];
  const float* se   = (const float*)d_in[4];
  const float* lpe  = (const float*)d_in[5];
  const float* cpe  = (const float*)d_in[6];
  const float* eiw  = (const float*)d_in[7];
  const float* eib  = (const float*)d_in[8];
  const float* eow  = (const float*)d_in[9];
  const float* eob  = (const float*)d_in[10];
  const float* f1w  = (const float*)d_in[11];
  const float* f1b  = (const float*)d_in[12];
  const float* f2w  = (const float*)d_in[13];
  const float* f2b  = (const float*)d_in[14];
  const float* n1w  = (const float*)d_in[15];
  const float* n1b  = (const float*)d_in[16];
  const float* n2w  = (const float*)d_in[17];
  const float* n2b  = (const float*)d_in[18];
  const float* tlw  = (const float*)d_in[19];
  const float* tlb  = (const float*)d_in[20];
  const float* thw  = (const float*)d_in[21];
  const float* thb  = (const float*)d_in[22];
  const float* pq   = (const float*)d_in[23];
  const float* paiw = (const float*)d_in[24];
  const float* paib = (const float*)d_in[25];
  const float* paow = (const float*)d_in[26];
  const float* paob = (const float*)d_in[27];
  const float* pnw  = (const float*)d_in[28];
  const float* pnb  = (const float*)d_in[29];

  const int NROW = BB * CC;  // 16384
  const size_t MB = 1048576;
  char* base = (char*)d_ws;
  // encoder phase:
  u16* xb   = (u16*)(base);                // [0,8M)   bf16 residual stream (post-LN)
  u16* qkvb = (u16*)(base + 8 * MB);       // [8M,32M)
  u16* atto = (u16*)(base + 32 * MB);      // [32M,40M)
  u16* tln  = (u16*)(base + 96 * MB);      // [96M,104M)
  // folded-weight region [64M,70M):
  u16* wcb   = (u16*)(base + 64 * MB);     // [64M,65M)  Wc = Wkv @ th_w, bf16 [2048,256]
  u16* thwTb = (u16*)(base + 65 * MB);     // [65M,65.5M) th_w^T bf16 [256,1024]
  float* bkv = (float*)(base + 66 * MB);   // [66M,66M+8K) folded KV bias fp32 [2048]
  u16* wckT  = (u16*)(base + 67 * MB);     // [67M,67.5M) Wck^T bf16 [256,1024]
  u16* qcg   = (u16*)(base + 68 * MB);     // [68M,+64K)  Qc bf16 [8][16][256]
  float* skpart = (float*)(base + 80 * MB);// [80M,88M) split-K f32 partials
  u16* wbf  = (u16*)(base + 104 * MB);     // [104M,~119M)
  u16* qh    = (u16*)(base + 120 * MB);    // [120M,+256K) qh scratch (rows 16..127 garbage)
  u16* prefo = (u16*)(base + 121 * MB);    // [121M,+1M)
  float* prefout = (float*)(base + 122 * MB);

  u16* eiw_b  = wbf + 0;
  u16* eow_b  = wbf + 786432;
  u16* f1w_b  = wbf + 1048576;
  u16* f2w_b  = wbf + 2097152;
  u16* thw_b  = wbf + 3145728;
  u16* paiw_b = wbf + 3407872;
  u16* paow_b = wbf + 6553600;
  u16* pqb    = wbf + 7602176;
  u16* veb    = wbf + 7618560;
  u16* seb    = wbf + 7749888;
  u16* lpeb   = wbf + 7750656;
  u16* cpeb   = wbf + 7754752;

  dim3 blk(256);
  cvt_kernel<<<7701, blk, 0, stream>>>(eiw, eow, f1w, f2w, thw, paiw, paow, pq,
                                       ve, se, lpe, cpe, wbf);
  // weight fold: Wc[n,d] = sum_h Wkv[n,h]*th_w[h,d]; bkv[n] = Wkv[n,:]·th_b + pa_in_b[1024+n]
  thwT_kernel<<<256, blk, 0, stream>>>(thw, thwTb);
  biasfold_kernel<<<512, blk, 0, stream>>>(paiw_b + (size_t)HH * HH, thb, paib, bkv);
  gemm128_kernel<<<dim3(2, 16, 4), blk, 0, stream>>>(
      paiw_b + (size_t)HH * HH, thwTb, nullptr, nullptr, skpart, 2048, 256, HH, 0);
  redk_kernel<<<512, blk, 0, stream>>>(skpart, nullptr, nullptr, nullptr, wcb,
                                       256, 4, 2048 * 256, 0);
  // qh = pq @ Wq^T via split-K (latency-bound tail fix)
  gemm128_kernel<<<dim3(8, 1, 8), blk, 0, stream>>>(
      pqb, paiw_b, nullptr, nullptr, skpart, 128, 1024, HH, 0);
  redk_kernel<<<128, blk, 0, stream>>>(skpart, paib, nullptr, nullptr, qh,
                                       1024, 8, 128 * 1024, 0);
  bT_kernel<<<256, blk, 0, stream>>>(wcb, wckT);
  qc_kernel<<<8, blk, 0, stream>>>(qh, wckT, qcg);
  embed_kernel<<<NROW/2, blk, 0, stream>>>(vi, si, mk, veb, seb, lpeb, cpeb, xb);
  for (int i = 0; i < NLAY; ++i) {
    gwide_kernel<384, false, false, false><<<dim3(2, NROW/32), blk, 0, stream>>>(
        xb, eiw_b + (size_t)i*768*DD, eib + i*768, nullptr, nullptr, nullptr, nullptr, nullptr,
        qkvb, 768, DD);
    attn_enc6_kernel<<<1024, blk, 0, stream>>>(qkvb, atto);
    gwide_kernel<256, false, true, false><<<dim3(1, NROW/32), blk, 0, stream>>>(
        atto, eow_b + (size_t)i*DD*DD, eob + i*DD, xb, n1w + i*DD, n1b + i*DD, nullptr, nullptr,
        xb, DD, DD);
    // fused FF1+gelu+FF2+res+LN v2: 64 rows/block, x staged once, Ws amortized 2x
    if (i < NLAY - 1) {
      ffu_kernel<false><<<NROW/64, blk, 0, stream>>>(
          xb, f1w_b + (size_t)i*HH*DD, f1b + i*HH, f2w_b + (size_t)i*DD*HH, f2b + i*DD,
          xb, n2w + i*DD, n2b + i*DD, nullptr, nullptr, xb);
    } else {
      ffu_kernel<true><<<NROW/64, blk, 0, stream>>>(
          xb, f1w_b + (size_t)i*HH*DD, f1b + i*HH, f2w_b + (size_t)i*DD*HH, f2b + i*DD,
          xb, n2w + i*DD, n2b + i*DD, tlw, tlb, tln);
    }
  }
  // fused prefix cross-attention (b-major grid: XCD = b&7, tln L2-resident per XCD)
  attn_preff_kernel<<<dim3(BB, 8), blk, 0, stream>>>(tln, wcb, qcg, bkv, prefo);
  // split-K out-proj
  gemm128_kernel<<<dim3(1024/128, (BB*PP)/128, 4), blk, 0, stream>>>(
      prefo, paow_b, nullptr, nullptr, skpart, BB*PP, HH, HH, 0);
  redk_kernel<<<512, blk, 0, stream>>>(skpart, paob, pq, prefout, nullptr,
                                       1024, 4, BB*PP*HH, 4);
  lnw_kernel<1024><<<(BB*PP)/4, blk, 0, stream>>>(prefout, pnw, pnb, (float*)d_out, nullptr);
}

// Round 12
// 718.031 us; speedup vs baseline: 1.1804x; 1.1804x over previous
//
#include <hip/hip_runtime.h>
#include <hip/hip_bf16.h>

typedef unsigned short u16;
typedef unsigned int u32;
typedef __attribute__((ext_vector_type(8))) short short8;
typedef __attribute__((ext_vector_type(4))) float floatx4;

#define BB 32
#define CC 512
#define LL 16
#define DD 256
#define HH 1024
#define PP 16
#define NLAY 4

__device__ __forceinline__ float bf2f(u16 u) {
  u32 x = ((u32)u) << 16; float f; __builtin_memcpy(&f, &x, 4); return f;
}
__device__ __forceinline__ u16 f2bf(float f) {
  __hip_bfloat16 h = __float2bfloat16(f);
  u16 r; __builtin_memcpy(&r, &h, 2); return r;
}
__device__ __forceinline__ void gload_lds16(const u16* g, u16* l) {
  __builtin_amdgcn_global_load_lds(
      (const __attribute__((address_space(1))) void*)g,
      (__attribute__((address_space(3))) void*)l, 16, 0, 0);
}

// ---------------- fp32 -> bf16 conversion: 8 weight tensors + 4 embedding tables ----------------
__global__ __launch_bounds__(256) void cvt_kernel(
    const float* __restrict__ s0, const float* __restrict__ s1,
    const float* __restrict__ s2, const float* __restrict__ s3,
    const float* __restrict__ s4, const float* __restrict__ s5,
    const float* __restrict__ s6, const float* __restrict__ s7,
    const float* __restrict__ s8, const float* __restrict__ s9,
    const float* __restrict__ s10, const float* __restrict__ s11,
    u16* __restrict__ dst)
{
  const float* srcs[12] = {s0, s1, s2, s3, s4, s5, s6, s7, s8, s9, s10, s11};
  const int pfx[12] = {786432, 1048576, 2097152, 3145728, 3407872, 6553600, 7602176,
                       7618560, 7749888, 7750656, 7754752, 7885824};
  int e = (blockIdx.x * 256 + threadIdx.x) * 4;
  int seg = 0;
  while (e >= pfx[seg]) seg++;
  int start = seg ? pfx[seg - 1] : 0;
  float4 f = *(const float4*)(srcs[seg] + (e - start));
  u16 o[4] = {f2bf(f.x), f2bf(f.y), f2bf(f.z), f2bf(f.w)};
  *(uint2*)(dst + e) = *(const uint2*)o;
}

// ---------------- th_w [1024,256] fp32 -> bf16 transposed [256,1024] (K-major for fold GEMM) ---
__global__ __launch_bounds__(256) void thwT_kernel(
    const float* __restrict__ thw, u16* __restrict__ out)
{
  __shared__ float tile[32][33];
  int bx = blockIdx.x & 7, by = blockIdx.x >> 3;   // bx: d-tile (8), by: h-tile (32)
  int tx = threadIdx.x & 31, ty = threadIdx.x >> 5;
  #pragma unroll
  for (int i = 0; i < 4; ++i) {
    int h = by * 32 + ty + i * 8, d = bx * 32 + tx;
    tile[ty + i * 8][tx] = thw[h * 256 + d];
  }
  __syncthreads();
  #pragma unroll
  for (int i = 0; i < 4; ++i) {
    int d = bx * 32 + ty + i * 8, h = by * 32 + tx;
    out[d * 1024 + h] = f2bf(tile[tx][ty + i * 8]);
  }
}

// ---------------- bf16 transpose [1024,256] -> [256,1024] (Wck^T for Qc fold) ----------------
__global__ __launch_bounds__(256) void bT_kernel(
    const u16* __restrict__ in, u16* __restrict__ out)
{
  __shared__ u16 tile[32][33];
  int bx = blockIdx.x & 7, by = blockIdx.x >> 3;   // bx: c-tile (8), by: hd-tile (32)
  int tx = threadIdx.x & 31, ty = threadIdx.x >> 5;
  #pragma unroll
  for (int i = 0; i < 4; ++i) {
    int hd = by * 32 + ty + i * 8, c = bx * 32 + tx;
    tile[ty + i * 8][tx] = in[hd * 256 + c];
  }
  __syncthreads();
  #pragma unroll
  for (int i = 0; i < 4; ++i) {
    int c = bx * 32 + ty + i * 8, hd = by * 32 + tx;
    out[c * 1024 + hd] = tile[tx][ty + i * 8];
  }
}

// ---------------- Qc fold: Qc[h][q][c] = sum_d qh[q, h*128+d] * Wck[h*128+d, c] ------------
__global__ __launch_bounds__(256) void qc_kernel(
    const u16* __restrict__ qh, const u16* __restrict__ wckT, u16* __restrict__ qcg)
{
  int h = blockIdx.x;
  int t = threadIdx.x, lane = t & 63, w = t >> 6;
  int mrow = lane & 15, quad = lane >> 4;
  const floatx4 zf = (floatx4){0.f, 0.f, 0.f, 0.f};
  floatx4 acc[4] = {zf, zf, zf, zf};
  #pragma unroll
  for (int kk = 0; kk < 4; ++kk) {
    short8 af = *(const short8*)(qh + (size_t)mrow * 1024 + h * 128 + kk * 32 + quad * 8);
    #pragma unroll
    for (int ct = 0; ct < 4; ++ct) {
      int c = w * 64 + ct * 16 + mrow;
      short8 bf = *(const short8*)(wckT + (size_t)c * 1024 + h * 128 + kk * 32 + quad * 8);
      acc[ct] = __builtin_amdgcn_mfma_f32_16x16x32_bf16(af, bf, acc[ct], 0, 0, 0);
    }
  }
  #pragma unroll
  for (int ct = 0; ct < 4; ++ct)
    #pragma unroll
    for (int r = 0; r < 4; ++r)
      qcg[((size_t)h * 16 + quad * 4 + r) * 256 + w * 64 + ct * 16 + mrow] = f2bf(acc[ct][r]);
}

// ---------------- folded KV bias: bkv[n] = Wkv[n,:]·th_b + pa_in_b[1024+n], one wave/row ------
__global__ __launch_bounds__(256) void biasfold_kernel(
    const u16* __restrict__ Wkv, const float* __restrict__ thb,
    const float* __restrict__ paib, float* __restrict__ out)
{
  int wv = threadIdx.x >> 6, lane = threadIdx.x & 63;
  int n = blockIdx.x * 4 + wv;
  const u16* wr = Wkv + (size_t)n * 1024;
  float s = 0.f;
  #pragma unroll
  for (int i = 0; i < 16; ++i) {
    int h = i * 64 + lane;
    s += bf2f(wr[h]) * thb[h];
  }
  #pragma unroll
  for (int off = 32; off; off >>= 1) s += __shfl_xor(s, off);
  if (!lane) out[n] = s + paib[1024 + n];
}

// ---------------- split-K reduce: sum nz f32 partials + bias/res, write f32 or bf16 ----------
__global__ __launch_bounds__(256) void redk_kernel(
    const float* __restrict__ part, const float* __restrict__ bias,
    const float* __restrict__ res, float* __restrict__ outf, u16* __restrict__ outb,
    int N, int nz, int total, int flags)   // flags&4: res row index is (row&15)
{
  int idx = (blockIdx.x * 256 + threadIdx.x) * 4;
  if (idx >= total) return;
  float4 a = *(const float4*)(part + idx);
  for (int z = 1; z < nz; ++z) {
    float4 b = *(const float4*)(part + (size_t)z * total + idx);
    a.x += b.x; a.y += b.y; a.z += b.z; a.w += b.w;
  }
  int row = idx / N, col = idx - row * N;   // 4 consecutive cols, same row (N % 4 == 0)
  float v4[4] = {a.x, a.y, a.z, a.w};
  #pragma unroll
  for (int i = 0; i < 4; ++i) {
    if (bias) v4[i] += bias[col + i];
    if (res) v4[i] += res[(size_t)((flags & 4) ? (row & 15) : row) * N + col + i];
  }
  if (outf) {
    *(float4*)(outf + idx) = *(const float4*)v4;
  } else {
    u16 o[4] = {f2bf(v4[0]), f2bf(v4[1]), f2bf(v4[2]), f2bf(v4[3])};
    *(uint2*)(outb + idx) = *(const uint2*)o;
  }
}

// ---------------- embed + masked mean pool (bf16 tables, 2 clauses/block, u32 loads) --------
__global__ __launch_bounds__(256) void embed_kernel(
    const int* __restrict__ vi, const int* __restrict__ si, const int* __restrict__ mk,
    const u16* __restrict__ veb, const u16* __restrict__ seb,
    const u16* __restrict__ lpeb, const u16* __restrict__ cpeb,
    u16* __restrict__ xb)
{
  int t = threadIdx.x;
  int bc = blockIdx.x * 2 + (t >> 7);
  int c = bc & (CC - 1);
  int dl = (t & 127) * 2;
  int base = bc * LL;
  float a0 = 0.f, a1 = 0.f; int cnt = 0;
  #pragma unroll
  for (int l = 0; l < LL; ++l) {
    if (mk[base + l]) {
      int v = vi[base + l], s = si[base + l];
      u32 vv = *(const u32*)&veb[v * DD + dl];
      u32 sv = *(const u32*)&seb[s * DD + dl];
      u32 lv = *(const u32*)&lpeb[l * DD + dl];
      a0 += bf2f((u16)vv) + bf2f((u16)sv) + bf2f((u16)lv);
      a1 += bf2f((u16)(vv >> 16)) + bf2f((u16)(sv >> 16)) + bf2f((u16)(lv >> 16));
      cnt++;
    }
  }
  u32 cv = *(const u32*)&cpeb[c * DD + dl];
  float inv = 1.f / (float)cnt;
  u32 pk = (u32)f2bf(a0 * inv + bf2f((u16)cv)) | ((u32)f2bf(a1 * inv + bf2f((u16)(cv >> 16))) << 16);
  *(u32*)&xb[(size_t)bc * DD + dl] = pk;
}

// ---------------- wide-N GEMM 32 rows (v2 warp mapping; QKV and attn-out-LN call-sites) ----
template<int NC, bool GELU, bool LN, bool DLN>
__global__ __launch_bounds__(256) void gwide_kernel(
    const u16* __restrict__ A, const u16* __restrict__ W, const float* __restrict__ bias,
    const u16* __restrict__ resb, const float* __restrict__ gam, const float* __restrict__ bet,
    const float* __restrict__ gam2, const float* __restrict__ bet2,
    u16* __restrict__ out, int N, int K)
{
  constexpr int NT = NC / 32;    // staging tile count
  constexpr int NT4 = NC / 64;   // col tiles per warp
  __shared__ __align__(16) u16 As[32 * 64];
  __shared__ __align__(16) u16 Ws[NC * 64];
  __shared__ float sred[32][4][2];
  __shared__ float sred2[32][4][2];
  int t = threadIdx.x, lane = t & 63, w = t >> 6;
  int mrow = lane & 15, quad = lane >> 4;
  int bn0 = blockIdx.x * NC, bm0 = blockIdx.y * 32;

  int rA = t >> 3, gcA = (t & 7) ^ (rA & 7);
  const u16* gAp = A + (size_t)(bm0 + rA) * K + gcA * 8;
  u16* lAp = As + (w * 64) * 8;
  const u16* gW0 = W + (size_t)(bn0 + rA) * K + gcA * 8;
  u16* lW0 = Ws + (w * 64) * 8;

  floatx4 acc[2][NT4];
  #pragma unroll
  for (int mi = 0; mi < 2; ++mi)
    #pragma unroll
    for (int nt = 0; nt < NT4; ++nt) acc[mi][nt] = (floatx4){0.f, 0.f, 0.f, 0.f};

  for (int k0 = 0; k0 < K; k0 += 64) {
    __syncthreads();
    gload_lds16(gAp, lAp); gAp += 64;
    #pragma unroll
    for (int i = 0; i < NT; ++i)
      gload_lds16(gW0 + (size_t)i * 32 * K, lW0 + i * 2048);
    gW0 += 64;
    __syncthreads();
    #pragma unroll
    for (int ks = 0; ks < 2; ++ks) {
      int sw = ((ks * 4 + quad) ^ (mrow & 7)) * 8;
      short8 af0 = *(const short8*)&As[mrow * 64 + sw];
      short8 af1 = *(const short8*)&As[(16 + mrow) * 64 + sw];
      #pragma unroll
      for (int nt = 0; nt < NT4; ++nt) {
        int rw = w * (NC / 4) + nt * 16 + mrow;
        short8 bf = *(const short8*)&Ws[rw * 64 + sw];
        acc[0][nt] = __builtin_amdgcn_mfma_f32_16x16x32_bf16(af0, bf, acc[0][nt], 0, 0, 0);
        acc[1][nt] = __builtin_amdgcn_mfma_f32_16x16x32_bf16(af1, bf, acc[1][nt], 0, 0, 0);
      }
    }
  }

  if constexpr (LN) {
    float val[2][NT4][4];
    float bv[NT4];
    #pragma unroll
    for (int nt = 0; nt < NT4; ++nt) bv[nt] = bias[w * 64 + nt * 16 + mrow];
    #pragma unroll
    for (int mi = 0; mi < 2; ++mi) {
      #pragma unroll
      for (int r = 0; r < 4; ++r) {
        int gm = bm0 + mi * 16 + quad * 4 + r;
        float sr = 0.f, s2r = 0.f;
        #pragma unroll
        for (int nt = 0; nt < NT4; ++nt) {
          int gn = w * 64 + nt * 16 + mrow;
          float v = acc[mi][nt][r] + bv[nt] + bf2f(resb[(size_t)gm * 256 + gn]);
          val[mi][nt][r] = v; sr += v; s2r += v * v;
        }
        sr += __shfl_xor(sr, 1); s2r += __shfl_xor(s2r, 1);
        sr += __shfl_xor(sr, 2); s2r += __shfl_xor(s2r, 2);
        sr += __shfl_xor(sr, 4); s2r += __shfl_xor(s2r, 4);
        sr += __shfl_xor(sr, 8); s2r += __shfl_xor(s2r, 8);
        if (mrow == 0) { sred[mi * 16 + quad * 4 + r][w][0] = sr; sred[mi * 16 + quad * 4 + r][w][1] = s2r; }
      }
    }
    __syncthreads();
    #pragma unroll
    for (int mi = 0; mi < 2; ++mi) {
      #pragma unroll
      for (int r = 0; r < 4; ++r) {
        int lrow = mi * 16 + quad * 4 + r;
        float S  = sred[lrow][0][0] + sred[lrow][1][0] + sred[lrow][2][0] + sred[lrow][3][0];
        float S2 = sred[lrow][0][1] + sred[lrow][1][1] + sred[lrow][2][1] + sred[lrow][3][1];
        float mean = S * (1.f / 256.f);
        float var = S2 * (1.f / 256.f) - mean * mean;
        float inv = rsqrtf(var + 1e-5f);
        float sr2 = 0.f, s2r2 = 0.f;
        #pragma unroll
        for (int nt = 0; nt < NT4; ++nt) {
          int gn = w * 64 + nt * 16 + mrow;
          float y = (val[mi][nt][r] - mean) * inv * gam[gn] + bet[gn];
          val[mi][nt][r] = y;
          if constexpr (DLN) { sr2 += y; s2r2 += y * y; }
          else out[(size_t)(bm0 + lrow) * 256 + gn] = f2bf(y);
        }
        if constexpr (DLN) {
          sr2 += __shfl_xor(sr2, 1); s2r2 += __shfl_xor(s2r2, 1);
          sr2 += __shfl_xor(sr2, 2); s2r2 += __shfl_xor(s2r2, 2);
          sr2 += __shfl_xor(sr2, 4); s2r2 += __shfl_xor(s2r2, 4);
          sr2 += __shfl_xor(sr2, 8); s2r2 += __shfl_xor(s2r2, 8);
          if (mrow == 0) { sred2[lrow][w][0] = sr2; sred2[lrow][w][1] = s2r2; }
        }
      }
    }
    if constexpr (DLN) {
      __syncthreads();
      #pragma unroll
      for (int mi = 0; mi < 2; ++mi) {
        #pragma unroll
        for (int r = 0; r < 4; ++r) {
          int lrow = mi * 16 + quad * 4 + r;
          float S  = sred2[lrow][0][0] + sred2[lrow][1][0] + sred2[lrow][2][0] + sred2[lrow][3][0];
          float S2 = sred2[lrow][0][1] + sred2[lrow][1][1] + sred2[lrow][2][1] + sred2[lrow][3][1];
          float mean = S * (1.f / 256.f);
          float var = S2 * (1.f / 256.f) - mean * mean;
          float inv = rsqrtf(var + 1e-5f);
          #pragma unroll
          for (int nt = 0; nt < NT4; ++nt) {
            int gn = w * 64 + nt * 16 + mrow;
            float z = (val[mi][nt][r] - mean) * inv * gam2[gn] + bet2[gn];
            out[(size_t)(bm0 + lrow) * 256 + gn] = f2bf(z);
          }
        }
      }
    }
  } else {
    #pragma unroll
    for (int nt = 0; nt < NT4; ++nt) {
      int gn = bn0 + w * (NC / 4) + nt * 16 + mrow;
      float bv = bias[gn];
      #pragma unroll
      for (int mi = 0; mi < 2; ++mi) {
        #pragma unroll
        for (int r = 0; r < 4; ++r) {
          int gm = bm0 + mi * 16 + quad * 4 + r;
          float v = acc[mi][nt][r] + bv;
          if (GELU) v = 0.5f * v * (1.f + erff(v * 0.70710678118654752f));
          out[(size_t)gm * N + gn] = f2bf(v);
        }
      }
    }
  }
}

// ---------------- fused FFN: y = LN(res + b2 + gelu(x@W1^T + b1)@W2^T) per 32 rows --------
//  h never leaves LDS: per 256-col quarter, FF1 -> gelu -> Hs (As-format) -> FF2 partial.
//  LDS 52KB -> 2 blocks/CU (the latency-hiding mechanism: co-resident block covers drains).
template<bool DLN>
__global__ __launch_bounds__(256) void ffu_kernel(
    const u16* __restrict__ A, const u16* __restrict__ W1, const float* __restrict__ b1,
    const u16* __restrict__ W2, const float* __restrict__ b2,
    const u16* __restrict__ resb,
    const float* __restrict__ gam, const float* __restrict__ bet,
    const float* __restrict__ gam2, const float* __restrict__ bet2,
    u16* __restrict__ out)
{
  __shared__ __align__(16) u16 As[2048];       // 4 KB: x k-step tile
  __shared__ __align__(16) u16 Ws[8 * 2048];   // 32 KB: W1-quarter / W2-slice staging
  __shared__ __align__(16) u16 Hs[4 * 2048];   // 16 KB: gelu(h) quarter, As-format (4 k-tiles)
  int t = threadIdx.x, lane = t & 63, w = t >> 6;
  int mrow = lane & 15, quad = lane >> 4;
  int bm0 = blockIdx.x * 32;
  int rA = t >> 3, gcA = (t & 7) ^ (rA & 7);

  floatx4 yacc[2][4];
  #pragma unroll
  for (int mi = 0; mi < 2; ++mi)
    #pragma unroll
    for (int nt = 0; nt < 4; ++nt) yacc[mi][nt] = (floatx4){0.f, 0.f, 0.f, 0.f};

  for (int nq = 0; nq < 4; ++nq) {
    floatx4 hacc[2][4];
    #pragma unroll
    for (int mi = 0; mi < 2; ++mi)
      #pragma unroll
      for (int nt = 0; nt < 4; ++nt) hacc[mi][nt] = (floatx4){0.f, 0.f, 0.f, 0.f};
    // FF1: h[:, nq*256 .. +256) = x @ W1_q^T  (K = 256, 4 k-steps)
    for (int kt = 0; kt < 4; ++kt) {
      __syncthreads();
      gload_lds16(A + (size_t)(bm0 + rA) * 256 + kt * 64 + gcA * 8, As + (w * 64) * 8);
      #pragma unroll
      for (int i = 0; i < 8; ++i)
        gload_lds16(W1 + (size_t)(nq * 256 + i * 32 + rA) * 256 + kt * 64 + gcA * 8,
                    Ws + i * 2048 + (w * 64) * 8);
      __syncthreads();
      #pragma unroll
      for (int ks = 0; ks < 2; ++ks) {
        int sw = ((ks * 4 + quad) ^ (mrow & 7)) * 8;
        short8 af0 = *(const short8*)&As[mrow * 64 + sw];
        short8 af1 = *(const short8*)&As[(16 + mrow) * 64 + sw];
        #pragma unroll
        for (int nt = 0; nt < 4; ++nt) {
          short8 bf = *(const short8*)&Ws[(w * 64 + nt * 16 + mrow) * 64 + sw];
          hacc[0][nt] = __builtin_amdgcn_mfma_f32_16x16x32_bf16(af0, bf, hacc[0][nt], 0, 0, 0);
          hacc[1][nt] = __builtin_amdgcn_mfma_f32_16x16x32_bf16(af1, bf, hacc[1][nt], 0, 0, 0);
        }
      }
    }
    // gelu + bias1, write quarter into Hs in As-format. Warp w's 64 cols = quarter-local
    // k-tile w. For value at (row, cc): group g = cc>>3, slot = g ^ (row&7), pos = cc&7.
    {
      float bv1[4];
      #pragma unroll
      for (int nt = 0; nt < 4; ++nt) bv1[nt] = b1[nq * 256 + w * 64 + nt * 16 + mrow];
      #pragma unroll
      for (int mi = 0; mi < 2; ++mi) {
        #pragma unroll
        for (int nt = 0; nt < 4; ++nt) {
          int g = nt * 2 + (mrow >> 3);
          #pragma unroll
          for (int r = 0; r < 4; ++r) {
            int row = mi * 16 + quad * 4 + r;
            float v = hacc[mi][nt][r] + bv1[nt];
            v = 0.5f * v * (1.f + erff(v * 0.70710678118654752f));
            Hs[w * 2048 + row * 64 + (g ^ (row & 7)) * 8 + (mrow & 7)] = f2bf(v);
          }
        }
      }
    }
    // FF2 partial: yacc += gelu_h_q @ W2[:, nq*256 .. +256)^T  (4 k-steps, A local in Hs)
    for (int kt2 = 0; kt2 < 4; ++kt2) {
      __syncthreads();   // covers Hs writes (iter 0) + Ws WAR
      #pragma unroll
      for (int i = 0; i < 8; ++i)
        gload_lds16(W2 + (size_t)(i * 32 + rA) * 1024 + nq * 256 + kt2 * 64 + gcA * 8,
                    Ws + i * 2048 + (w * 64) * 8);
      __syncthreads();
      #pragma unroll
      for (int ks = 0; ks < 2; ++ks) {
        int sw = ((ks * 4 + quad) ^ (mrow & 7)) * 8;
        short8 af0 = *(const short8*)&Hs[kt2 * 2048 + mrow * 64 + sw];
        short8 af1 = *(const short8*)&Hs[kt2 * 2048 + (16 + mrow) * 64 + sw];
        #pragma unroll
        for (int nt = 0; nt < 4; ++nt) {
          short8 bf = *(const short8*)&Ws[(w * 64 + nt * 16 + mrow) * 64 + sw];
          yacc[0][nt] = __builtin_amdgcn_mfma_f32_16x16x32_bf16(af0, bf, yacc[0][nt], 0, 0, 0);
          yacc[1][nt] = __builtin_amdgcn_mfma_f32_16x16x32_bf16(af1, bf, yacc[1][nt], 0, 0, 0);
        }
      }
    }
  }
  // epilogue: residual + LN (+DLN). sred aliased into Hs (dead; guarded by barrier).
  __syncthreads();
  float* sred  = (float*)Hs;            // [32][4][2]
  float* sred2 = (float*)(Hs + 2048);   // [32][4][2]
  float val[2][4][4];
  float bv[4];
  #pragma unroll
  for (int nt = 0; nt < 4; ++nt) bv[nt] = b2[w * 64 + nt * 16 + mrow];
  #pragma unroll
  for (int mi = 0; mi < 2; ++mi) {
    #pragma unroll
    for (int r = 0; r < 4; ++r) {
      int gm = bm0 + mi * 16 + quad * 4 + r;
      float sr = 0.f, s2r = 0.f;
      #pragma unroll
      for (int nt = 0; nt < 4; ++nt) {
        int gn = w * 64 + nt * 16 + mrow;
        float v = yacc[mi][nt][r] + bv[nt] + bf2f(resb[(size_t)gm * 256 + gn]);
        val[mi][nt][r] = v; sr += v; s2r += v * v;
      }
      sr += __shfl_xor(sr, 1); s2r += __shfl_xor(s2r, 1);
      sr += __shfl_xor(sr, 2); s2r += __shfl_xor(s2r, 2);
      sr += __shfl_xor(sr, 4); s2r += __shfl_xor(s2r, 4);
      sr += __shfl_xor(sr, 8); s2r += __shfl_xor(s2r, 8);
      if (mrow == 0) {
        int lrow = mi * 16 + quad * 4 + r;
        sred[lrow * 8 + w * 2 + 0] = sr; sred[lrow * 8 + w * 2 + 1] = s2r;
      }
    }
  }
  __syncthreads();
  #pragma unroll
  for (int mi = 0; mi < 2; ++mi) {
    #pragma unroll
    for (int r = 0; r < 4; ++r) {
      int lrow = mi * 16 + quad * 4 + r;
      float S  = sred[lrow * 8 + 0] + sred[lrow * 8 + 2] + sred[lrow * 8 + 4] + sred[lrow * 8 + 6];
      float S2 = sred[lrow * 8 + 1] + sred[lrow * 8 + 3] + sred[lrow * 8 + 5] + sred[lrow * 8 + 7];
      float mean = S * (1.f / 256.f);
      float var = S2 * (1.f / 256.f) - mean * mean;
      float inv = rsqrtf(var + 1e-5f);
      float sr2 = 0.f, s2r2 = 0.f;
      #pragma unroll
      for (int nt = 0; nt < 4; ++nt) {
        int gn = w * 64 + nt * 16 + mrow;
        float y = (val[mi][nt][r] - mean) * inv * gam[gn] + bet[gn];
        val[mi][nt][r] = y;
        if constexpr (DLN) { sr2 += y; s2r2 += y * y; }
        else out[(size_t)(bm0 + lrow) * 256 + gn] = f2bf(y);
      }
      if constexpr (DLN) {
        sr2 += __shfl_xor(sr2, 1); s2r2 += __shfl_xor(s2r2, 1);
        sr2 += __shfl_xor(sr2, 2); s2r2 += __shfl_xor(s2r2, 2);
        sr2 += __shfl_xor(sr2, 4); s2r2 += __shfl_xor(s2r2, 4);
        sr2 += __shfl_xor(sr2, 8); s2r2 += __shfl_xor(s2r2, 8);
        if (mrow == 0) {
          sred2[lrow * 8 + w * 2 + 0] = sr2; sred2[lrow * 8 + w * 2 + 1] = s2r2;
        }
      }
    }
  }
  if constexpr (DLN) {
    __syncthreads();
    #pragma unroll
    for (int mi = 0; mi < 2; ++mi) {
      #pragma unroll
      for (int r = 0; r < 4; ++r) {
        int lrow = mi * 16 + quad * 4 + r;
        float S  = sred2[lrow * 8 + 0] + sred2[lrow * 8 + 2] + sred2[lrow * 8 + 4] + sred2[lrow * 8 + 6];
        float S2 = sred2[lrow * 8 + 1] + sred2[lrow * 8 + 3] + sred2[lrow * 8 + 5] + sred2[lrow * 8 + 7];
        float mean = S * (1.f / 256.f);
        float var = S2 * (1.f / 256.f) - mean * mean;
        float inv = rsqrtf(var + 1e-5f);
        #pragma unroll
        for (int nt = 0; nt < 4; ++nt) {
          int gn = w * 64 + nt * 16 + mrow;
          float z = (val[mi][nt][r] - mean) * inv * gam2[gn] + bet2[gn];
          out[(size_t)(bm0 + lrow) * 256 + gn] = f2bf(z);
        }
      }
    }
  }
}

// ---- MFMA GEMM 128x128, optional split-K via blockIdx.z (z>1: raw f32 partials out) -------
//      flags: 1=gelu, 2=f32 out, 4=pq-broadcast res
__global__ __launch_bounds__(256) void gemm128_kernel(
    const u16* __restrict__ A, const u16* __restrict__ W, const float* __restrict__ bias,
    const float* __restrict__ res, void* __restrict__ out,
    int M, int N, int K, int flags)
{
  __shared__ __align__(16) u16 As[128 * 64];
  __shared__ __align__(16) u16 Bs[128 * 64];
  int t = threadIdx.x;
  int lane = t & 63, w = t >> 6;
  int wm = w & 1, wn = w >> 1;
  int bn0 = blockIdx.x * 128, bm0 = blockIdx.y * 128;
  int mrow = lane & 15, quad = lane >> 4;
  int z = blockIdx.z, NZ = gridDim.z;
  int Kc = K / NZ, kbase = z * Kc;

  const u16* gA[4]; const u16* gB[4];
  u16* lA[4]; u16* lB[4];
  #pragma unroll
  for (int it = 0; it < 4; ++it) {
    int c = w * 256 + it * 64 + lane;
    int r = c >> 3;
    int gc = (c & 7) ^ (r & 7);
    gA[it] = A + (size_t)(bm0 + r) * K + kbase + gc * 8;
    gB[it] = W + (size_t)(bn0 + r) * K + kbase + gc * 8;
    lA[it] = As + (w * 256 + it * 64) * 8;
    lB[it] = Bs + (w * 256 + it * 64) * 8;
  }
  floatx4 acc[4][4];
  #pragma unroll
  for (int i = 0; i < 4; ++i)
    #pragma unroll
    for (int j = 0; j < 4; ++j)
      acc[i][j] = (floatx4){0.f, 0.f, 0.f, 0.f};
  int sw0 = ((0 * 4 + quad) ^ (mrow & 7)) * 8;
  int sw1 = ((1 * 4 + quad) ^ (mrow & 7)) * 8;

  for (int k0 = 0; k0 < Kc; k0 += 64) {
    __syncthreads();
    #pragma unroll
    for (int it = 0; it < 4; ++it) { gload_lds16(gA[it], lA[it]); gA[it] += 64; }
    #pragma unroll
    for (int it = 0; it < 4; ++it) { gload_lds16(gB[it], lB[it]); gB[it] += 64; }
    __syncthreads();
    #pragma unroll
    for (int ks = 0; ks < 2; ++ks) {
      int sw = ks ? sw1 : sw0;
      short8 af[4], bfr[4];
      #pragma unroll
      for (int mi = 0; mi < 4; ++mi)
        af[mi] = *(const short8*)&As[(wm * 64 + mi * 16 + mrow) * 64 + sw];
      #pragma unroll
      for (int nj = 0; nj < 4; ++nj)
        bfr[nj] = *(const short8*)&Bs[(wn * 64 + nj * 16 + mrow) * 64 + sw];
      #pragma unroll
      for (int mi = 0; mi < 4; ++mi)
        #pragma unroll
        for (int nj = 0; nj < 4; ++nj)
          acc[mi][nj] = __builtin_amdgcn_mfma_f32_16x16x32_bf16(af[mi], bfr[nj], acc[mi][nj], 0, 0, 0);
    }
  }
  if (NZ > 1) {
    // raw partial accumulators -> f32 buffer at out + z*M*N
    float* po = (float*)out + (size_t)z * M * N;
    #pragma unroll
    for (int nj = 0; nj < 4; ++nj) {
      int gn = bn0 + wn * 64 + nj * 16 + mrow;
      #pragma unroll
      for (int mi = 0; mi < 4; ++mi)
        #pragma unroll
        for (int r = 0; r < 4; ++r) {
          int gm = bm0 + wm * 64 + mi * 16 + quad * 4 + r;
          po[(size_t)gm * N + gn] = acc[mi][nj][r];
        }
    }
    return;
  }
  bool do_gelu = (flags & 1) != 0, of32 = (flags & 2) != 0;
  #pragma unroll
  for (int nj = 0; nj < 4; ++nj) {
    int gn = bn0 + wn * 64 + nj * 16 + mrow;
    float bv = bias ? bias[gn] : 0.f;
    #pragma unroll
    for (int mi = 0; mi < 4; ++mi) {
      #pragma unroll
      for (int r = 0; r < 4; ++r) {
        int gm = bm0 + wm * 64 + mi * 16 + quad * 4 + r;
        float v = acc[mi][nj][r] + bv;
        if (do_gelu) v = 0.5f * v * (1.f + erff(v * 0.70710678118654752f));
        if (flags & 4) v += res[(size_t)(gm & 15) * N + gn];
        else if (res) v += res[(size_t)gm * N + gn];
        if (of32) ((float*)out)[(size_t)gm * N + gn] = v;
        else      ((u16*)out)[(size_t)gm * N + gn] = f2bf(v);
      }
    }
  }
}

// ---------------- LayerNorm: one wave per row, 4 rows/block (final output) ----------------
template<int D>
__global__ __launch_bounds__(256) void lnw_kernel(
    const float* __restrict__ in, const float* __restrict__ w, const float* __restrict__ b,
    float* __restrict__ outf, u16* __restrict__ outb)
{
  constexpr int NV = D / 64;
  int lane = threadIdx.x & 63, wv = threadIdx.x >> 6;
  int row = blockIdx.x * 4 + wv;
  const float* xr = in + (size_t)row * D;
  float v[NV];
  float s = 0.f, s2 = 0.f;
  #pragma unroll
  for (int i = 0; i < NV; ++i) {
    v[i] = xr[lane + i * 64];
    s += v[i]; s2 += v[i] * v[i];
  }
  #pragma unroll
  for (int off = 32; off > 0; off >>= 1) { s += __shfl_xor(s, off); s2 += __shfl_xor(s2, off); }
  float mean = s / (float)D;
  float var = s2 / (float)D - mean * mean;
  float inv = rsqrtf(var + 1e-5f);
  #pragma unroll
  for (int i = 0; i < NV; ++i) {
    int col = lane + i * 64;
    float y = (v[i] - mean) * inv * w[col] + b[col];
    size_t o = (size_t)row * D + col;
    if (outf) outf[o] = y;
    if (outb) outb[o] = f2bf(y);
  }
}

// ---------------- encoder self-attention v6: enc5 body (28KB LDS, 5 blocks/CU) with
//                  XCD-affine 1D grid: the 4 qt-blocks of each (b,h) land on one XCD L2 ------
__global__ __launch_bounds__(256, 5) void attn_enc6_kernel(
    const u16* __restrict__ qkv, u16* __restrict__ out)
{
  __shared__ __align__(16) u16 Ks[64 * 40];       // 5120 B
  __shared__ __align__(16) u16 Vt[32 * 72];       // 4608 B
  __shared__ __align__(16) u16 Pl[4 * 32 * 72];   // 18432 B  (total 28160 -> 5 blocks/CU)
  int F = blockIdx.x;
  int xcd = F & 7, jj = F >> 3;
  int pair = xcd * 32 + (jj >> 2), qt = jj & 3;
  int b = pair >> 3, h = pair & 7;
  int t = threadIdx.x, lane = t & 63, w = t >> 6;
  int mrow = lane & 15, quad = lane >> 4;
  int q0 = qt * 128 + w * 32;
  short8 qf[2];
  #pragma unroll
  for (int mi = 0; mi < 2; ++mi)
    qf[mi] = *(const short8*)(qkv + (size_t)(b * CC + q0 + mi * 16 + mrow) * 768 + h * 32 + quad * 8);
  floatx4 o[2][2];
  #pragma unroll
  for (int mi = 0; mi < 2; ++mi)
    #pragma unroll
    for (int di = 0; di < 2; ++di) o[mi][di] = (floatx4){0.f, 0.f, 0.f, 0.f};
  float lst[2][4] = {{0.f,0.f,0.f,0.f},{0.f,0.f,0.f,0.f}};
  const float sc = 0.17677669529663687f * 1.4426950408889634f;
  const floatx4 zf = (floatx4){0.f, 0.f, 0.f, 0.f};
  for (int jt = 0; jt < 8; ++jt) {
    if (jt) __syncthreads();
    {  // K tile: 64 j x 32 d (one u16x8 per thread)
      int j = t >> 2, q4 = (t & 3) * 8;
      uint4 kk = *(const uint4*)(qkv + (size_t)(b * CC + jt * 64 + j) * 768 + 256 + h * 32 + q4);
      *(uint4*)&Ks[j * 40 + q4] = kk;
      // V tile: transpose+permute into Vt[d][jp], jp=(j&15)*4+(j>>4)
      uint4 vv = *(const uint4*)(qkv + (size_t)(b * CC + jt * 64 + j) * 768 + 512 + h * 32 + q4);
      u16 tmp[8]; *(uint4*)tmp = vv;
      int jp = (j & 15) * 4 + (j >> 4);
      #pragma unroll
      for (int i = 0; i < 8; ++i) Vt[(q4 + i) * 72 + jp] = tmp[i];
    }
    __syncthreads();
    floatx4 s[2][4];
    #pragma unroll
    for (int nj = 0; nj < 4; ++nj) {
      short8 bf = *(const short8*)&Ks[(nj * 16 + mrow) * 40 + quad * 8];
      s[0][nj] = __builtin_amdgcn_mfma_f32_16x16x32_bf16(qf[0], bf, zf, 0, 0, 0);
      s[1][nj] = __builtin_amdgcn_mfma_f32_16x16x32_bf16(qf[1], bf, zf, 0, 0, 0);
    }
    #pragma unroll
    for (int mi = 0; mi < 2; ++mi) {
      #pragma unroll
      for (int r = 0; r < 4; ++r) {
        float ps = 0.f; u16 hv[4];
        #pragma unroll
        for (int nj = 0; nj < 4; ++nj) {
          float p = exp2f(s[mi][nj][r] * sc);
          ps += p; hv[nj] = f2bf(p);
        }
        lst[mi][r] += ps;
        *(uint2*)&Pl[(w * 32 + mi * 16 + quad * 4 + r) * 72 + mrow * 4] = *(uint2*)hv;
      }
    }
    #pragma unroll
    for (int ks = 0; ks < 2; ++ks) {
      short8 a0 = *(const short8*)&Pl[(w * 32 + mrow) * 72 + ks * 32 + quad * 8];
      short8 a1 = *(const short8*)&Pl[(w * 32 + 16 + mrow) * 72 + ks * 32 + quad * 8];
      short8 b0 = *(const short8*)&Vt[mrow * 72 + ks * 32 + quad * 8];
      short8 b1 = *(const short8*)&Vt[(16 + mrow) * 72 + ks * 32 + quad * 8];
      o[0][0] = __builtin_amdgcn_mfma_f32_16x16x32_bf16(a0, b0, o[0][0], 0, 0, 0);
      o[0][1] = __builtin_amdgcn_mfma_f32_16x16x32_bf16(a0, b1, o[0][1], 0, 0, 0);
      o[1][0] = __builtin_amdgcn_mfma_f32_16x16x32_bf16(a1, b0, o[1][0], 0, 0, 0);
      o[1][1] = __builtin_amdgcn_mfma_f32_16x16x32_bf16(a1, b1, o[1][1], 0, 0, 0);
    }
  }
  #pragma unroll
  for (int mi = 0; mi < 2; ++mi) {
    #pragma unroll
    for (int r = 0; r < 4; ++r) {
      float l = lst[mi][r];
      l += __shfl_xor(l, 1); l += __shfl_xor(l, 2);
      l += __shfl_xor(l, 4); l += __shfl_xor(l, 8);
      float inv = 1.f / l;
      int row = b * CC + q0 + mi * 16 + quad * 4 + r;
      #pragma unroll
      for (int di = 0; di < 2; ++di)
        out[(size_t)row * DD + h * 32 + di * 16 + mrow] = f2bf(o[mi][di][r] * inv);
    }
  }
}

// ---------------- fused prefix cross-attention: K/V projections folded through the
//  attention contractions (S = Qc·tln, T = P·tln, O = (T/l)·Wcv^T + bv).
//  Grid is (b, h) so XCD = b&7: each XCD L2 holds 4 tln batches (1MB) reused by 8 heads. ----
__global__ __launch_bounds__(256) void attn_preff_kernel(
    const u16* __restrict__ tln, const u16* __restrict__ wcb,
    const u16* __restrict__ qcg, const float* __restrict__ bkv,
    u16* __restrict__ out)
{
  __shared__ __align__(16) u16 Ajc[64 * 264];   // tln tile [j][c]      33792 B
  __shared__ __align__(16) u16 Acj[256 * 72];   // tln^T tile [c][j]    36864 B
  __shared__ __align__(16) u16 Qs[16 * 264];    // Qc_h [q][c]           8448 B
  __shared__ __align__(16) u16 Ps[16 * 72];     // P tile [q][j]         2304 B
  __shared__ __align__(16) u16 Ts[16 * 264];    // T/l [q][c]            8448 B
  __shared__ float Lred[4][16];
  int b = blockIdx.x, h = blockIdx.y;
  int t = threadIdx.x, lane = t & 63, w = t >> 6;
  int mrow = lane & 15, quad = lane >> 4;
  const float sc = 0.08838834764831845f * 1.4426950408889634f;
  const floatx4 zf = (floatx4){0.f, 0.f, 0.f, 0.f};
  {  // stage Qc_h: 16 x 256, thread t -> row t>>4, 16 cols
    int q = t >> 4, c0 = (t & 15) * 16;
    *(uint4*)&Qs[q * 264 + c0]     = *(const uint4*)(qcg + ((size_t)h * 16 + q) * 256 + c0);
    *(uint4*)&Qs[q * 264 + c0 + 8] = *(const uint4*)(qcg + ((size_t)h * 16 + q) * 256 + c0 + 8);
  }
  floatx4 Tacc[4] = {zf, zf, zf, zf};   // T[q][c], warp owns c in [w*64, w*64+64)
  float lacc = 0.f;
  const u16* tb = tln + (size_t)b * 512 * 256;
  for (int jt = 0; jt < 8; ++jt) {
    __syncthreads();   // WAR vs prev tile's reads; covers Qs staging on iter 0
    {  // stage tln tile [64 j][256 c] both orientations; thread: row j=t>>2, cols (t&3)*64..+64
      int j = t >> 2, c0 = (t & 3) * 64;
      #pragma unroll
      for (int u = 0; u < 8; ++u) {
        uint4 v = *(const uint4*)(tb + (size_t)(jt * 64 + j) * 256 + c0 + u * 8);
        *(uint4*)&Ajc[j * 264 + c0 + u * 8] = v;
        u16 tmp[8]; *(uint4*)tmp = v;
        #pragma unroll
        for (int i = 0; i < 8; ++i) Acj[(c0 + u * 8 + i) * 72 + j] = tmp[i];
      }
    }
    __syncthreads();
    // S^T[j,q]: warp w handles j in [w*16, w*16+16); K = 256 c
    floatx4 s = zf;
    #pragma unroll
    for (int kk = 0; kk < 8; ++kk) {
      short8 af = *(const short8*)&Ajc[(w * 16 + mrow) * 264 + kk * 32 + quad * 8];
      short8 bf = *(const short8*)&Qs[mrow * 264 + kk * 32 + quad * 8];
      s = __builtin_amdgcn_mfma_f32_16x16x32_bf16(af, bf, s, 0, 0, 0);
    }
    // lane holds s[r] for j = w*16 + quad*4 + r, q = mrow
    u16 hv[4]; float ps = 0.f;
    #pragma unroll
    for (int r = 0; r < 4; ++r) {
      float p = exp2f(s[r] * sc);
      ps += p; hv[r] = f2bf(p);
    }
    ps += __shfl_xor(ps, 16); ps += __shfl_xor(ps, 32);  // sum over warp's 16 j (per q=mrow)
    lacc += ps;
    *(uint2*)&Ps[mrow * 72 + w * 16 + quad * 4] = *(uint2*)hv;
    __syncthreads();
    // T += P @ tln_tile: warp w owns c-tiles [w*64..); K = 64 j
    #pragma unroll
    for (int kk = 0; kk < 2; ++kk) {
      short8 af = *(const short8*)&Ps[mrow * 72 + kk * 32 + quad * 8];
      #pragma unroll
      for (int ct = 0; ct < 4; ++ct) {
        short8 bf = *(const short8*)&Acj[(w * 64 + ct * 16 + mrow) * 72 + kk * 32 + quad * 8];
        Tacc[ct] = __builtin_amdgcn_mfma_f32_16x16x32_bf16(af, bf, Tacc[ct], 0, 0, 0);
      }
    }
  }
  if (lane < 16) Lred[w][lane] = lacc;   // lacc valid for q = mrow = lane
  __syncthreads();
  // normalize T, write Ts[q][c] (lane: q = quad*4+r, c = w*64 + ct*16 + mrow)
  #pragma unroll
  for (int r = 0; r < 4; ++r) {
    int q = quad * 4 + r;
    float l = Lred[0][q] + Lred[1][q] + Lred[2][q] + Lred[3][q];
    float inv = 1.f / l;
    #pragma unroll
    for (int ct = 0; ct < 4; ++ct)
      Ts[q * 264 + w * 64 + ct * 16 + mrow] = f2bf(Tacc[ct][r] * inv);
  }
  __syncthreads();
  // O = Ts @ Wcv_h^T + bv: warp w owns d-tiles [w*32, w*32+32); K = 256 c
  const u16* wv = wcb + (size_t)(1024 + h * 128) * 256;
  floatx4 oacc[2] = {zf, zf};
  #pragma unroll
  for (int kk = 0; kk < 8; ++kk) {
    short8 af = *(const short8*)&Ts[mrow * 264 + kk * 32 + quad * 8];
    #pragma unroll
    for (int dt = 0; dt < 2; ++dt) {
      short8 bf = *(const short8*)(wv + (size_t)(w * 32 + dt * 16 + mrow) * 256 + kk * 32 + quad * 8);
      oacc[dt] = __builtin_amdgcn_mfma_f32_16x16x32_bf16(af, bf, oacc[dt], 0, 0, 0);
    }
  }
  #pragma unroll
  for (int dt = 0; dt < 2; ++dt) {
    int d = w * 32 + dt * 16 + mrow;
    float bv = bkv[1024 + h * 128 + d];
    #pragma unroll
    for (int r = 0; r < 4; ++r) {
      int q = quad * 4 + r;
      out[((size_t)(b * 16 + q)) * 1024 + h * 128 + d] = f2bf(oacc[dt][r] + bv);
    }
  }
}

extern "C" void kernel_launch(void* const* d_in, const int* in_sizes, int n_in,
                              void* d_out, int out_size, void* d_ws, size_t ws_size,
                              hipStream_t stream)
{
  const int* vi = (const int*)d_in[0];
  const int* si = (const int*)d_in[1];
  const int* mk = (const int*)d_in[2];
  const float* ve   = (const float*)d_in[3];
  const float* se   = (const float*)d_in[4];
  const float* lpe  = (const float*)d_in[5];
  const float* cpe  = (const float*)d_in[6];
  const float* eiw  = (const float*)d_in[7];
  const float* eib  = (const float*)d_in[8];
  const float* eow  = (const float*)d_in[9];
  const float* eob  = (const float*)d_in[10];
  const float* f1w  = (const float*)d_in[11];
  const float* f1b  = (const float*)d_in[12];
  const float* f2w  = (const float*)d_in[13];
  const float* f2b  = (const float*)d_in[14];
  const float* n1w  = (const float*)d_in[15];
  const float* n1b  = (const float*)d_in[16];
  const float* n2w  = (const float*)d_in[17];
  const float* n2b  = (const float*)d_in[18];
  const float* tlw  = (const float*)d_in[19];
  const float* tlb  = (const float*)d_in[20];
  const float* thw  = (const float*)d_in[21];
  const float* thb  = (const float*)d_in[22];
  const float* pq   = (const float*)d_in[23];
  const float* paiw = (const float*)d_in[24];
  const float* paib = (const float*)d_in[25];
  const float* paow = (const float*)d_in[26];
  const float* paob = (const float*)d_in[27];
  const float* pnw  = (const float*)d_in[28];
  const float* pnb  = (const float*)d_in[29];

  const int NROW = BB * CC;  // 16384
  const size_t MB = 1048576;
  char* base = (char*)d_ws;
  // encoder phase:
  u16* xb   = (u16*)(base);                // [0,8M)   bf16 residual stream (post-LN)
  u16* qkvb = (u16*)(base + 8 * MB);       // [8M,32M)
  u16* atto = (u16*)(base + 32 * MB);      // [32M,40M)
  u16* tln  = (u16*)(base + 96 * MB);      // [96M,104M)
  // folded-weight region [64M,70M):
  u16* wcb   = (u16*)(base + 64 * MB);     // [64M,65M)  Wc = Wkv @ th_w, bf16 [2048,256]
  u16* thwTb = (u16*)(base + 65 * MB);     // [65M,65.5M) th_w^T bf16 [256,1024]
  float* bkv = (float*)(base + 66 * MB);   // [66M,66M+8K) folded KV bias fp32 [2048]
  u16* wckT  = (u16*)(base + 67 * MB);     // [67M,67.5M) Wck^T bf16 [256,1024]
  u16* qcg   = (u16*)(base + 68 * MB);     // [68M,+64K)  Qc bf16 [8][16][256]
  float* skpart = (float*)(base + 80 * MB);// [80M,88M) split-K f32 partials
  u16* wbf  = (u16*)(base + 104 * MB);     // [104M,~119M)
  u16* qh    = (u16*)(base + 120 * MB);    // [120M,+256K) qh scratch (rows 16..127 garbage)
  u16* prefo = (u16*)(base + 121 * MB);    // [121M,+1M)
  float* prefout = (float*)(base + 122 * MB);

  u16* eiw_b  = wbf + 0;
  u16* eow_b  = wbf + 786432;
  u16* f1w_b  = wbf + 1048576;
  u16* f2w_b  = wbf + 2097152;
  u16* thw_b  = wbf + 3145728;
  u16* paiw_b = wbf + 3407872;
  u16* paow_b = wbf + 6553600;
  u16* pqb    = wbf + 7602176;
  u16* veb    = wbf + 7618560;
  u16* seb    = wbf + 7749888;
  u16* lpeb   = wbf + 7750656;
  u16* cpeb   = wbf + 7754752;

  dim3 blk(256);
  cvt_kernel<<<7701, blk, 0, stream>>>(eiw, eow, f1w, f2w, thw, paiw, paow, pq,
                                       ve, se, lpe, cpe, wbf);
  // weight fold: Wc[n,d] = sum_h Wkv[n,h]*th_w[h,d]; bkv[n] = Wkv[n,:]·th_b + pa_in_b[1024+n]
  thwT_kernel<<<256, blk, 0, stream>>>(thw, thwTb);
  biasfold_kernel<<<512, blk, 0, stream>>>(paiw_b + (size_t)HH * HH, thb, paib, bkv);
  gemm128_kernel<<<dim3(2, 16, 4), blk, 0, stream>>>(
      paiw_b + (size_t)HH * HH, thwTb, nullptr, nullptr, skpart, 2048, 256, HH, 0);
  redk_kernel<<<512, blk, 0, stream>>>(skpart, nullptr, nullptr, nullptr, wcb,
                                       256, 4, 2048 * 256, 0);
  // qh = pq @ Wq^T via split-K (latency-bound tail fix)
  gemm128_kernel<<<dim3(8, 1, 8), blk, 0, stream>>>(
      pqb, paiw_b, nullptr, nullptr, skpart, 128, 1024, HH, 0);
  redk_kernel<<<128, blk, 0, stream>>>(skpart, paib, nullptr, nullptr, qh,
                                       1024, 8, 128 * 1024, 0);
  bT_kernel<<<256, blk, 0, stream>>>(wcb, wckT);
  qc_kernel<<<8, blk, 0, stream>>>(qh, wckT, qcg);
  embed_kernel<<<NROW/2, blk, 0, stream>>>(vi, si, mk, veb, seb, lpeb, cpeb, xb);
  for (int i = 0; i < NLAY; ++i) {
    gwide_kernel<384, false, false, false><<<dim3(2, NROW/32), blk, 0, stream>>>(
        xb, eiw_b + (size_t)i*768*DD, eib + i*768, nullptr, nullptr, nullptr, nullptr, nullptr,
        qkvb, 768, DD);
    attn_enc6_kernel<<<1024, blk, 0, stream>>>(qkvb, atto);
    gwide_kernel<256, false, true, false><<<dim3(1, NROW/32), blk, 0, stream>>>(
        atto, eow_b + (size_t)i*DD*DD, eob + i*DD, xb, n1w + i*DD, n1b + i*DD, nullptr, nullptr,
        xb, DD, DD);
    // fused FF1+gelu+FF2+res+LN (32 rows, 52KB LDS, 2 blocks/CU)
    if (i < NLAY - 1) {
      ffu_kernel<false><<<NROW/32, blk, 0, stream>>>(
          xb, f1w_b + (size_t)i*HH*DD, f1b + i*HH, f2w_b + (size_t)i*DD*HH, f2b + i*DD,
          xb, n2w + i*DD, n2b + i*DD, nullptr, nullptr, xb);
    } else {
      ffu_kernel<true><<<NROW/32, blk, 0, stream>>>(
          xb, f1w_b + (size_t)i*HH*DD, f1b + i*HH, f2w_b + (size_t)i*DD*HH, f2b + i*DD,
          xb, n2w + i*DD, n2b + i*DD, tlw, tlb, tln);
    }
  }
  // fused prefix cross-attention (b-major grid: XCD = b&7, tln L2-resident per XCD)
  attn_preff_kernel<<<dim3(BB, 8), blk, 0, stream>>>(tln, wcb, qcg, bkv, prefo);
  // split-K out-proj
  gemm128_kernel<<<dim3(1024/128, (BB*PP)/128, 4), blk, 0, stream>>>(
      prefo, paow_b, nullptr, nullptr, skpart, BB*PP, HH, HH, 0);
  redk_kernel<<<512, blk, 0, stream>>>(skpart, paob, pq, prefout, nullptr,
                                       1024, 4, BB*PP*HH, 4);
  lnw_kernel<1024><<<(BB*PP)/4, blk, 0, stream>>>(prefout, pnw, pnb, (float*)d_out, nullptr);
}

// Round 13
// 659.080 us; speedup vs baseline: 1.2860x; 1.0894x over previous
//
#include <hip/hip_runtime.h>
#include <hip/hip_bf16.h>

typedef unsigned short u16;
typedef unsigned int u32;
typedef __attribute__((ext_vector_type(8))) short short8;
typedef __attribute__((ext_vector_type(4))) float floatx4;

#define BB 32
#define CC 512
#define LL 16
#define DD 256
#define HH 1024
#define PP 16
#define NLAY 4

__device__ __forceinline__ float bf2f(u16 u) {
  u32 x = ((u32)u) << 16; float f; __builtin_memcpy(&f, &x, 4); return f;
}
__device__ __forceinline__ u16 f2bf(float f) {
  __hip_bfloat16 h = __float2bfloat16(f);
  u16 r; __builtin_memcpy(&r, &h, 2); return r;
}
__device__ __forceinline__ void gload_lds16(const u16* g, u16* l) {
  __builtin_amdgcn_global_load_lds(
      (const __attribute__((address_space(1))) void*)g,
      (__attribute__((address_space(3))) void*)l, 16, 0, 0);
}

// ---------------- fp32 -> bf16 conversion: 8 weight tensors + 4 embedding tables ----------------
__global__ __launch_bounds__(256) void cvt_kernel(
    const float* __restrict__ s0, const float* __restrict__ s1,
    const float* __restrict__ s2, const float* __restrict__ s3,
    const float* __restrict__ s4, const float* __restrict__ s5,
    const float* __restrict__ s6, const float* __restrict__ s7,
    const float* __restrict__ s8, const float* __restrict__ s9,
    const float* __restrict__ s10, const float* __restrict__ s11,
    u16* __restrict__ dst)
{
  const float* srcs[12] = {s0, s1, s2, s3, s4, s5, s6, s7, s8, s9, s10, s11};
  const int pfx[12] = {786432, 1048576, 2097152, 3145728, 3407872, 6553600, 7602176,
                       7618560, 7749888, 7750656, 7754752, 7885824};
  int e = (blockIdx.x * 256 + threadIdx.x) * 4;
  int seg = 0;
  while (e >= pfx[seg]) seg++;
  int start = seg ? pfx[seg - 1] : 0;
  float4 f = *(const float4*)(srcs[seg] + (e - start));
  u16 o[4] = {f2bf(f.x), f2bf(f.y), f2bf(f.z), f2bf(f.w)};
  *(uint2*)(dst + e) = *(const uint2*)o;
}

// ---------------- th_w [1024,256] fp32 -> bf16 transposed [256,1024] (K-major for fold GEMM) ---
__global__ __launch_bounds__(256) void thwT_kernel(
    const float* __restrict__ thw, u16* __restrict__ out)
{
  __shared__ float tile[32][33];
  int bx = blockIdx.x & 7, by = blockIdx.x >> 3;   // bx: d-tile (8), by: h-tile (32)
  int tx = threadIdx.x & 31, ty = threadIdx.x >> 5;
  #pragma unroll
  for (int i = 0; i < 4; ++i) {
    int h = by * 32 + ty + i * 8, d = bx * 32 + tx;
    tile[ty + i * 8][tx] = thw[h * 256 + d];
  }
  __syncthreads();
  #pragma unroll
  for (int i = 0; i < 4; ++i) {
    int d = bx * 32 + ty + i * 8, h = by * 32 + tx;
    out[d * 1024 + h] = f2bf(tile[tx][ty + i * 8]);
  }
}

// ---------------- bf16 transpose [1024,256] -> [256,1024] (Wck^T for Qc fold) ----------------
__global__ __launch_bounds__(256) void bT_kernel(
    const u16* __restrict__ in, u16* __restrict__ out)
{
  __shared__ u16 tile[32][33];
  int bx = blockIdx.x & 7, by = blockIdx.x >> 3;   // bx: c-tile (8), by: hd-tile (32)
  int tx = threadIdx.x & 31, ty = threadIdx.x >> 5;
  #pragma unroll
  for (int i = 0; i < 4; ++i) {
    int hd = by * 32 + ty + i * 8, c = bx * 32 + tx;
    tile[ty + i * 8][tx] = in[hd * 256 + c];
  }
  __syncthreads();
  #pragma unroll
  for (int i = 0; i < 4; ++i) {
    int c = bx * 32 + ty + i * 8, hd = by * 32 + tx;
    out[c * 1024 + hd] = tile[tx][ty + i * 8];
  }
}

// ---------------- Qc fold: Qc[h][q][c] = sum_d qh[q, h*128+d] * Wck[h*128+d, c] ------------
__global__ __launch_bounds__(256) void qc_kernel(
    const u16* __restrict__ qh, const u16* __restrict__ wckT, u16* __restrict__ qcg)
{
  int h = blockIdx.x;
  int t = threadIdx.x, lane = t & 63, w = t >> 6;
  int mrow = lane & 15, quad = lane >> 4;
  const floatx4 zf = (floatx4){0.f, 0.f, 0.f, 0.f};
  floatx4 acc[4] = {zf, zf, zf, zf};
  #pragma unroll
  for (int kk = 0; kk < 4; ++kk) {
    short8 af = *(const short8*)(qh + (size_t)mrow * 1024 + h * 128 + kk * 32 + quad * 8);
    #pragma unroll
    for (int ct = 0; ct < 4; ++ct) {
      int c = w * 64 + ct * 16 + mrow;
      short8 bf = *(const short8*)(wckT + (size_t)c * 1024 + h * 128 + kk * 32 + quad * 8);
      acc[ct] = __builtin_amdgcn_mfma_f32_16x16x32_bf16(af, bf, acc[ct], 0, 0, 0);
    }
  }
  #pragma unroll
  for (int ct = 0; ct < 4; ++ct)
    #pragma unroll
    for (int r = 0; r < 4; ++r)
      qcg[((size_t)h * 16 + quad * 4 + r) * 256 + w * 64 + ct * 16 + mrow] = f2bf(acc[ct][r]);
}

// ---------------- folded KV bias: bkv[n] = Wkv[n,:]·th_b + pa_in_b[1024+n], one wave/row ------
__global__ __launch_bounds__(256) void biasfold_kernel(
    const u16* __restrict__ Wkv, const float* __restrict__ thb,
    const float* __restrict__ paib, float* __restrict__ out)
{
  int wv = threadIdx.x >> 6, lane = threadIdx.x & 63;
  int n = blockIdx.x * 4 + wv;
  const u16* wr = Wkv + (size_t)n * 1024;
  float s = 0.f;
  #pragma unroll
  for (int i = 0; i < 16; ++i) {
    int h = i * 64 + lane;
    s += bf2f(wr[h]) * thb[h];
  }
  #pragma unroll
  for (int off = 32; off; off >>= 1) s += __shfl_xor(s, off);
  if (!lane) out[n] = s + paib[1024 + n];
}

// ---------------- split-K reduce: sum nz f32 partials + bias/res, write f32 or bf16 ----------
__global__ __launch_bounds__(256) void redk_kernel(
    const float* __restrict__ part, const float* __restrict__ bias,
    const float* __restrict__ res, float* __restrict__ outf, u16* __restrict__ outb,
    int N, int nz, int total, int flags)   // flags&4: res row index is (row&15)
{
  int idx = (blockIdx.x * 256 + threadIdx.x) * 4;
  if (idx >= total) return;
  float4 a = *(const float4*)(part + idx);
  for (int z = 1; z < nz; ++z) {
    float4 b = *(const float4*)(part + (size_t)z * total + idx);
    a.x += b.x; a.y += b.y; a.z += b.z; a.w += b.w;
  }
  int row = idx / N, col = idx - row * N;   // 4 consecutive cols, same row (N % 4 == 0)
  float v4[4] = {a.x, a.y, a.z, a.w};
  #pragma unroll
  for (int i = 0; i < 4; ++i) {
    if (bias) v4[i] += bias[col + i];
    if (res) v4[i] += res[(size_t)((flags & 4) ? (row & 15) : row) * N + col + i];
  }
  if (outf) {
    *(float4*)(outf + idx) = *(const float4*)v4;
  } else {
    u16 o[4] = {f2bf(v4[0]), f2bf(v4[1]), f2bf(v4[2]), f2bf(v4[3])};
    *(uint2*)(outb + idx) = *(const uint2*)o;
  }
}

// ---------------- embed + masked mean pool (bf16 tables, 2 clauses/block, u32 loads) --------
__global__ __launch_bounds__(256) void embed_kernel(
    const int* __restrict__ vi, const int* __restrict__ si, const int* __restrict__ mk,
    const u16* __restrict__ veb, const u16* __restrict__ seb,
    const u16* __restrict__ lpeb, const u16* __restrict__ cpeb,
    u16* __restrict__ xb)
{
  int t = threadIdx.x;
  int bc = blockIdx.x * 2 + (t >> 7);
  int c = bc & (CC - 1);
  int dl = (t & 127) * 2;
  int base = bc * LL;
  float a0 = 0.f, a1 = 0.f; int cnt = 0;
  #pragma unroll
  for (int l = 0; l < LL; ++l) {
    if (mk[base + l]) {
      int v = vi[base + l], s = si[base + l];
      u32 vv = *(const u32*)&veb[v * DD + dl];
      u32 sv = *(const u32*)&seb[s * DD + dl];
      u32 lv = *(const u32*)&lpeb[l * DD + dl];
      a0 += bf2f((u16)vv) + bf2f((u16)sv) + bf2f((u16)lv);
      a1 += bf2f((u16)(vv >> 16)) + bf2f((u16)(sv >> 16)) + bf2f((u16)(lv >> 16));
      cnt++;
    }
  }
  u32 cv = *(const u32*)&cpeb[c * DD + dl];
  float inv = 1.f / (float)cnt;
  u32 pk = (u32)f2bf(a0 * inv + bf2f((u16)cv)) | ((u32)f2bf(a1 * inv + bf2f((u16)(cv >> 16))) << 16);
  *(u32*)&xb[(size_t)bc * DD + dl] = pk;
}

// ---------------- wide-N GEMM 32 rows (v2 warp mapping; QKV and attn-out-LN call-sites) ----
template<int NC, bool GELU, bool LN, bool DLN>
__global__ __launch_bounds__(256) void gwide_kernel(
    const u16* __restrict__ A, const u16* __restrict__ W, const float* __restrict__ bias,
    const u16* __restrict__ resb, const float* __restrict__ gam, const float* __restrict__ bet,
    const float* __restrict__ gam2, const float* __restrict__ bet2,
    u16* __restrict__ out, int N, int K)
{
  constexpr int NT = NC / 32;    // staging tile count
  constexpr int NT4 = NC / 64;   // col tiles per warp
  __shared__ __align__(16) u16 As[32 * 64];
  __shared__ __align__(16) u16 Ws[NC * 64];
  __shared__ float sred[32][4][2];
  __shared__ float sred2[32][4][2];
  int t = threadIdx.x, lane = t & 63, w = t >> 6;
  int mrow = lane & 15, quad = lane >> 4;
  int bn0 = blockIdx.x * NC, bm0 = blockIdx.y * 32;

  int rA = t >> 3, gcA = (t & 7) ^ (rA & 7);
  const u16* gAp = A + (size_t)(bm0 + rA) * K + gcA * 8;
  u16* lAp = As + (w * 64) * 8;
  const u16* gW0 = W + (size_t)(bn0 + rA) * K + gcA * 8;
  u16* lW0 = Ws + (w * 64) * 8;

  floatx4 acc[2][NT4];
  #pragma unroll
  for (int mi = 0; mi < 2; ++mi)
    #pragma unroll
    for (int nt = 0; nt < NT4; ++nt) acc[mi][nt] = (floatx4){0.f, 0.f, 0.f, 0.f};

  for (int k0 = 0; k0 < K; k0 += 64) {
    __syncthreads();
    gload_lds16(gAp, lAp); gAp += 64;
    #pragma unroll
    for (int i = 0; i < NT; ++i)
      gload_lds16(gW0 + (size_t)i * 32 * K, lW0 + i * 2048);
    gW0 += 64;
    __syncthreads();
    #pragma unroll
    for (int ks = 0; ks < 2; ++ks) {
      int sw = ((ks * 4 + quad) ^ (mrow & 7)) * 8;
      short8 af0 = *(const short8*)&As[mrow * 64 + sw];
      short8 af1 = *(const short8*)&As[(16 + mrow) * 64 + sw];
      #pragma unroll
      for (int nt = 0; nt < NT4; ++nt) {
        int rw = w * (NC / 4) + nt * 16 + mrow;
        short8 bf = *(const short8*)&Ws[rw * 64 + sw];
        acc[0][nt] = __builtin_amdgcn_mfma_f32_16x16x32_bf16(af0, bf, acc[0][nt], 0, 0, 0);
        acc[1][nt] = __builtin_amdgcn_mfma_f32_16x16x32_bf16(af1, bf, acc[1][nt], 0, 0, 0);
      }
    }
  }

  if constexpr (LN) {
    float val[2][NT4][4];
    float bv[NT4];
    #pragma unroll
    for (int nt = 0; nt < NT4; ++nt) bv[nt] = bias[w * 64 + nt * 16 + mrow];
    #pragma unroll
    for (int mi = 0; mi < 2; ++mi) {
      #pragma unroll
      for (int r = 0; r < 4; ++r) {
        int gm = bm0 + mi * 16 + quad * 4 + r;
        float sr = 0.f, s2r = 0.f;
        #pragma unroll
        for (int nt = 0; nt < NT4; ++nt) {
          int gn = w * 64 + nt * 16 + mrow;
          float v = acc[mi][nt][r] + bv[nt] + bf2f(resb[(size_t)gm * 256 + gn]);
          val[mi][nt][r] = v; sr += v; s2r += v * v;
        }
        sr += __shfl_xor(sr, 1); s2r += __shfl_xor(s2r, 1);
        sr += __shfl_xor(sr, 2); s2r += __shfl_xor(s2r, 2);
        sr += __shfl_xor(sr, 4); s2r += __shfl_xor(s2r, 4);
        sr += __shfl_xor(sr, 8); s2r += __shfl_xor(s2r, 8);
        if (mrow == 0) { sred[mi * 16 + quad * 4 + r][w][0] = sr; sred[mi * 16 + quad * 4 + r][w][1] = s2r; }
      }
    }
    __syncthreads();
    #pragma unroll
    for (int mi = 0; mi < 2; ++mi) {
      #pragma unroll
      for (int r = 0; r < 4; ++r) {
        int lrow = mi * 16 + quad * 4 + r;
        float S  = sred[lrow][0][0] + sred[lrow][1][0] + sred[lrow][2][0] + sred[lrow][3][0];
        float S2 = sred[lrow][0][1] + sred[lrow][1][1] + sred[lrow][2][1] + sred[lrow][3][1];
        float mean = S * (1.f / 256.f);
        float var = S2 * (1.f / 256.f) - mean * mean;
        float inv = rsqrtf(var + 1e-5f);
        float sr2 = 0.f, s2r2 = 0.f;
        #pragma unroll
        for (int nt = 0; nt < NT4; ++nt) {
          int gn = w * 64 + nt * 16 + mrow;
          float y = (val[mi][nt][r] - mean) * inv * gam[gn] + bet[gn];
          val[mi][nt][r] = y;
          if constexpr (DLN) { sr2 += y; s2r2 += y * y; }
          else out[(size_t)(bm0 + lrow) * 256 + gn] = f2bf(y);
        }
        if constexpr (DLN) {
          sr2 += __shfl_xor(sr2, 1); s2r2 += __shfl_xor(s2r2, 1);
          sr2 += __shfl_xor(sr2, 2); s2r2 += __shfl_xor(s2r2, 2);
          sr2 += __shfl_xor(sr2, 4); s2r2 += __shfl_xor(s2r2, 4);
          sr2 += __shfl_xor(sr2, 8); s2r2 += __shfl_xor(s2r2, 8);
          if (mrow == 0) { sred2[lrow][w][0] = sr2; sred2[lrow][w][1] = s2r2; }
        }
      }
    }
    if constexpr (DLN) {
      __syncthreads();
      #pragma unroll
      for (int mi = 0; mi < 2; ++mi) {
        #pragma unroll
        for (int r = 0; r < 4; ++r) {
          int lrow = mi * 16 + quad * 4 + r;
          float S  = sred2[lrow][0][0] + sred2[lrow][1][0] + sred2[lrow][2][0] + sred2[lrow][3][0];
          float S2 = sred2[lrow][0][1] + sred2[lrow][1][1] + sred2[lrow][2][1] + sred2[lrow][3][1];
          float mean = S * (1.f / 256.f);
          float var = S2 * (1.f / 256.f) - mean * mean;
          float inv = rsqrtf(var + 1e-5f);
          #pragma unroll
          for (int nt = 0; nt < NT4; ++nt) {
            int gn = w * 64 + nt * 16 + mrow;
            float z = (val[mi][nt][r] - mean) * inv * gam2[gn] + bet2[gn];
            out[(size_t)(bm0 + lrow) * 256 + gn] = f2bf(z);
          }
        }
      }
    }
  } else {
    #pragma unroll
    for (int nt = 0; nt < NT4; ++nt) {
      int gn = bn0 + w * (NC / 4) + nt * 16 + mrow;
      float bv = bias[gn];
      #pragma unroll
      for (int mi = 0; mi < 2; ++mi) {
        #pragma unroll
        for (int r = 0; r < 4; ++r) {
          int gm = bm0 + mi * 16 + quad * 4 + r;
          float v = acc[mi][nt][r] + bv;
          if (GELU) v = 0.5f * v * (1.f + erff(v * 0.70710678118654752f));
          out[(size_t)gm * N + gn] = f2bf(v);
        }
      }
    }
  }
}

// ---------------- fused FFN: y = LN(res + b2 + gelu(x@W1^T + b1)@W2^T) per 32 rows --------
//  h never leaves LDS: per 256-col quarter, FF1 -> gelu -> Hs (As-format) -> FF2 partial.
//  LDS 52KB -> 2 blocks/CU (the latency-hiding mechanism: co-resident block covers drains).
template<bool DLN>
__global__ __launch_bounds__(256) void ffu_kernel(
    const u16* __restrict__ A, const u16* __restrict__ W1, const float* __restrict__ b1,
    const u16* __restrict__ W2, const float* __restrict__ b2,
    const u16* __restrict__ resb,
    const float* __restrict__ gam, const float* __restrict__ bet,
    const float* __restrict__ gam2, const float* __restrict__ bet2,
    u16* __restrict__ out)
{
  __shared__ __align__(16) u16 As[2048];       // 4 KB: x k-step tile
  __shared__ __align__(16) u16 Ws[8 * 2048];   // 32 KB: W1-quarter / W2-slice staging
  __shared__ __align__(16) u16 Hs[4 * 2048];   // 16 KB: gelu(h) quarter, As-format (4 k-tiles)
  int t = threadIdx.x, lane = t & 63, w = t >> 6;
  int mrow = lane & 15, quad = lane >> 4;
  int bm0 = blockIdx.x * 32;
  int rA = t >> 3, gcA = (t & 7) ^ (rA & 7);

  floatx4 yacc[2][4];
  #pragma unroll
  for (int mi = 0; mi < 2; ++mi)
    #pragma unroll
    for (int nt = 0; nt < 4; ++nt) yacc[mi][nt] = (floatx4){0.f, 0.f, 0.f, 0.f};

  for (int nq = 0; nq < 4; ++nq) {
    floatx4 hacc[2][4];
    #pragma unroll
    for (int mi = 0; mi < 2; ++mi)
      #pragma unroll
      for (int nt = 0; nt < 4; ++nt) hacc[mi][nt] = (floatx4){0.f, 0.f, 0.f, 0.f};
    // FF1: h[:, nq*256 .. +256) = x @ W1_q^T  (K = 256, 4 k-steps)
    for (int kt = 0; kt < 4; ++kt) {
      __syncthreads();
      gload_lds16(A + (size_t)(bm0 + rA) * 256 + kt * 64 + gcA * 8, As + (w * 64) * 8);
      #pragma unroll
      for (int i = 0; i < 8; ++i)
        gload_lds16(W1 + (size_t)(nq * 256 + i * 32 + rA) * 256 + kt * 64 + gcA * 8,
                    Ws + i * 2048 + (w * 64) * 8);
      __syncthreads();
      #pragma unroll
      for (int ks = 0; ks < 2; ++ks) {
        int sw = ((ks * 4 + quad) ^ (mrow & 7)) * 8;
        short8 af0 = *(const short8*)&As[mrow * 64 + sw];
        short8 af1 = *(const short8*)&As[(16 + mrow) * 64 + sw];
        #pragma unroll
        for (int nt = 0; nt < 4; ++nt) {
          short8 bf = *(const short8*)&Ws[(w * 64 + nt * 16 + mrow) * 64 + sw];
          hacc[0][nt] = __builtin_amdgcn_mfma_f32_16x16x32_bf16(af0, bf, hacc[0][nt], 0, 0, 0);
          hacc[1][nt] = __builtin_amdgcn_mfma_f32_16x16x32_bf16(af1, bf, hacc[1][nt], 0, 0, 0);
        }
      }
    }
    // gelu + bias1, write quarter into Hs in As-format. Warp w's 64 cols = quarter-local
    // k-tile w. For value at (row, cc): group g = cc>>3, slot = g ^ (row&7), pos = cc&7.
    {
      float bv1[4];
      #pragma unroll
      for (int nt = 0; nt < 4; ++nt) bv1[nt] = b1[nq * 256 + w * 64 + nt * 16 + mrow];
      #pragma unroll
      for (int mi = 0; mi < 2; ++mi) {
        #pragma unroll
        for (int nt = 0; nt < 4; ++nt) {
          int g = nt * 2 + (mrow >> 3);
          #pragma unroll
          for (int r = 0; r < 4; ++r) {
            int row = mi * 16 + quad * 4 + r;
            float v = hacc[mi][nt][r] + bv1[nt];
            v = 0.5f * v * (1.f + erff(v * 0.70710678118654752f));
            Hs[w * 2048 + row * 64 + (g ^ (row & 7)) * 8 + (mrow & 7)] = f2bf(v);
          }
        }
      }
    }
    // FF2 partial: yacc += gelu_h_q @ W2[:, nq*256 .. +256)^T  (4 k-steps, A local in Hs)
    for (int kt2 = 0; kt2 < 4; ++kt2) {
      __syncthreads();   // covers Hs writes (iter 0) + Ws WAR
      #pragma unroll
      for (int i = 0; i < 8; ++i)
        gload_lds16(W2 + (size_t)(i * 32 + rA) * 1024 + nq * 256 + kt2 * 64 + gcA * 8,
                    Ws + i * 2048 + (w * 64) * 8);
      __syncthreads();
      #pragma unroll
      for (int ks = 0; ks < 2; ++ks) {
        int sw = ((ks * 4 + quad) ^ (mrow & 7)) * 8;
        short8 af0 = *(const short8*)&Hs[kt2 * 2048 + mrow * 64 + sw];
        short8 af1 = *(const short8*)&Hs[kt2 * 2048 + (16 + mrow) * 64 + sw];
        #pragma unroll
        for (int nt = 0; nt < 4; ++nt) {
          short8 bf = *(const short8*)&Ws[(w * 64 + nt * 16 + mrow) * 64 + sw];
          yacc[0][nt] = __builtin_amdgcn_mfma_f32_16x16x32_bf16(af0, bf, yacc[0][nt], 0, 0, 0);
          yacc[1][nt] = __builtin_amdgcn_mfma_f32_16x16x32_bf16(af1, bf, yacc[1][nt], 0, 0, 0);
        }
      }
    }
  }
  // epilogue: residual + LN (+DLN). sred aliased into Hs (dead; guarded by barrier).
  __syncthreads();
  float* sred  = (float*)Hs;            // [32][4][2]
  float* sred2 = (float*)(Hs + 2048);   // [32][4][2]
  float val[2][4][4];
  float bv[4];
  #pragma unroll
  for (int nt = 0; nt < 4; ++nt) bv[nt] = b2[w * 64 + nt * 16 + mrow];
  #pragma unroll
  for (int mi = 0; mi < 2; ++mi) {
    #pragma unroll
    for (int r = 0; r < 4; ++r) {
      int gm = bm0 + mi * 16 + quad * 4 + r;
      float sr = 0.f, s2r = 0.f;
      #pragma unroll
      for (int nt = 0; nt < 4; ++nt) {
        int gn = w * 64 + nt * 16 + mrow;
        float v = yacc[mi][nt][r] + bv[nt] + bf2f(resb[(size_t)gm * 256 + gn]);
        val[mi][nt][r] = v; sr += v; s2r += v * v;
      }
      sr += __shfl_xor(sr, 1); s2r += __shfl_xor(s2r, 1);
      sr += __shfl_xor(sr, 2); s2r += __shfl_xor(s2r, 2);
      sr += __shfl_xor(sr, 4); s2r += __shfl_xor(s2r, 4);
      sr += __shfl_xor(sr, 8); s2r += __shfl_xor(s2r, 8);
      if (mrow == 0) {
        int lrow = mi * 16 + quad * 4 + r;
        sred[lrow * 8 + w * 2 + 0] = sr; sred[lrow * 8 + w * 2 + 1] = s2r;
      }
    }
  }
  __syncthreads();
  #pragma unroll
  for (int mi = 0; mi < 2; ++mi) {
    #pragma unroll
    for (int r = 0; r < 4; ++r) {
      int lrow = mi * 16 + quad * 4 + r;
      float S  = sred[lrow * 8 + 0] + sred[lrow * 8 + 2] + sred[lrow * 8 + 4] + sred[lrow * 8 + 6];
      float S2 = sred[lrow * 8 + 1] + sred[lrow * 8 + 3] + sred[lrow * 8 + 5] + sred[lrow * 8 + 7];
      float mean = S * (1.f / 256.f);
      float var = S2 * (1.f / 256.f) - mean * mean;
      float inv = rsqrtf(var + 1e-5f);
      float sr2 = 0.f, s2r2 = 0.f;
      #pragma unroll
      for (int nt = 0; nt < 4; ++nt) {
        int gn = w * 64 + nt * 16 + mrow;
        float y = (val[mi][nt][r] - mean) * inv * gam[gn] + bet[gn];
        val[mi][nt][r] = y;
        if constexpr (DLN) { sr2 += y; s2r2 += y * y; }
        else out[(size_t)(bm0 + lrow) * 256 + gn] = f2bf(y);
      }
      if constexpr (DLN) {
        sr2 += __shfl_xor(sr2, 1); s2r2 += __shfl_xor(s2r2, 1);
        sr2 += __shfl_xor(sr2, 2); s2r2 += __shfl_xor(s2r2, 2);
        sr2 += __shfl_xor(sr2, 4); s2r2 += __shfl_xor(s2r2, 4);
        sr2 += __shfl_xor(sr2, 8); s2r2 += __shfl_xor(s2r2, 8);
        if (mrow == 0) {
          sred2[lrow * 8 + w * 2 + 0] = sr2; sred2[lrow * 8 + w * 2 + 1] = s2r2;
        }
      }
    }
  }
  if constexpr (DLN) {
    __syncthreads();
    #pragma unroll
    for (int mi = 0; mi < 2; ++mi) {
      #pragma unroll
      for (int r = 0; r < 4; ++r) {
        int lrow = mi * 16 + quad * 4 + r;
        float S  = sred2[lrow * 8 + 0] + sred2[lrow * 8 + 2] + sred2[lrow * 8 + 4] + sred2[lrow * 8 + 6];
        float S2 = sred2[lrow * 8 + 1] + sred2[lrow * 8 + 3] + sred2[lrow * 8 + 5] + sred2[lrow * 8 + 7];
        float mean = S * (1.f / 256.f);
        float var = S2 * (1.f / 256.f) - mean * mean;
        float inv = rsqrtf(var + 1e-5f);
        #pragma unroll
        for (int nt = 0; nt < 4; ++nt) {
          int gn = w * 64 + nt * 16 + mrow;
          float z = (val[mi][nt][r] - mean) * inv * gam2[gn] + bet2[gn];
          out[(size_t)(bm0 + lrow) * 256 + gn] = f2bf(z);
        }
      }
    }
  }
}

// ---- MFMA GEMM 128x128, optional split-K via blockIdx.z (z>1: raw f32 partials out) -------
//      flags: 1=gelu, 2=f32 out, 4=pq-broadcast res
__global__ __launch_bounds__(256) void gemm128_kernel(
    const u16* __restrict__ A, const u16* __restrict__ W, const float* __restrict__ bias,
    const float* __restrict__ res, void* __restrict__ out,
    int M, int N, int K, int flags)
{
  __shared__ __align__(16) u16 As[128 * 64];
  __shared__ __align__(16) u16 Bs[128 * 64];
  int t = threadIdx.x;
  int lane = t & 63, w = t >> 6;
  int wm = w & 1, wn = w >> 1;
  int bn0 = blockIdx.x * 128, bm0 = blockIdx.y * 128;
  int mrow = lane & 15, quad = lane >> 4;
  int z = blockIdx.z, NZ = gridDim.z;
  int Kc = K / NZ, kbase = z * Kc;

  const u16* gA[4]; const u16* gB[4];
  u16* lA[4]; u16* lB[4];
  #pragma unroll
  for (int it = 0; it < 4; ++it) {
    int c = w * 256 + it * 64 + lane;
    int r = c >> 3;
    int gc = (c & 7) ^ (r & 7);
    gA[it] = A + (size_t)(bm0 + r) * K + kbase + gc * 8;
    gB[it] = W + (size_t)(bn0 + r) * K + kbase + gc * 8;
    lA[it] = As + (w * 256 + it * 64) * 8;
    lB[it] = Bs + (w * 256 + it * 64) * 8;
  }
  floatx4 acc[4][4];
  #pragma unroll
  for (int i = 0; i < 4; ++i)
    #pragma unroll
    for (int j = 0; j < 4; ++j)
      acc[i][j] = (floatx4){0.f, 0.f, 0.f, 0.f};
  int sw0 = ((0 * 4 + quad) ^ (mrow & 7)) * 8;
  int sw1 = ((1 * 4 + quad) ^ (mrow & 7)) * 8;

  for (int k0 = 0; k0 < Kc; k0 += 64) {
    __syncthreads();
    #pragma unroll
    for (int it = 0; it < 4; ++it) { gload_lds16(gA[it], lA[it]); gA[it] += 64; }
    #pragma unroll
    for (int it = 0; it < 4; ++it) { gload_lds16(gB[it], lB[it]); gB[it] += 64; }
    __syncthreads();
    #pragma unroll
    for (int ks = 0; ks < 2; ++ks) {
      int sw = ks ? sw1 : sw0;
      short8 af[4], bfr[4];
      #pragma unroll
      for (int mi = 0; mi < 4; ++mi)
        af[mi] = *(const short8*)&As[(wm * 64 + mi * 16 + mrow) * 64 + sw];
      #pragma unroll
      for (int nj = 0; nj < 4; ++nj)
        bfr[nj] = *(const short8*)&Bs[(wn * 64 + nj * 16 + mrow) * 64 + sw];
      #pragma unroll
      for (int mi = 0; mi < 4; ++mi)
        #pragma unroll
        for (int nj = 0; nj < 4; ++nj)
          acc[mi][nj] = __builtin_amdgcn_mfma_f32_16x16x32_bf16(af[mi], bfr[nj], acc[mi][nj], 0, 0, 0);
    }
  }
  if (NZ > 1) {
    // raw partial accumulators -> f32 buffer at out + z*M*N
    float* po = (float*)out + (size_t)z * M * N;
    #pragma unroll
    for (int nj = 0; nj < 4; ++nj) {
      int gn = bn0 + wn * 64 + nj * 16 + mrow;
      #pragma unroll
      for (int mi = 0; mi < 4; ++mi)
        #pragma unroll
        for (int r = 0; r < 4; ++r) {
          int gm = bm0 + wm * 64 + mi * 16 + quad * 4 + r;
          po[(size_t)gm * N + gn] = acc[mi][nj][r];
        }
    }
    return;
  }
  bool do_gelu = (flags & 1) != 0, of32 = (flags & 2) != 0;
  #pragma unroll
  for (int nj = 0; nj < 4; ++nj) {
    int gn = bn0 + wn * 64 + nj * 16 + mrow;
    float bv = bias ? bias[gn] : 0.f;
    #pragma unroll
    for (int mi = 0; mi < 4; ++mi) {
      #pragma unroll
      for (int r = 0; r < 4; ++r) {
        int gm = bm0 + wm * 64 + mi * 16 + quad * 4 + r;
        float v = acc[mi][nj][r] + bv;
        if (do_gelu) v = 0.5f * v * (1.f + erff(v * 0.70710678118654752f));
        if (flags & 4) v += res[(size_t)(gm & 15) * N + gn];
        else if (res) v += res[(size_t)gm * N + gn];
        if (of32) ((float*)out)[(size_t)gm * N + gn] = v;
        else      ((u16*)out)[(size_t)gm * N + gn] = f2bf(v);
      }
    }
  }
}

// ---------------- LayerNorm: one wave per row, 4 rows/block (final output) ----------------
template<int D>
__global__ __launch_bounds__(256) void lnw_kernel(
    const float* __restrict__ in, const float* __restrict__ w, const float* __restrict__ b,
    float* __restrict__ outf, u16* __restrict__ outb)
{
  constexpr int NV = D / 64;
  int lane = threadIdx.x & 63, wv = threadIdx.x >> 6;
  int row = blockIdx.x * 4 + wv;
  const float* xr = in + (size_t)row * D;
  float v[NV];
  float s = 0.f, s2 = 0.f;
  #pragma unroll
  for (int i = 0; i < NV; ++i) {
    v[i] = xr[lane + i * 64];
    s += v[i]; s2 += v[i] * v[i];
  }
  #pragma unroll
  for (int off = 32; off > 0; off >>= 1) { s += __shfl_xor(s, off); s2 += __shfl_xor(s2, off); }
  float mean = s / (float)D;
  float var = s2 / (float)D - mean * mean;
  float inv = rsqrtf(var + 1e-5f);
  #pragma unroll
  for (int i = 0; i < NV; ++i) {
    int col = lane + i * 64;
    float y = (v[i] - mean) * inv * w[col] + b[col];
    size_t o = (size_t)row * D + col;
    if (outf) outf[o] = y;
    if (outb) outb[o] = f2bf(y);
  }
}

// ---------------- encoder self-attention v6: enc5 body (28KB LDS, 5 blocks/CU) with
//                  XCD-affine 1D grid: the 4 qt-blocks of each (b,h) land on one XCD L2 ------
__global__ __launch_bounds__(256, 5) void attn_enc6_kernel(
    const u16* __restrict__ qkv, u16* __restrict__ out)
{
  __shared__ __align__(16) u16 Ks[64 * 40];       // 5120 B
  __shared__ __align__(16) u16 Vt[32 * 72];       // 4608 B
  __shared__ __align__(16) u16 Pl[4 * 32 * 72];   // 18432 B  (total 28160 -> 5 blocks/CU)
  int F = blockIdx.x;
  int xcd = F & 7, jj = F >> 3;
  int pair = xcd * 32 + (jj >> 2), qt = jj & 3;
  int b = pair >> 3, h = pair & 7;
  int t = threadIdx.x, lane = t & 63, w = t >> 6;
  int mrow = lane & 15, quad = lane >> 4;
  int q0 = qt * 128 + w * 32;
  short8 qf[2];
  #pragma unroll
  for (int mi = 0; mi < 2; ++mi)
    qf[mi] = *(const short8*)(qkv + (size_t)(b * CC + q0 + mi * 16 + mrow) * 768 + h * 32 + quad * 8);
  floatx4 o[2][2];
  #pragma unroll
  for (int mi = 0; mi < 2; ++mi)
    #pragma unroll
    for (int di = 0; di < 2; ++di) o[mi][di] = (floatx4){0.f, 0.f, 0.f, 0.f};
  float lst[2][4] = {{0.f,0.f,0.f,0.f},{0.f,0.f,0.f,0.f}};
  const float sc = 0.17677669529663687f * 1.4426950408889634f;
  const floatx4 zf = (floatx4){0.f, 0.f, 0.f, 0.f};
  for (int jt = 0; jt < 8; ++jt) {
    if (jt) __syncthreads();
    {  // K tile: 64 j x 32 d (one u16x8 per thread)
      int j = t >> 2, q4 = (t & 3) * 8;
      uint4 kk = *(const uint4*)(qkv + (size_t)(b * CC + jt * 64 + j) * 768 + 256 + h * 32 + q4);
      *(uint4*)&Ks[j * 40 + q4] = kk;
      // V tile: transpose+permute into Vt[d][jp], jp=(j&15)*4+(j>>4)
      uint4 vv = *(const uint4*)(qkv + (size_t)(b * CC + jt * 64 + j) * 768 + 512 + h * 32 + q4);
      u16 tmp[8]; *(uint4*)tmp = vv;
      int jp = (j & 15) * 4 + (j >> 4);
      #pragma unroll
      for (int i = 0; i < 8; ++i) Vt[(q4 + i) * 72 + jp] = tmp[i];
    }
    __syncthreads();
    floatx4 s[2][4];
    #pragma unroll
    for (int nj = 0; nj < 4; ++nj) {
      short8 bf = *(const short8*)&Ks[(nj * 16 + mrow) * 40 + quad * 8];
      s[0][nj] = __builtin_amdgcn_mfma_f32_16x16x32_bf16(qf[0], bf, zf, 0, 0, 0);
      s[1][nj] = __builtin_amdgcn_mfma_f32_16x16x32_bf16(qf[1], bf, zf, 0, 0, 0);
    }
    #pragma unroll
    for (int mi = 0; mi < 2; ++mi) {
      #pragma unroll
      for (int r = 0; r < 4; ++r) {
        float ps = 0.f; u16 hv[4];
        #pragma unroll
        for (int nj = 0; nj < 4; ++nj) {
          float p = exp2f(s[mi][nj][r] * sc);
          ps += p; hv[nj] = f2bf(p);
        }
        lst[mi][r] += ps;
        *(uint2*)&Pl[(w * 32 + mi * 16 + quad * 4 + r) * 72 + mrow * 4] = *(uint2*)hv;
      }
    }
    #pragma unroll
    for (int ks = 0; ks < 2; ++ks) {
      short8 a0 = *(const short8*)&Pl[(w * 32 + mrow) * 72 + ks * 32 + quad * 8];
      short8 a1 = *(const short8*)&Pl[(w * 32 + 16 + mrow) * 72 + ks * 32 + quad * 8];
      short8 b0 = *(const short8*)&Vt[mrow * 72 + ks * 32 + quad * 8];
      short8 b1 = *(const short8*)&Vt[(16 + mrow) * 72 + ks * 32 + quad * 8];
      o[0][0] = __builtin_amdgcn_mfma_f32_16x16x32_bf16(a0, b0, o[0][0], 0, 0, 0);
      o[0][1] = __builtin_amdgcn_mfma_f32_16x16x32_bf16(a0, b1, o[0][1], 0, 0, 0);
      o[1][0] = __builtin_amdgcn_mfma_f32_16x16x32_bf16(a1, b0, o[1][0], 0, 0, 0);
      o[1][1] = __builtin_amdgcn_mfma_f32_16x16x32_bf16(a1, b1, o[1][1], 0, 0, 0);
    }
  }
  #pragma unroll
  for (int mi = 0; mi < 2; ++mi) {
    #pragma unroll
    for (int r = 0; r < 4; ++r) {
      float l = lst[mi][r];
      l += __shfl_xor(l, 1); l += __shfl_xor(l, 2);
      l += __shfl_xor(l, 4); l += __shfl_xor(l, 8);
      float inv = 1.f / l;
      int row = b * CC + q0 + mi * 16 + quad * 4 + r;
      #pragma unroll
      for (int di = 0; di < 2; ++di)
        out[(size_t)row * DD + h * 32 + di * 16 + mrow] = f2bf(o[mi][di][r] * inv);
    }
  }
}

// ---------------- fused prefix cross-attention: K/V projections folded through the
//  attention contractions (S = Qc·tln, T = P·tln, O = (T/l)·Wcv^T + bv).
//  Grid is (b, h) so XCD = b&7: each XCD L2 holds 4 tln batches (1MB) reused by 8 heads. ----
__global__ __launch_bounds__(256) void attn_preff_kernel(
    const u16* __restrict__ tln, const u16* __restrict__ wcb,
    const u16* __restrict__ qcg, const float* __restrict__ bkv,
    u16* __restrict__ out)
{
  __shared__ __align__(16) u16 Ajc[64 * 264];   // tln tile [j][c]      33792 B
  __shared__ __align__(16) u16 Acj[256 * 72];   // tln^T tile [c][j]    36864 B
  __shared__ __align__(16) u16 Qs[16 * 264];    // Qc_h [q][c]           8448 B
  __shared__ __align__(16) u16 Ps[16 * 72];     // P tile [q][j]         2304 B
  __shared__ __align__(16) u16 Ts[16 * 264];    // T/l [q][c]            8448 B
  __shared__ float Lred[4][16];
  int b = blockIdx.x, h = blockIdx.y;
  int t = threadIdx.x, lane = t & 63, w = t >> 6;
  int mrow = lane & 15, quad = lane >> 4;
  const float sc = 0.08838834764831845f * 1.4426950408889634f;
  const floatx4 zf = (floatx4){0.f, 0.f, 0.f, 0.f};
  {  // stage Qc_h: 16 x 256, thread t -> row t>>4, 16 cols
    int q = t >> 4, c0 = (t & 15) * 16;
    *(uint4*)&Qs[q * 264 + c0]     = *(const uint4*)(qcg + ((size_t)h * 16 + q) * 256 + c0);
    *(uint4*)&Qs[q * 264 + c0 + 8] = *(const uint4*)(qcg + ((size_t)h * 16 + q) * 256 + c0 + 8);
  }
  floatx4 Tacc[4] = {zf, zf, zf, zf};   // T[q][c], warp owns c in [w*64, w*64+64)
  float lacc = 0.f;
  const u16* tb = tln + (size_t)b * 512 * 256;
  for (int jt = 0; jt < 8; ++jt) {
    __syncthreads();   // WAR vs prev tile's reads; covers Qs staging on iter 0
    {  // stage tln tile [64 j][256 c] both orientations; thread: row j=t>>2, cols (t&3)*64..+64
      int j = t >> 2, c0 = (t & 3) * 64;
      #pragma unroll
      for (int u = 0; u < 8; ++u) {
        uint4 v = *(const uint4*)(tb + (size_t)(jt * 64 + j) * 256 + c0 + u * 8);
        *(uint4*)&Ajc[j * 264 + c0 + u * 8] = v;
        u16 tmp[8]; *(uint4*)tmp = v;
        #pragma unroll
        for (int i = 0; i < 8; ++i) Acj[(c0 + u * 8 + i) * 72 + j] = tmp[i];
      }
    }
    __syncthreads();
    // S^T[j,q]: warp w handles j in [w*16, w*16+16); K = 256 c
    floatx4 s = zf;
    #pragma unroll
    for (int kk = 0; kk < 8; ++kk) {
      short8 af = *(const short8*)&Ajc[(w * 16 + mrow) * 264 + kk * 32 + quad * 8];
      short8 bf = *(const short8*)&Qs[mrow * 264 + kk * 32 + quad * 8];
      s = __builtin_amdgcn_mfma_f32_16x16x32_bf16(af, bf, s, 0, 0, 0);
    }
    // lane holds s[r] for j = w*16 + quad*4 + r, q = mrow
    u16 hv[4]; float ps = 0.f;
    #pragma unroll
    for (int r = 0; r < 4; ++r) {
      float p = exp2f(s[r] * sc);
      ps += p; hv[r] = f2bf(p);
    }
    ps += __shfl_xor(ps, 16); ps += __shfl_xor(ps, 32);  // sum over warp's 16 j (per q=mrow)
    lacc += ps;
    *(uint2*)&Ps[mrow * 72 + w * 16 + quad * 4] = *(uint2*)hv;
    __syncthreads();
    // T += P @ tln_tile: warp w owns c-tiles [w*64..); K = 64 j
    #pragma unroll
    for (int kk = 0; kk < 2; ++kk) {
      short8 af = *(const short8*)&Ps[mrow * 72 + kk * 32 + quad * 8];
      #pragma unroll
      for (int ct = 0; ct < 4; ++ct) {
        short8 bf = *(const short8*)&Acj[(w * 64 + ct * 16 + mrow) * 72 + kk * 32 + quad * 8];
        Tacc[ct] = __builtin_amdgcn_mfma_f32_16x16x32_bf16(af, bf, Tacc[ct], 0, 0, 0);
      }
    }
  }
  if (lane < 16) Lred[w][lane] = lacc;   // lacc valid for q = mrow = lane
  __syncthreads();
  // normalize T, write Ts[q][c] (lane: q = quad*4+r, c = w*64 + ct*16 + mrow)
  #pragma unroll
  for (int r = 0; r < 4; ++r) {
    int q = quad * 4 + r;
    float l = Lred[0][q] + Lred[1][q] + Lred[2][q] + Lred[3][q];
    float inv = 1.f / l;
    #pragma unroll
    for (int ct = 0; ct < 4; ++ct)
      Ts[q * 264 + w * 64 + ct * 16 + mrow] = f2bf(Tacc[ct][r] * inv);
  }
  __syncthreads();
  // O = Ts @ Wcv_h^T + bv: warp w owns d-tiles [w*32, w*32+32); K = 256 c
  const u16* wv = wcb + (size_t)(1024 + h * 128) * 256;
  floatx4 oacc[2] = {zf, zf};
  #pragma unroll
  for (int kk = 0; kk < 8; ++kk) {
    short8 af = *(const short8*)&Ts[mrow * 264 + kk * 32 + quad * 8];
    #pragma unroll
    for (int dt = 0; dt < 2; ++dt) {
      short8 bf = *(const short8*)(wv + (size_t)(w * 32 + dt * 16 + mrow) * 256 + kk * 32 + quad * 8);
      oacc[dt] = __builtin_amdgcn_mfma_f32_16x16x32_bf16(af, bf, oacc[dt], 0, 0, 0);
    }
  }
  #pragma unroll
  for (int dt = 0; dt < 2; ++dt) {
    int d = w * 32 + dt * 16 + mrow;
    float bv = bkv[1024 + h * 128 + d];
    #pragma unroll
    for (int r = 0; r < 4; ++r) {
      int q = quad * 4 + r;
      out[((size_t)(b * 16 + q)) * 1024 + h * 128 + d] = f2bf(oacc[dt][r] + bv);
    }
  }
}

extern "C" void kernel_launch(void* const* d_in, const int* in_sizes, int n_in,
                              void* d_out, int out_size, void* d_ws, size_t ws_size,
                              hipStream_t stream)
{
  const int* vi = (const int*)d_in[0];
  const int* si = (const int*)d_in[1];
  const int* mk = (const int*)d_in[2];
  const float* ve   = (const float*)d_in[3];
  const float* se   = (const float*)d_in[4];
  const float* lpe  = (const float*)d_in[5];
  const float* cpe  = (const float*)d_in[6];
  const float* eiw  = (const float*)d_in[7];
  const float* eib  = (const float*)d_in[8];
  const float* eow  = (const float*)d_in[9];
  const float* eob  = (const float*)d_in[10];
  const float* f1w  = (const float*)d_in[11];
  const float* f1b  = (const float*)d_in[12];
  const float* f2w  = (const float*)d_in[13];
  const float* f2b  = (const float*)d_in[14];
  const float* n1w  = (const float*)d_in[15];
  const float* n1b  = (const float*)d_in[16];
  const float* n2w  = (const float*)d_in[17];
  const float* n2b  = (const float*)d_in[18];
  const float* tlw  = (const float*)d_in[19];
  const float* tlb  = (const float*)d_in[20];
  const float* thw  = (const float*)d_in[21];
  const float* thb  = (const float*)d_in[22];
  const float* pq   = (const float*)d_in[23];
  const float* paiw = (const float*)d_in[24];
  const float* paib = (const float*)d_in[25];
  const float* paow = (const float*)d_in[26];
  const float* paob = (const float*)d_in[27];
  const float* pnw  = (const float*)d_in[28];
  const float* pnb  = (const float*)d_in[29];

  const int NROW = BB * CC;  // 16384
  const size_t MB = 1048576;
  char* base = (char*)d_ws;
  // encoder phase:
  u16* xb   = (u16*)(base);                // [0,8M)   bf16 residual stream (post-LN)
  u16* qkvb = (u16*)(base + 8 * MB);       // [8M,32M)
  u16* atto = (u16*)(base + 32 * MB);      // [32M,40M)
  u16* tln  = (u16*)(base + 96 * MB);      // [96M,104M)
  // folded-weight region [64M,70M):
  u16* wcb   = (u16*)(base + 64 * MB);     // [64M,65M)  Wc = Wkv @ th_w, bf16 [2048,256]
  u16* thwTb = (u16*)(base + 65 * MB);     // [65M,65.5M) th_w^T bf16 [256,1024]
  float* bkv = (float*)(base + 66 * MB);   // [66M,66M+8K) folded KV bias fp32 [2048]
  u16* wckT  = (u16*)(base + 67 * MB);     // [67M,67.5M) Wck^T bf16 [256,1024]
  u16* qcg   = (u16*)(base + 68 * MB);     // [68M,+64K)  Qc bf16 [8][16][256]
  float* skpart = (float*)(base + 80 * MB);// [80M,88M) split-K f32 partials
  u16* wbf  = (u16*)(base + 104 * MB);     // [104M,~119M)
  u16* qh    = (u16*)(base + 120 * MB);    // [120M,+256K) qh scratch (rows 16..127 garbage)
  u16* prefo = (u16*)(base + 121 * MB);    // [121M,+1M)
  float* prefout = (float*)(base + 122 * MB);

  u16* eiw_b  = wbf + 0;
  u16* eow_b  = wbf + 786432;
  u16* f1w_b  = wbf + 1048576;
  u16* f2w_b  = wbf + 2097152;
  u16* thw_b  = wbf + 3145728;
  u16* paiw_b = wbf + 3407872;
  u16* paow_b = wbf + 6553600;
  u16* pqb    = wbf + 7602176;
  u16* veb    = wbf + 7618560;
  u16* seb    = wbf + 7749888;
  u16* lpeb   = wbf + 7750656;
  u16* cpeb   = wbf + 7754752;

  dim3 blk(256);
  cvt_kernel<<<7701, blk, 0, stream>>>(eiw, eow, f1w, f2w, thw, paiw, paow, pq,
                                       ve, se, lpe, cpe, wbf);
  // weight fold: Wc[n,d] = sum_h Wkv[n,h]*th_w[h,d]; bkv[n] = Wkv[n,:]·th_b + pa_in_b[1024+n]
  thwT_kernel<<<256, blk, 0, stream>>>(thw, thwTb);
  biasfold_kernel<<<512, blk, 0, stream>>>(paiw_b + (size_t)HH * HH, thb, paib, bkv);
  gemm128_kernel<<<dim3(2, 16, 4), blk, 0, stream>>>(
      paiw_b + (size_t)HH * HH, thwTb, nullptr, nullptr, skpart, 2048, 256, HH, 0);
  redk_kernel<<<512, blk, 0, stream>>>(skpart, nullptr, nullptr, nullptr, wcb,
                                       256, 4, 2048 * 256, 0);
  // qh = pq @ Wq^T via split-K (latency-bound tail fix)
  gemm128_kernel<<<dim3(8, 1, 8), blk, 0, stream>>>(
      pqb, paiw_b, nullptr, nullptr, skpart, 128, 1024, HH, 0);
  redk_kernel<<<128, blk, 0, stream>>>(skpart, paib, nullptr, nullptr, qh,
                                       1024, 8, 128 * 1024, 0);
  bT_kernel<<<256, blk, 0, stream>>>(wcb, wckT);
  qc_kernel<<<8, blk, 0, stream>>>(qh, wckT, qcg);
  embed_kernel<<<NROW/2, blk, 0, stream>>>(vi, si, mk, veb, seb, lpeb, cpeb, xb);
  for (int i = 0; i < NLAY; ++i) {
    gwide_kernel<384, false, false, false><<<dim3(2, NROW/32), blk, 0, stream>>>(
        xb, eiw_b + (size_t)i*768*DD, eib + i*768, nullptr, nullptr, nullptr, nullptr, nullptr,
        qkvb, 768, DD);
    attn_enc6_kernel<<<1024, blk, 0, stream>>>(qkvb, atto);
    gwide_kernel<256, false, true, false><<<dim3(1, NROW/32), blk, 0, stream>>>(
        atto, eow_b + (size_t)i*DD*DD, eob + i*DD, xb, n1w + i*DD, n1b + i*DD, nullptr, nullptr,
        xb, DD, DD);
    // fused FF1+gelu+FF2+res+LN (32 rows, 52KB LDS, 2 blocks/CU)
    if (i < NLAY - 1) {
      ffu_kernel<false><<<NROW/32, blk, 0, stream>>>(
          xb, f1w_b + (size_t)i*HH*DD, f1b + i*HH, f2w_b + (size_t)i*DD*HH, f2b + i*DD,
          xb, n2w + i*DD, n2b + i*DD, nullptr, nullptr, xb);
    } else {
      ffu_kernel<true><<<NROW/32, blk, 0, stream>>>(
          xb, f1w_b + (size_t)i*HH*DD, f1b + i*HH, f2w_b + (size_t)i*DD*HH, f2b + i*DD,
          xb, n2w + i*DD, n2b + i*DD, tlw, tlb, tln);
    }
  }
  // fused prefix cross-attention (b-major grid: XCD = b&7, tln L2-resident per XCD)
  attn_preff_kernel<<<dim3(BB, 8), blk, 0, stream>>>(tln, wcb, qcg, bkv, prefo);
  // split-K out-proj
  gemm128_kernel<<<dim3(1024/128, (BB*PP)/128, 4), blk, 0, stream>>>(
      prefo, paow_b, nullptr, nullptr, skpart, BB*PP, HH, HH, 0);
  redk_kernel<<<512, blk, 0, stream>>>(skpart, paob, pq, prefout, nullptr,
                                       1024, 4, BB*PP*HH, 4);
  lnw_kernel<1024><<<(BB*PP)/4, blk, 0, stream>>>(prefout, pnw, pnb, (float*)d_out, nullptr);
}

// Round 14
// 655.361 us; speedup vs baseline: 1.2933x; 1.0057x over previous
//
#include <hip/hip_runtime.h>
#include <hip/hip_bf16.h>

typedef unsigned short u16;
typedef unsigned int u32;
typedef __attribute__((ext_vector_type(8))) short short8;
typedef __attribute__((ext_vector_type(4))) float floatx4;

#define BB 32
#define CC 512
#define LL 16
#define DD 256
#define HH 1024
#define PP 16
#define NLAY 4

__device__ __forceinline__ float bf2f(u16 u) {
  u32 x = ((u32)u) << 16; float f; __builtin_memcpy(&f, &x, 4); return f;
}
__device__ __forceinline__ u16 f2bf(float f) {
  __hip_bfloat16 h = __float2bfloat16(f);
  u16 r; __builtin_memcpy(&r, &h, 2); return r;
}
__device__ __forceinline__ void gload_lds16(const u16* g, u16* l) {
  __builtin_amdgcn_global_load_lds(
      (const __attribute__((address_space(1))) void*)g,
      (__attribute__((address_space(3))) void*)l, 16, 0, 0);
}

// ---------------- fp32 -> bf16 conversion: 8 weight tensors + 4 embedding tables ----------------
__global__ __launch_bounds__(256) void cvt_kernel(
    const float* __restrict__ s0, const float* __restrict__ s1,
    const float* __restrict__ s2, const float* __restrict__ s3,
    const float* __restrict__ s4, const float* __restrict__ s5,
    const float* __restrict__ s6, const float* __restrict__ s7,
    const float* __restrict__ s8, const float* __restrict__ s9,
    const float* __restrict__ s10, const float* __restrict__ s11,
    u16* __restrict__ dst)
{
  const float* srcs[12] = {s0, s1, s2, s3, s4, s5, s6, s7, s8, s9, s10, s11};
  const int pfx[12] = {786432, 1048576, 2097152, 3145728, 3407872, 6553600, 7602176,
                       7618560, 7749888, 7750656, 7754752, 7885824};
  int e = (blockIdx.x * 256 + threadIdx.x) * 4;
  int seg = 0;
  while (e >= pfx[seg]) seg++;
  int start = seg ? pfx[seg - 1] : 0;
  float4 f = *(const float4*)(srcs[seg] + (e - start));
  u16 o[4] = {f2bf(f.x), f2bf(f.y), f2bf(f.z), f2bf(f.w)};
  *(uint2*)(dst + e) = *(const uint2*)o;
}

// ---------------- th_w [1024,256] fp32 -> bf16 transposed [256,1024] (K-major for fold GEMM) ---
__global__ __launch_bounds__(256) void thwT_kernel(
    const float* __restrict__ thw, u16* __restrict__ out)
{
  __shared__ float tile[32][33];
  int bx = blockIdx.x & 7, by = blockIdx.x >> 3;   // bx: d-tile (8), by: h-tile (32)
  int tx = threadIdx.x & 31, ty = threadIdx.x >> 5;
  #pragma unroll
  for (int i = 0; i < 4; ++i) {
    int h = by * 32 + ty + i * 8, d = bx * 32 + tx;
    tile[ty + i * 8][tx] = thw[h * 256 + d];
  }
  __syncthreads();
  #pragma unroll
  for (int i = 0; i < 4; ++i) {
    int d = bx * 32 + ty + i * 8, h = by * 32 + tx;
    out[d * 1024 + h] = f2bf(tile[tx][ty + i * 8]);
  }
}

// ---------------- bf16 transpose [1024,256] -> [256,1024] (Wck^T for Qc fold) ----------------
__global__ __launch_bounds__(256) void bT_kernel(
    const u16* __restrict__ in, u16* __restrict__ out)
{
  __shared__ u16 tile[32][33];
  int bx = blockIdx.x & 7, by = blockIdx.x >> 3;   // bx: c-tile (8), by: hd-tile (32)
  int tx = threadIdx.x & 31, ty = threadIdx.x >> 5;
  #pragma unroll
  for (int i = 0; i < 4; ++i) {
    int hd = by * 32 + ty + i * 8, c = bx * 32 + tx;
    tile[ty + i * 8][tx] = in[hd * 256 + c];
  }
  __syncthreads();
  #pragma unroll
  for (int i = 0; i < 4; ++i) {
    int c = bx * 32 + ty + i * 8, hd = by * 32 + tx;
    out[c * 1024 + hd] = tile[tx][ty + i * 8];
  }
}

// ---------------- Qc fold: Qc[h][q][c] = sum_d qh[q, h*128+d] * Wck[h*128+d, c] ------------
__global__ __launch_bounds__(256) void qc_kernel(
    const u16* __restrict__ qh, const u16* __restrict__ wckT, u16* __restrict__ qcg)
{
  int h = blockIdx.x;
  int t = threadIdx.x, lane = t & 63, w = t >> 6;
  int mrow = lane & 15, quad = lane >> 4;
  const floatx4 zf = (floatx4){0.f, 0.f, 0.f, 0.f};
  floatx4 acc[4] = {zf, zf, zf, zf};
  #pragma unroll
  for (int kk = 0; kk < 4; ++kk) {
    short8 af = *(const short8*)(qh + (size_t)mrow * 1024 + h * 128 + kk * 32 + quad * 8);
    #pragma unroll
    for (int ct = 0; ct < 4; ++ct) {
      int c = w * 64 + ct * 16 + mrow;
      short8 bf = *(const short8*)(wckT + (size_t)c * 1024 + h * 128 + kk * 32 + quad * 8);
      acc[ct] = __builtin_amdgcn_mfma_f32_16x16x32_bf16(af, bf, acc[ct], 0, 0, 0);
    }
  }
  #pragma unroll
  for (int ct = 0; ct < 4; ++ct)
    #pragma unroll
    for (int r = 0; r < 4; ++r)
      qcg[((size_t)h * 16 + quad * 4 + r) * 256 + w * 64 + ct * 16 + mrow] = f2bf(acc[ct][r]);
}

// ---------------- folded KV bias: bkv[n] = Wkv[n,:]·th_b + pa_in_b[1024+n], one wave/row ------
__global__ __launch_bounds__(256) void biasfold_kernel(
    const u16* __restrict__ Wkv, const float* __restrict__ thb,
    const float* __restrict__ paib, float* __restrict__ out)
{
  int wv = threadIdx.x >> 6, lane = threadIdx.x & 63;
  int n = blockIdx.x * 4 + wv;
  const u16* wr = Wkv + (size_t)n * 1024;
  float s = 0.f;
  #pragma unroll
  for (int i = 0; i < 16; ++i) {
    int h = i * 64 + lane;
    s += bf2f(wr[h]) * thb[h];
  }
  #pragma unroll
  for (int off = 32; off; off >>= 1) s += __shfl_xor(s, off);
  if (!lane) out[n] = s + paib[1024 + n];
}

// ---------------- split-K reduce: sum nz f32 partials + bias/res, write f32 or bf16 ----------
__global__ __launch_bounds__(256) void redk_kernel(
    const float* __restrict__ part, const float* __restrict__ bias,
    const float* __restrict__ res, float* __restrict__ outf, u16* __restrict__ outb,
    int N, int nz, int total, int flags)   // flags&4: res row index is (row&15)
{
  int idx = (blockIdx.x * 256 + threadIdx.x) * 4;
  if (idx >= total) return;
  float4 a = *(const float4*)(part + idx);
  for (int z = 1; z < nz; ++z) {
    float4 b = *(const float4*)(part + (size_t)z * total + idx);
    a.x += b.x; a.y += b.y; a.z += b.z; a.w += b.w;
  }
  int row = idx / N, col = idx - row * N;   // 4 consecutive cols, same row (N % 4 == 0)
  float v4[4] = {a.x, a.y, a.z, a.w};
  #pragma unroll
  for (int i = 0; i < 4; ++i) {
    if (bias) v4[i] += bias[col + i];
    if (res) v4[i] += res[(size_t)((flags & 4) ? (row & 15) : row) * N + col + i];
  }
  if (outf) {
    *(float4*)(outf + idx) = *(const float4*)v4;
  } else {
    u16 o[4] = {f2bf(v4[0]), f2bf(v4[1]), f2bf(v4[2]), f2bf(v4[3])};
    *(uint2*)(outb + idx) = *(const uint2*)o;
  }
}

// ---------------- embed + masked mean pool (bf16 tables, 2 clauses/block, u32 loads) --------
__global__ __launch_bounds__(256) void embed_kernel(
    const int* __restrict__ vi, const int* __restrict__ si, const int* __restrict__ mk,
    const u16* __restrict__ veb, const u16* __restrict__ seb,
    const u16* __restrict__ lpeb, const u16* __restrict__ cpeb,
    u16* __restrict__ xb)
{
  int t = threadIdx.x;
  int bc = blockIdx.x * 2 + (t >> 7);
  int c = bc & (CC - 1);
  int dl = (t & 127) * 2;
  int base = bc * LL;
  float a0 = 0.f, a1 = 0.f; int cnt = 0;
  #pragma unroll
  for (int l = 0; l < LL; ++l) {
    if (mk[base + l]) {
      int v = vi[base + l], s = si[base + l];
      u32 vv = *(const u32*)&veb[v * DD + dl];
      u32 sv = *(const u32*)&seb[s * DD + dl];
      u32 lv = *(const u32*)&lpeb[l * DD + dl];
      a0 += bf2f((u16)vv) + bf2f((u16)sv) + bf2f((u16)lv);
      a1 += bf2f((u16)(vv >> 16)) + bf2f((u16)(sv >> 16)) + bf2f((u16)(lv >> 16));
      cnt++;
    }
  }
  u32 cv = *(const u32*)&cpeb[c * DD + dl];
  float inv = 1.f / (float)cnt;
  u32 pk = (u32)f2bf(a0 * inv + bf2f((u16)cv)) | ((u32)f2bf(a1 * inv + bf2f((u16)(cv >> 16))) << 16);
  *(u32*)&xb[(size_t)bc * DD + dl] = pk;
}

// ---------------- wide-N GEMM 32 rows (v2 warp mapping; QKV and attn-out-LN call-sites) ----
template<int NC, bool GELU, bool LN, bool DLN>
__global__ __launch_bounds__(256) void gwide_kernel(
    const u16* __restrict__ A, const u16* __restrict__ W, const float* __restrict__ bias,
    const u16* __restrict__ resb, const float* __restrict__ gam, const float* __restrict__ bet,
    const float* __restrict__ gam2, const float* __restrict__ bet2,
    u16* __restrict__ out, int N, int K)
{
  constexpr int NT = NC / 32;    // staging tile count
  constexpr int NT4 = NC / 64;   // col tiles per warp
  __shared__ __align__(16) u16 As[32 * 64];
  __shared__ __align__(16) u16 Ws[NC * 64];
  __shared__ float sred[32][4][2];
  __shared__ float sred2[32][4][2];
  int t = threadIdx.x, lane = t & 63, w = t >> 6;
  int mrow = lane & 15, quad = lane >> 4;
  int bn0 = blockIdx.x * NC, bm0 = blockIdx.y * 32;

  int rA = t >> 3, gcA = (t & 7) ^ (rA & 7);
  const u16* gAp = A + (size_t)(bm0 + rA) * K + gcA * 8;
  u16* lAp = As + (w * 64) * 8;
  const u16* gW0 = W + (size_t)(bn0 + rA) * K + gcA * 8;
  u16* lW0 = Ws + (w * 64) * 8;

  floatx4 acc[2][NT4];
  #pragma unroll
  for (int mi = 0; mi < 2; ++mi)
    #pragma unroll
    for (int nt = 0; nt < NT4; ++nt) acc[mi][nt] = (floatx4){0.f, 0.f, 0.f, 0.f};

  for (int k0 = 0; k0 < K; k0 += 64) {
    __syncthreads();
    gload_lds16(gAp, lAp); gAp += 64;
    #pragma unroll
    for (int i = 0; i < NT; ++i)
      gload_lds16(gW0 + (size_t)i * 32 * K, lW0 + i * 2048);
    gW0 += 64;
    __syncthreads();
    #pragma unroll
    for (int ks = 0; ks < 2; ++ks) {
      int sw = ((ks * 4 + quad) ^ (mrow & 7)) * 8;
      short8 af0 = *(const short8*)&As[mrow * 64 + sw];
      short8 af1 = *(const short8*)&As[(16 + mrow) * 64 + sw];
      #pragma unroll
      for (int nt = 0; nt < NT4; ++nt) {
        int rw = w * (NC / 4) + nt * 16 + mrow;
        short8 bf = *(const short8*)&Ws[rw * 64 + sw];
        acc[0][nt] = __builtin_amdgcn_mfma_f32_16x16x32_bf16(af0, bf, acc[0][nt], 0, 0, 0);
        acc[1][nt] = __builtin_amdgcn_mfma_f32_16x16x32_bf16(af1, bf, acc[1][nt], 0, 0, 0);
      }
    }
  }

  if constexpr (LN) {
    float val[2][NT4][4];
    float bv[NT4];
    #pragma unroll
    for (int nt = 0; nt < NT4; ++nt) bv[nt] = bias[w * 64 + nt * 16 + mrow];
    #pragma unroll
    for (int mi = 0; mi < 2; ++mi) {
      #pragma unroll
      for (int r = 0; r < 4; ++r) {
        int gm = bm0 + mi * 16 + quad * 4 + r;
        float sr = 0.f, s2r = 0.f;
        #pragma unroll
        for (int nt = 0; nt < NT4; ++nt) {
          int gn = w * 64 + nt * 16 + mrow;
          float v = acc[mi][nt][r] + bv[nt] + bf2f(resb[(size_t)gm * 256 + gn]);
          val[mi][nt][r] = v; sr += v; s2r += v * v;
        }
        sr += __shfl_xor(sr, 1); s2r += __shfl_xor(s2r, 1);
        sr += __shfl_xor(sr, 2); s2r += __shfl_xor(s2r, 2);
        sr += __shfl_xor(sr, 4); s2r += __shfl_xor(s2r, 4);
        sr += __shfl_xor(sr, 8); s2r += __shfl_xor(s2r, 8);
        if (mrow == 0) { sred[mi * 16 + quad * 4 + r][w][0] = sr; sred[mi * 16 + quad * 4 + r][w][1] = s2r; }
      }
    }
    __syncthreads();
    #pragma unroll
    for (int mi = 0; mi < 2; ++mi) {
      #pragma unroll
      for (int r = 0; r < 4; ++r) {
        int lrow = mi * 16 + quad * 4 + r;
        float S  = sred[lrow][0][0] + sred[lrow][1][0] + sred[lrow][2][0] + sred[lrow][3][0];
        float S2 = sred[lrow][0][1] + sred[lrow][1][1] + sred[lrow][2][1] + sred[lrow][3][1];
        float mean = S * (1.f / 256.f);
        float var = S2 * (1.f / 256.f) - mean * mean;
        float inv = rsqrtf(var + 1e-5f);
        float sr2 = 0.f, s2r2 = 0.f;
        #pragma unroll
        for (int nt = 0; nt < NT4; ++nt) {
          int gn = w * 64 + nt * 16 + mrow;
          float y = (val[mi][nt][r] - mean) * inv * gam[gn] + bet[gn];
          val[mi][nt][r] = y;
          if constexpr (DLN) { sr2 += y; s2r2 += y * y; }
          else out[(size_t)(bm0 + lrow) * 256 + gn] = f2bf(y);
        }
        if constexpr (DLN) {
          sr2 += __shfl_xor(sr2, 1); s2r2 += __shfl_xor(s2r2, 1);
          sr2 += __shfl_xor(sr2, 2); s2r2 += __shfl_xor(s2r2, 2);
          sr2 += __shfl_xor(sr2, 4); s2r2 += __shfl_xor(s2r2, 4);
          sr2 += __shfl_xor(sr2, 8); s2r2 += __shfl_xor(s2r2, 8);
          if (mrow == 0) { sred2[lrow][w][0] = sr2; sred2[lrow][w][1] = s2r2; }
        }
      }
    }
    if constexpr (DLN) {
      __syncthreads();
      #pragma unroll
      for (int mi = 0; mi < 2; ++mi) {
        #pragma unroll
        for (int r = 0; r < 4; ++r) {
          int lrow = mi * 16 + quad * 4 + r;
          float S  = sred2[lrow][0][0] + sred2[lrow][1][0] + sred2[lrow][2][0] + sred2[lrow][3][0];
          float S2 = sred2[lrow][0][1] + sred2[lrow][1][1] + sred2[lrow][2][1] + sred2[lrow][3][1];
          float mean = S * (1.f / 256.f);
          float var = S2 * (1.f / 256.f) - mean * mean;
          float inv = rsqrtf(var + 1e-5f);
          #pragma unroll
          for (int nt = 0; nt < NT4; ++nt) {
            int gn = w * 64 + nt * 16 + mrow;
            float z = (val[mi][nt][r] - mean) * inv * gam2[gn] + bet2[gn];
            out[(size_t)(bm0 + lrow) * 256 + gn] = f2bf(z);
          }
        }
      }
    }
  } else {
    #pragma unroll
    for (int nt = 0; nt < NT4; ++nt) {
      int gn = bn0 + w * (NC / 4) + nt * 16 + mrow;
      float bv = bias[gn];
      #pragma unroll
      for (int mi = 0; mi < 2; ++mi) {
        #pragma unroll
        for (int r = 0; r < 4; ++r) {
          int gm = bm0 + mi * 16 + quad * 4 + r;
          float v = acc[mi][nt][r] + bv;
          if (GELU) v = 0.5f * v * (1.f + erff(v * 0.70710678118654752f));
          out[(size_t)gm * N + gn] = f2bf(v);
        }
      }
    }
  }
}

// ---------------- fused FFN v3: 8-warp (512t) blocks, 64 rows, 72KB LDS -> 2 blocks/CU,
//  16 waves/CU. Each Ws stage feeds 2x rows (per-CU weight staging halved) while keeping
//  the co-resident-block drain cover (round-11 lesson). Warp: rh=w>>2 row-half, wc=w&3 cols.
template<bool DLN>
__global__ __launch_bounds__(512) void ffu_kernel(
    const u16* __restrict__ A, const u16* __restrict__ W1, const float* __restrict__ b1,
    const u16* __restrict__ W2, const float* __restrict__ b2,
    const u16* __restrict__ resb,
    const float* __restrict__ gam, const float* __restrict__ bet,
    const float* __restrict__ gam2, const float* __restrict__ bet2,
    u16* __restrict__ out)
{
  __shared__ __align__(16) u16 As[4096];       // 8 KB: x k-step tile [64r][64k] As-format
  __shared__ __align__(16) u16 Ws[16384];      // 32 KB: W1/W2 staging (256 out-rows x 64 k)
  __shared__ __align__(16) u16 Hs[4 * 4096];   // 32 KB: gelu(h) quarter [64r][256k] As-format
  int t = threadIdx.x, lane = t & 63, w = t >> 6;
  int mrow = lane & 15, quad = lane >> 4;
  int rh = w >> 2, wc = w & 3;                 // row-half (32 rows), col ownership (64 cols)
  int bm0 = blockIdx.x * 64;
  int rA = t >> 3, gcA = (t & 7) ^ (rA & 7);   // rA in [0,64): As rows; Ws iter i row = i*64+rA

  floatx4 yacc[2][4];
  #pragma unroll
  for (int mi = 0; mi < 2; ++mi)
    #pragma unroll
    for (int nt = 0; nt < 4; ++nt) yacc[mi][nt] = (floatx4){0.f, 0.f, 0.f, 0.f};

  for (int nq = 0; nq < 4; ++nq) {
    floatx4 hacc[2][4];
    #pragma unroll
    for (int mi = 0; mi < 2; ++mi)
      #pragma unroll
      for (int nt = 0; nt < 4; ++nt) hacc[mi][nt] = (floatx4){0.f, 0.f, 0.f, 0.f};
    // FF1: h[:, nq*256 .. +256) = x @ W1_q^T  (K = 256, 4 k-steps)
    for (int kt = 0; kt < 4; ++kt) {
      __syncthreads();
      gload_lds16(A + (size_t)(bm0 + rA) * 256 + kt * 64 + gcA * 8, As + (w * 64) * 8);
      #pragma unroll
      for (int i = 0; i < 4; ++i)   // Ws row = i*64 + rA; (i*64+rA)&7 == rA&7 so gcA valid
        gload_lds16(W1 + (size_t)(nq * 256 + i * 64 + rA) * 256 + kt * 64 + gcA * 8,
                    Ws + i * 4096 + (w * 64) * 8);
      __syncthreads();
      #pragma unroll
      for (int ks = 0; ks < 2; ++ks) {
        int sw = ((ks * 4 + quad) ^ (mrow & 7)) * 8;
        short8 af0 = *(const short8*)&As[(rh * 32 + mrow) * 64 + sw];
        short8 af1 = *(const short8*)&As[(rh * 32 + 16 + mrow) * 64 + sw];
        #pragma unroll
        for (int nt = 0; nt < 4; ++nt) {
          short8 bf = *(const short8*)&Ws[(wc * 64 + nt * 16 + mrow) * 64 + sw];
          hacc[0][nt] = __builtin_amdgcn_mfma_f32_16x16x32_bf16(af0, bf, hacc[0][nt], 0, 0, 0);
          hacc[1][nt] = __builtin_amdgcn_mfma_f32_16x16x32_bf16(af1, bf, hacc[1][nt], 0, 0, 0);
        }
      }
    }
    // gelu + bias1 -> Hs (As-format). Col cc = wc*64 + nt*16 + mrow -> k-tile wc,
    // in-tile g = nt*2 + (mrow>>3); off = row*64 + (g^(row&7))*8 + (mrow&7).
    {
      float bv1[4];
      #pragma unroll
      for (int nt = 0; nt < 4; ++nt) bv1[nt] = b1[nq * 256 + wc * 64 + nt * 16 + mrow];
      #pragma unroll
      for (int mi = 0; mi < 2; ++mi) {
        #pragma unroll
        for (int nt = 0; nt < 4; ++nt) {
          int g = nt * 2 + (mrow >> 3);
          #pragma unroll
          for (int r = 0; r < 4; ++r) {
            int row = rh * 32 + mi * 16 + quad * 4 + r;
            float v = hacc[mi][nt][r] + bv1[nt];
            v = 0.5f * v * (1.f + erff(v * 0.70710678118654752f));
            Hs[wc * 4096 + row * 64 + (g ^ (row & 7)) * 8 + (mrow & 7)] = f2bf(v);
          }
        }
      }
    }
    // FF2 partial: yacc += gelu_h_q @ W2[:, nq*256 .. +256)^T  (4 k-steps over Hs)
    for (int kt2 = 0; kt2 < 4; ++kt2) {
      __syncthreads();   // Hs RAW (first iter) + Ws WAR
      #pragma unroll
      for (int i = 0; i < 4; ++i)
        gload_lds16(W2 + (size_t)(i * 64 + rA) * 1024 + nq * 256 + kt2 * 64 + gcA * 8,
                    Ws + i * 4096 + (w * 64) * 8);
      __syncthreads();
      #pragma unroll
      for (int ks = 0; ks < 2; ++ks) {
        int sw = ((ks * 4 + quad) ^ (mrow & 7)) * 8;
        short8 af0 = *(const short8*)&Hs[kt2 * 4096 + (rh * 32 + mrow) * 64 + sw];
        short8 af1 = *(const short8*)&Hs[kt2 * 4096 + (rh * 32 + 16 + mrow) * 64 + sw];
        #pragma unroll
        for (int nt = 0; nt < 4; ++nt) {
          short8 bf = *(const short8*)&Ws[(wc * 64 + nt * 16 + mrow) * 64 + sw];
          yacc[0][nt] = __builtin_amdgcn_mfma_f32_16x16x32_bf16(af0, bf, yacc[0][nt], 0, 0, 0);
          yacc[1][nt] = __builtin_amdgcn_mfma_f32_16x16x32_bf16(af1, bf, yacc[1][nt], 0, 0, 0);
        }
      }
    }
  }
  // epilogue: residual + LN (+DLN). sred aliased into As (dead; guarded by barrier).
  __syncthreads();
  float* sred  = (float*)As;        // [64 rows][4 wc][2] = 512 floats
  float* sred2 = sred + 512;
  float val[2][4][4];
  float bv[4];
  #pragma unroll
  for (int nt = 0; nt < 4; ++nt) bv[nt] = b2[wc * 64 + nt * 16 + mrow];
  #pragma unroll
  for (int mi = 0; mi < 2; ++mi) {
    #pragma unroll
    for (int r = 0; r < 4; ++r) {
      int row = rh * 32 + mi * 16 + quad * 4 + r;
      int gm = bm0 + row;
      float sr = 0.f, s2r = 0.f;
      #pragma unroll
      for (int nt = 0; nt < 4; ++nt) {
        int gn = wc * 64 + nt * 16 + mrow;
        float v = yacc[mi][nt][r] + bv[nt] + bf2f(resb[(size_t)gm * 256 + gn]);
        val[mi][nt][r] = v; sr += v; s2r += v * v;
      }
      sr += __shfl_xor(sr, 1); s2r += __shfl_xor(s2r, 1);
      sr += __shfl_xor(sr, 2); s2r += __shfl_xor(s2r, 2);
      sr += __shfl_xor(sr, 4); s2r += __shfl_xor(s2r, 4);
      sr += __shfl_xor(sr, 8); s2r += __shfl_xor(s2r, 8);
      if (mrow == 0) { sred[row * 8 + wc * 2 + 0] = sr; sred[row * 8 + wc * 2 + 1] = s2r; }
    }
  }
  __syncthreads();
  #pragma unroll
  for (int mi = 0; mi < 2; ++mi) {
    #pragma unroll
    for (int r = 0; r < 4; ++r) {
      int row = rh * 32 + mi * 16 + quad * 4 + r;
      float S  = sred[row * 8 + 0] + sred[row * 8 + 2] + sred[row * 8 + 4] + sred[row * 8 + 6];
      float S2 = sred[row * 8 + 1] + sred[row * 8 + 3] + sred[row * 8 + 5] + sred[row * 8 + 7];
      float mean = S * (1.f / 256.f);
      float var = S2 * (1.f / 256.f) - mean * mean;
      float inv = rsqrtf(var + 1e-5f);
      float sr2 = 0.f, s2r2 = 0.f;
      #pragma unroll
      for (int nt = 0; nt < 4; ++nt) {
        int gn = wc * 64 + nt * 16 + mrow;
        float y = (val[mi][nt][r] - mean) * inv * gam[gn] + bet[gn];
        val[mi][nt][r] = y;
        if constexpr (DLN) { sr2 += y; s2r2 += y * y; }
        else out[(size_t)(bm0 + row) * 256 + gn] = f2bf(y);
      }
      if constexpr (DLN) {
        sr2 += __shfl_xor(sr2, 1); s2r2 += __shfl_xor(s2r2, 1);
        sr2 += __shfl_xor(sr2, 2); s2r2 += __shfl_xor(s2r2, 2);
        sr2 += __shfl_xor(sr2, 4); s2r2 += __shfl_xor(s2r2, 4);
        sr2 += __shfl_xor(sr2, 8); s2r2 += __shfl_xor(s2r2, 8);
        if (mrow == 0) { sred2[row * 8 + wc * 2 + 0] = sr2; sred2[row * 8 + wc * 2 + 1] = s2r2; }
      }
    }
  }
  if constexpr (DLN) {
    __syncthreads();
    #pragma unroll
    for (int mi = 0; mi < 2; ++mi) {
      #pragma unroll
      for (int r = 0; r < 4; ++r) {
        int row = rh * 32 + mi * 16 + quad * 4 + r;
        float S  = sred2[row * 8 + 0] + sred2[row * 8 + 2] + sred2[row * 8 + 4] + sred2[row * 8 + 6];
        float S2 = sred2[row * 8 + 1] + sred2[row * 8 + 3] + sred2[row * 8 + 5] + sred2[row * 8 + 7];
        float mean = S * (1.f / 256.f);
        float var = S2 * (1.f / 256.f) - mean * mean;
        float inv = rsqrtf(var + 1e-5f);
        #pragma unroll
        for (int nt = 0; nt < 4; ++nt) {
          int gn = wc * 64 + nt * 16 + mrow;
          float z = (val[mi][nt][r] - mean) * inv * gam2[gn] + bet2[gn];
          out[(size_t)(bm0 + row) * 256 + gn] = f2bf(z);
        }
      }
    }
  }
}

// ---- MFMA GEMM 128x128, optional split-K via blockIdx.z (z>1: raw f32 partials out) -------
//      flags: 1=gelu, 2=f32 out, 4=pq-broadcast res
__global__ __launch_bounds__(256) void gemm128_kernel(
    const u16* __restrict__ A, const u16* __restrict__ W, const float* __restrict__ bias,
    const float* __restrict__ res, void* __restrict__ out,
    int M, int N, int K, int flags)
{
  __shared__ __align__(16) u16 As[128 * 64];
  __shared__ __align__(16) u16 Bs[128 * 64];
  int t = threadIdx.x;
  int lane = t & 63, w = t >> 6;
  int wm = w & 1, wn = w >> 1;
  int bn0 = blockIdx.x * 128, bm0 = blockIdx.y * 128;
  int mrow = lane & 15, quad = lane >> 4;
  int z = blockIdx.z, NZ = gridDim.z;
  int Kc = K / NZ, kbase = z * Kc;

  const u16* gA[4]; const u16* gB[4];
  u16* lA[4]; u16* lB[4];
  #pragma unroll
  for (int it = 0; it < 4; ++it) {
    int c = w * 256 + it * 64 + lane;
    int r = c >> 3;
    int gc = (c & 7) ^ (r & 7);
    gA[it] = A + (size_t)(bm0 + r) * K + kbase + gc * 8;
    gB[it] = W + (size_t)(bn0 + r) * K + kbase + gc * 8;
    lA[it] = As + (w * 256 + it * 64) * 8;
    lB[it] = Bs + (w * 256 + it * 64) * 8;
  }
  floatx4 acc[4][4];
  #pragma unroll
  for (int i = 0; i < 4; ++i)
    #pragma unroll
    for (int j = 0; j < 4; ++j)
      acc[i][j] = (floatx4){0.f, 0.f, 0.f, 0.f};
  int sw0 = ((0 * 4 + quad) ^ (mrow & 7)) * 8;
  int sw1 = ((1 * 4 + quad) ^ (mrow & 7)) * 8;

  for (int k0 = 0; k0 < Kc; k0 += 64) {
    __syncthreads();
    #pragma unroll
    for (int it = 0; it < 4; ++it) { gload_lds16(gA[it], lA[it]); gA[it] += 64; }
    #pragma unroll
    for (int it = 0; it < 4; ++it) { gload_lds16(gB[it], lB[it]); gB[it] += 64; }
    __syncthreads();
    #pragma unroll
    for (int ks = 0; ks < 2; ++ks) {
      int sw = ks ? sw1 : sw0;
      short8 af[4], bfr[4];
      #pragma unroll
      for (int mi = 0; mi < 4; ++mi)
        af[mi] = *(const short8*)&As[(wm * 64 + mi * 16 + mrow) * 64 + sw];
      #pragma unroll
      for (int nj = 0; nj < 4; ++nj)
        bfr[nj] = *(const short8*)&Bs[(wn * 64 + nj * 16 + mrow) * 64 + sw];
      #pragma unroll
      for (int mi = 0; mi < 4; ++mi)
        #pragma unroll
        for (int nj = 0; nj < 4; ++nj)
          acc[mi][nj] = __builtin_amdgcn_mfma_f32_16x16x32_bf16(af[mi], bfr[nj], acc[mi][nj], 0, 0, 0);
    }
  }
  if (NZ > 1) {
    // raw partial accumulators -> f32 buffer at out + z*M*N
    float* po = (float*)out + (size_t)z * M * N;
    #pragma unroll
    for (int nj = 0; nj < 4; ++nj) {
      int gn = bn0 + wn * 64 + nj * 16 + mrow;
      #pragma unroll
      for (int mi = 0; mi < 4; ++mi)
        #pragma unroll
        for (int r = 0; r < 4; ++r) {
          int gm = bm0 + wm * 64 + mi * 16 + quad * 4 + r;
          po[(size_t)gm * N + gn] = acc[mi][nj][r];
        }
    }
    return;
  }
  bool do_gelu = (flags & 1) != 0, of32 = (flags & 2) != 0;
  #pragma unroll
  for (int nj = 0; nj < 4; ++nj) {
    int gn = bn0 + wn * 64 + nj * 16 + mrow;
    float bv = bias ? bias[gn] : 0.f;
    #pragma unroll
    for (int mi = 0; mi < 4; ++mi) {
      #pragma unroll
      for (int r = 0; r < 4; ++r) {
        int gm = bm0 + wm * 64 + mi * 16 + quad * 4 + r;
        float v = acc[mi][nj][r] + bv;
        if (do_gelu) v = 0.5f * v * (1.f + erff(v * 0.70710678118654752f));
        if (flags & 4) v += res[(size_t)(gm & 15) * N + gn];
        else if (res) v += res[(size_t)gm * N + gn];
        if (of32) ((float*)out)[(size_t)gm * N + gn] = v;
        else      ((u16*)out)[(size_t)gm * N + gn] = f2bf(v);
      }
    }
  }
}

// ---------------- LayerNorm: one wave per row, 4 rows/block (final output) ----------------
template<int D>
__global__ __launch_bounds__(256) void lnw_kernel(
    const float* __restrict__ in, const float* __restrict__ w, const float* __restrict__ b,
    float* __restrict__ outf, u16* __restrict__ outb)
{
  constexpr int NV = D / 64;
  int lane = threadIdx.x & 63, wv = threadIdx.x >> 6;
  int row = blockIdx.x * 4 + wv;
  const float* xr = in + (size_t)row * D;
  float v[NV];
  float s = 0.f, s2 = 0.f;
  #pragma unroll
  for (int i = 0; i < NV; ++i) {
    v[i] = xr[lane + i * 64];
    s += v[i]; s2 += v[i] * v[i];
  }
  #pragma unroll
  for (int off = 32; off > 0; off >>= 1) { s += __shfl_xor(s, off); s2 += __shfl_xor(s2, off); }
  float mean = s / (float)D;
  float var = s2 / (float)D - mean * mean;
  float inv = rsqrtf(var + 1e-5f);
  #pragma unroll
  for (int i = 0; i < NV; ++i) {
    int col = lane + i * 64;
    float y = (v[i] - mean) * inv * w[col] + b[col];
    size_t o = (size_t)row * D + col;
    if (outf) outf[o] = y;
    if (outb) outb[o] = f2bf(y);
  }
}

// ---------------- encoder self-attention v6: enc5 body (28KB LDS, 5 blocks/CU) with
//                  XCD-affine 1D grid: the 4 qt-blocks of each (b,h) land on one XCD L2 ------
__global__ __launch_bounds__(256, 5) void attn_enc6_kernel(
    const u16* __restrict__ qkv, u16* __restrict__ out)
{
  __shared__ __align__(16) u16 Ks[64 * 40];       // 5120 B
  __shared__ __align__(16) u16 Vt[32 * 72];       // 4608 B
  __shared__ __align__(16) u16 Pl[4 * 32 * 72];   // 18432 B  (total 28160 -> 5 blocks/CU)
  int F = blockIdx.x;
  int xcd = F & 7, jj = F >> 3;
  int pair = xcd * 32 + (jj >> 2), qt = jj & 3;
  int b = pair >> 3, h = pair & 7;
  int t = threadIdx.x, lane = t & 63, w = t >> 6;
  int mrow = lane & 15, quad = lane >> 4;
  int q0 = qt * 128 + w * 32;
  short8 qf[2];
  #pragma unroll
  for (int mi = 0; mi < 2; ++mi)
    qf[mi] = *(const short8*)(qkv + (size_t)(b * CC + q0 + mi * 16 + mrow) * 768 + h * 32 + quad * 8);
  floatx4 o[2][2];
  #pragma unroll
  for (int mi = 0; mi < 2; ++mi)
    #pragma unroll
    for (int di = 0; di < 2; ++di) o[mi][di] = (floatx4){0.f, 0.f, 0.f, 0.f};
  float lst[2][4] = {{0.f,0.f,0.f,0.f},{0.f,0.f,0.f,0.f}};
  const float sc = 0.17677669529663687f * 1.4426950408889634f;
  const floatx4 zf = (floatx4){0.f, 0.f, 0.f, 0.f};
  for (int jt = 0; jt < 8; ++jt) {
    if (jt) __syncthreads();
    {  // K tile: 64 j x 32 d (one u16x8 per thread)
      int j = t >> 2, q4 = (t & 3) * 8;
      uint4 kk = *(const uint4*)(qkv + (size_t)(b * CC + jt * 64 + j) * 768 + 256 + h * 32 + q4);
      *(uint4*)&Ks[j * 40 + q4] = kk;
      // V tile: transpose+permute into Vt[d][jp], jp=(j&15)*4+(j>>4)
      uint4 vv = *(const uint4*)(qkv + (size_t)(b * CC + jt * 64 + j) * 768 + 512 + h * 32 + q4);
      u16 tmp[8]; *(uint4*)tmp = vv;
      int jp = (j & 15) * 4 + (j >> 4);
      #pragma unroll
      for (int i = 0; i < 8; ++i) Vt[(q4 + i) * 72 + jp] = tmp[i];
    }
    __syncthreads();
    floatx4 s[2][4];
    #pragma unroll
    for (int nj = 0; nj < 4; ++nj) {
      short8 bf = *(const short8*)&Ks[(nj * 16 + mrow) * 40 + quad * 8];
      s[0][nj] = __builtin_amdgcn_mfma_f32_16x16x32_bf16(qf[0], bf, zf, 0, 0, 0);
      s[1][nj] = __builtin_amdgcn_mfma_f32_16x16x32_bf16(qf[1], bf, zf, 0, 0, 0);
    }
    #pragma unroll
    for (int mi = 0; mi < 2; ++mi) {
      #pragma unroll
      for (int r = 0; r < 4; ++r) {
        float ps = 0.f; u16 hv[4];
        #pragma unroll
        for (int nj = 0; nj < 4; ++nj) {
          float p = exp2f(s[mi][nj][r] * sc);
          ps += p; hv[nj] = f2bf(p);
        }
        lst[mi][r] += ps;
        *(uint2*)&Pl[(w * 32 + mi * 16 + quad * 4 + r) * 72 + mrow * 4] = *(uint2*)hv;
      }
    }
    #pragma unroll
    for (int ks = 0; ks < 2; ++ks) {
      short8 a0 = *(const short8*)&Pl[(w * 32 + mrow) * 72 + ks * 32 + quad * 8];
      short8 a1 = *(const short8*)&Pl[(w * 32 + 16 + mrow) * 72 + ks * 32 + quad * 8];
      short8 b0 = *(const short8*)&Vt[mrow * 72 + ks * 32 + quad * 8];
      short8 b1 = *(const short8*)&Vt[(16 + mrow) * 72 + ks * 32 + quad * 8];
      o[0][0] = __builtin_amdgcn_mfma_f32_16x16x32_bf16(a0, b0, o[0][0], 0, 0, 0);
      o[0][1] = __builtin_amdgcn_mfma_f32_16x16x32_bf16(a0, b1, o[0][1], 0, 0, 0);
      o[1][0] = __builtin_amdgcn_mfma_f32_16x16x32_bf16(a1, b0, o[1][0], 0, 0, 0);
      o[1][1] = __builtin_amdgcn_mfma_f32_16x16x32_bf16(a1, b1, o[1][1], 0, 0, 0);
    }
  }
  #pragma unroll
  for (int mi = 0; mi < 2; ++mi) {
    #pragma unroll
    for (int r = 0; r < 4; ++r) {
      float l = lst[mi][r];
      l += __shfl_xor(l, 1); l += __shfl_xor(l, 2);
      l += __shfl_xor(l, 4); l += __shfl_xor(l, 8);
      float inv = 1.f / l;
      int row = b * CC + q0 + mi * 16 + quad * 4 + r;
      #pragma unroll
      for (int di = 0; di < 2; ++di)
        out[(size_t)row * DD + h * 32 + di * 16 + mrow] = f2bf(o[mi][di][r] * inv);
    }
  }
}

// ---------------- fused prefix cross-attention: K/V projections folded through the
//  attention contractions (S = Qc·tln, T = P·tln, O = (T/l)·Wcv^T + bv).
//  Grid is (b, h) so XCD = b&7: each XCD L2 holds 4 tln batches (1MB) reused by 8 heads. ----
__global__ __launch_bounds__(256) void attn_preff_kernel(
    const u16* __restrict__ tln, const u16* __restrict__ wcb,
    const u16* __restrict__ qcg, const float* __restrict__ bkv,
    u16* __restrict__ out)
{
  __shared__ __align__(16) u16 Ajc[64 * 264];   // tln tile [j][c]      33792 B
  __shared__ __align__(16) u16 Acj[256 * 72];   // tln^T tile [c][j]    36864 B
  __shared__ __align__(16) u16 Qs[16 * 264];    // Qc_h [q][c]           8448 B
  __shared__ __align__(16) u16 Ps[16 * 72];     // P tile [q][j]         2304 B
  __shared__ __align__(16) u16 Ts[16 * 264];    // T/l [q][c]            8448 B
  __shared__ float Lred[4][16];
  int b = blockIdx.x, h = blockIdx.y;
  int t = threadIdx.x, lane = t & 63, w = t >> 6;
  int mrow = lane & 15, quad = lane >> 4;
  const float sc = 0.08838834764831845f * 1.4426950408889634f;
  const floatx4 zf = (floatx4){0.f, 0.f, 0.f, 0.f};
  {  // stage Qc_h: 16 x 256, thread t -> row t>>4, 16 cols
    int q = t >> 4, c0 = (t & 15) * 16;
    *(uint4*)&Qs[q * 264 + c0]     = *(const uint4*)(qcg + ((size_t)h * 16 + q) * 256 + c0);
    *(uint4*)&Qs[q * 264 + c0 + 8] = *(const uint4*)(qcg + ((size_t)h * 16 + q) * 256 + c0 + 8);
  }
  floatx4 Tacc[4] = {zf, zf, zf, zf};   // T[q][c], warp owns c in [w*64, w*64+64)
  float lacc = 0.f;
  const u16* tb = tln + (size_t)b * 512 * 256;
  for (int jt = 0; jt < 8; ++jt) {
    __syncthreads();   // WAR vs prev tile's reads; covers Qs staging on iter 0
    {  // stage tln tile [64 j][256 c] both orientations; thread: row j=t>>2, cols (t&3)*64..+64
      int j = t >> 2, c0 = (t & 3) * 64;
      #pragma unroll
      for (int u = 0; u < 8; ++u) {
        uint4 v = *(const uint4*)(tb + (size_t)(jt * 64 + j) * 256 + c0 + u * 8);
        *(uint4*)&Ajc[j * 264 + c0 + u * 8] = v;
        u16 tmp[8]; *(uint4*)tmp = v;
        #pragma unroll
        for (int i = 0; i < 8; ++i) Acj[(c0 + u * 8 + i) * 72 + j] = tmp[i];
      }
    }
    __syncthreads();
    // S^T[j,q]: warp w handles j in [w*16, w*16+16); K = 256 c
    floatx4 s = zf;
    #pragma unroll
    for (int kk = 0; kk < 8; ++kk) {
      short8 af = *(const short8*)&Ajc[(w * 16 + mrow) * 264 + kk * 32 + quad * 8];
      short8 bf = *(const short8*)&Qs[mrow * 264 + kk * 32 + quad * 8];
      s = __builtin_amdgcn_mfma_f32_16x16x32_bf16(af, bf, s, 0, 0, 0);
    }
    // lane holds s[r] for j = w*16 + quad*4 + r, q = mrow
    u16 hv[4]; float ps = 0.f;
    #pragma unroll
    for (int r = 0; r < 4; ++r) {
      float p = exp2f(s[r] * sc);
      ps += p; hv[r] = f2bf(p);
    }
    ps += __shfl_xor(ps, 16); ps += __shfl_xor(ps, 32);  // sum over warp's 16 j (per q=mrow)
    lacc += ps;
    *(uint2*)&Ps[mrow * 72 + w * 16 + quad * 4] = *(uint2*)hv;
    __syncthreads();
    // T += P @ tln_tile: warp w owns c-tiles [w*64..); K = 64 j
    #pragma unroll
    for (int kk = 0; kk < 2; ++kk) {
      short8 af = *(const short8*)&Ps[mrow * 72 + kk * 32 + quad * 8];
      #pragma unroll
      for (int ct = 0; ct < 4; ++ct) {
        short8 bf = *(const short8*)&Acj[(w * 64 + ct * 16 + mrow) * 72 + kk * 32 + quad * 8];
        Tacc[ct] = __builtin_amdgcn_mfma_f32_16x16x32_bf16(af, bf, Tacc[ct], 0, 0, 0);
      }
    }
  }
  if (lane < 16) Lred[w][lane] = lacc;   // lacc valid for q = mrow = lane
  __syncthreads();
  // normalize T, write Ts[q][c] (lane: q = quad*4+r, c = w*64 + ct*16 + mrow)
  #pragma unroll
  for (int r = 0; r < 4; ++r) {
    int q = quad * 4 + r;
    float l = Lred[0][q] + Lred[1][q] + Lred[2][q] + Lred[3][q];
    float inv = 1.f / l;
    #pragma unroll
    for (int ct = 0; ct < 4; ++ct)
      Ts[q * 264 + w * 64 + ct * 16 + mrow] = f2bf(Tacc[ct][r] * inv);
  }
  __syncthreads();
  // O = Ts @ Wcv_h^T + bv: warp w owns d-tiles [w*32, w*32+32); K = 256 c
  const u16* wv = wcb + (size_t)(1024 + h * 128) * 256;
  floatx4 oacc[2] = {zf, zf};
  #pragma unroll
  for (int kk = 0; kk < 8; ++kk) {
    short8 af = *(const short8*)&Ts[mrow * 264 + kk * 32 + quad * 8];
    #pragma unroll
    for (int dt = 0; dt < 2; ++dt) {
      short8 bf = *(const short8*)(wv + (size_t)(w * 32 + dt * 16 + mrow) * 256 + kk * 32 + quad * 8);
      oacc[dt] = __builtin_amdgcn_mfma_f32_16x16x32_bf16(af, bf, oacc[dt], 0, 0, 0);
    }
  }
  #pragma unroll
  for (int dt = 0; dt < 2; ++dt) {
    int d = w * 32 + dt * 16 + mrow;
    float bv = bkv[1024 + h * 128 + d];
    #pragma unroll
    for (int r = 0; r < 4; ++r) {
      int q = quad * 4 + r;
      out[((size_t)(b * 16 + q)) * 1024 + h * 128 + d] = f2bf(oacc[dt][r] + bv);
    }
  }
}

extern "C" void kernel_launch(void* const* d_in, const int* in_sizes, int n_in,
                              void* d_out, int out_size, void* d_ws, size_t ws_size,
                              hipStream_t stream)
{
  const int* vi = (const int*)d_in[0];
  const int* si = (const int*)d_in[1];
  const int* mk = (const int*)d_in[2];
  const float* ve   = (const float*)d_in[3];
  const float* se   = (const float*)d_in[4];
  const float* lpe  = (const float*)d_in[5];
  const float* cpe  = (const float*)d_in[6];
  const float* eiw  = (const float*)d_in[7];
  const float* eib  = (const float*)d_in[8];
  const float* eow  = (const float*)d_in[9];
  const float* eob  = (const float*)d_in[10];
  const float* f1w  = (const float*)d_in[11];
  const float* f1b  = (const float*)d_in[12];
  const float* f2w  = (const float*)d_in[13];
  const float* f2b  = (const float*)d_in[14];
  const float* n1w  = (const float*)d_in[15];
  const float* n1b  = (const float*)d_in[16];
  const float* n2w  = (const float*)d_in[17];
  const float* n2b  = (const float*)d_in[18];
  const float* tlw  = (const float*)d_in[19];
  const float* tlb  = (const float*)d_in[20];
  const float* thw  = (const float*)d_in[21];
  const float* thb  = (const float*)d_in[22];
  const float* pq   = (const float*)d_in[23];
  const float* paiw = (const float*)d_in[24];
  const float* paib = (const float*)d_in[25];
  const float* paow = (const float*)d_in[26];
  const float* paob = (const float*)d_in[27];
  const float* pnw  = (const float*)d_in[28];
  const float* pnb  = (const float*)d_in[29];

  const int NROW = BB * CC;  // 16384
  const size_t MB = 1048576;
  char* base = (char*)d_ws;
  // encoder phase:
  u16* xb   = (u16*)(base);                // [0,8M)   bf16 residual stream (post-LN)
  u16* qkvb = (u16*)(base + 8 * MB);       // [8M,32M)
  u16* atto = (u16*)(base + 32 * MB);      // [32M,40M)
  u16* tln  = (u16*)(base + 96 * MB);      // [96M,104M)
  // folded-weight region [64M,70M):
  u16* wcb   = (u16*)(base + 64 * MB);     // [64M,65M)  Wc = Wkv @ th_w, bf16 [2048,256]
  u16* thwTb = (u16*)(base + 65 * MB);     // [65M,65.5M) th_w^T bf16 [256,1024]
  float* bkv = (float*)(base + 66 * MB);   // [66M,66M+8K) folded KV bias fp32 [2048]
  u16* wckT  = (u16*)(base + 67 * MB);     // [67M,67.5M) Wck^T bf16 [256,1024]
  u16* qcg   = (u16*)(base + 68 * MB);     // [68M,+64K)  Qc bf16 [8][16][256]
  float* skpart = (float*)(base + 80 * MB);// [80M,88M) split-K f32 partials
  u16* wbf  = (u16*)(base + 104 * MB);     // [104M,~119M)
  u16* qh    = (u16*)(base + 120 * MB);    // [120M,+256K) qh scratch (rows 16..127 garbage)
  u16* prefo = (u16*)(base + 121 * MB);    // [121M,+1M)
  float* prefout = (float*)(base + 122 * MB);

  u16* eiw_b  = wbf + 0;
  u16* eow_b  = wbf + 786432;
  u16* f1w_b  = wbf + 1048576;
  u16* f2w_b  = wbf + 2097152;
  u16* thw_b  = wbf + 3145728;
  u16* paiw_b = wbf + 3407872;
  u16* paow_b = wbf + 6553600;
  u16* pqb    = wbf + 7602176;
  u16* veb    = wbf + 7618560;
  u16* seb    = wbf + 7749888;
  u16* lpeb   = wbf + 7750656;
  u16* cpeb   = wbf + 7754752;

  dim3 blk(256);
  dim3 blk512(512);
  cvt_kernel<<<7701, blk, 0, stream>>>(eiw, eow, f1w, f2w, thw, paiw, paow, pq,
                                       ve, se, lpe, cpe, wbf);
  // weight fold: Wc[n,d] = sum_h Wkv[n,h]*th_w[h,d]; bkv[n] = Wkv[n,:]·th_b + pa_in_b[1024+n]
  thwT_kernel<<<256, blk, 0, stream>>>(thw, thwTb);
  biasfold_kernel<<<512, blk, 0, stream>>>(paiw_b + (size_t)HH * HH, thb, paib, bkv);
  gemm128_kernel<<<dim3(2, 16, 4), blk, 0, stream>>>(
      paiw_b + (size_t)HH * HH, thwTb, nullptr, nullptr, skpart, 2048, 256, HH, 0);
  redk_kernel<<<512, blk, 0, stream>>>(skpart, nullptr, nullptr, nullptr, wcb,
                                       256, 4, 2048 * 256, 0);
  // qh = pq @ Wq^T via split-K (latency-bound tail fix)
  gemm128_kernel<<<dim3(8, 1, 8), blk, 0, stream>>>(
      pqb, paiw_b, nullptr, nullptr, skpart, 128, 1024, HH, 0);
  redk_kernel<<<128, blk, 0, stream>>>(skpart, paib, nullptr, nullptr, qh,
                                       1024, 8, 128 * 1024, 0);
  bT_kernel<<<256, blk, 0, stream>>>(wcb, wckT);
  qc_kernel<<<8, blk, 0, stream>>>(qh, wckT, qcg);
  embed_kernel<<<NROW/2, blk, 0, stream>>>(vi, si, mk, veb, seb, lpeb, cpeb, xb);
  for (int i = 0; i < NLAY; ++i) {
    gwide_kernel<384, false, false, false><<<dim3(2, NROW/32), blk, 0, stream>>>(
        xb, eiw_b + (size_t)i*768*DD, eib + i*768, nullptr, nullptr, nullptr, nullptr, nullptr,
        qkvb, 768, DD);
    attn_enc6_kernel<<<1024, blk, 0, stream>>>(qkvb, atto);
    gwide_kernel<256, false, true, false><<<dim3(1, NROW/32), blk, 0, stream>>>(
        atto, eow_b + (size_t)i*DD*DD, eob + i*DD, xb, n1w + i*DD, n1b + i*DD, nullptr, nullptr,
        xb, DD, DD);
    // fused FF1+gelu+FF2+res+LN v3: 8-warp/64-row blocks, 72KB LDS, 2 blocks/CU
    if (i < NLAY - 1) {
      ffu_kernel<false><<<NROW/64, blk512, 0, stream>>>(
          xb, f1w_b + (size_t)i*HH*DD, f1b + i*HH, f2w_b + (size_t)i*DD*HH, f2b + i*DD,
          xb, n2w + i*DD, n2b + i*DD, nullptr, nullptr, xb);
    } else {
      ffu_kernel<true><<<NROW/64, blk512, 0, stream>>>(
          xb, f1w_b + (size_t)i*HH*DD, f1b + i*HH, f2w_b + (size_t)i*DD*HH, f2b + i*DD,
          xb, n2w + i*DD, n2b + i*DD, tlw, tlb, tln);
    }
  }
  // fused prefix cross-attention (b-major grid: XCD = b&7, tln L2-resident per XCD)
  attn_preff_kernel<<<dim3(BB, 8), blk, 0, stream>>>(tln, wcb, qcg, bkv, prefo);
  // split-K out-proj
  gemm128_kernel<<<dim3(1024/128, (BB*PP)/128, 4), blk, 0, stream>>>(
      prefo, paow_b, nullptr, nullptr, skpart, BB*PP, HH, HH, 0);
  redk_kernel<<<512, blk, 0, stream>>>(skpart, paob, pq, prefout, nullptr,
                                       1024, 4, BB*PP*HH, 4);
  lnw_kernel<1024><<<(BB*PP)/4, blk, 0, stream>>>(prefout, pnw, pnb, (float*)d_out, nullptr);
}

// Round 15
// 643.873 us; speedup vs baseline: 1.3163x; 1.0178x over previous
//
#include <hip/hip_runtime.h>
#include <hip/hip_bf16.h>

typedef unsigned short u16;
typedef unsigned int u32;
typedef __attribute__((ext_vector_type(8))) short short8;
typedef __attribute__((ext_vector_type(4))) float floatx4;

#define BB 32
#define CC 512
#define LL 16
#define DD 256
#define HH 1024
#define PP 16
#define NLAY 4

__device__ __forceinline__ float bf2f(u16 u) {
  u32 x = ((u32)u) << 16; float f; __builtin_memcpy(&f, &x, 4); return f;
}
__device__ __forceinline__ u16 f2bf(float f) {
  __hip_bfloat16 h = __float2bfloat16(f);
  u16 r; __builtin_memcpy(&r, &h, 2); return r;
}
__device__ __forceinline__ void gload_lds16(const u16* g, u16* l) {
  __builtin_amdgcn_global_load_lds(
      (const __attribute__((address_space(1))) void*)g,
      (__attribute__((address_space(3))) void*)l, 16, 0, 0);
}

// ---------------- fp32 -> bf16 conversion: 8 weight tensors + 4 embedding tables ----------------
__global__ __launch_bounds__(256) void cvt_kernel(
    const float* __restrict__ s0, const float* __restrict__ s1,
    const float* __restrict__ s2, const float* __restrict__ s3,
    const float* __restrict__ s4, const float* __restrict__ s5,
    const float* __restrict__ s6, const float* __restrict__ s7,
    const float* __restrict__ s8, const float* __restrict__ s9,
    const float* __restrict__ s10, const float* __restrict__ s11,
    u16* __restrict__ dst)
{
  const float* srcs[12] = {s0, s1, s2, s3, s4, s5, s6, s7, s8, s9, s10, s11};
  const int pfx[12] = {786432, 1048576, 2097152, 3145728, 3407872, 6553600, 7602176,
                       7618560, 7749888, 7750656, 7754752, 7885824};
  int e = (blockIdx.x * 256 + threadIdx.x) * 4;
  int seg = 0;
  while (e >= pfx[seg]) seg++;
  int start = seg ? pfx[seg - 1] : 0;
  float4 f = *(const float4*)(srcs[seg] + (e - start));
  u16 o[4] = {f2bf(f.x), f2bf(f.y), f2bf(f.z), f2bf(f.w)};
  *(uint2*)(dst + e) = *(const uint2*)o;
}

// ---------------- th_w [1024,256] fp32 -> bf16 transposed [256,1024] (K-major for fold GEMM) ---
__global__ __launch_bounds__(256) void thwT_kernel(
    const float* __restrict__ thw, u16* __restrict__ out)
{
  __shared__ float tile[32][33];
  int bx = blockIdx.x & 7, by = blockIdx.x >> 3;   // bx: d-tile (8), by: h-tile (32)
  int tx = threadIdx.x & 31, ty = threadIdx.x >> 5;
  #pragma unroll
  for (int i = 0; i < 4; ++i) {
    int h = by * 32 + ty + i * 8, d = bx * 32 + tx;
    tile[ty + i * 8][tx] = thw[h * 256 + d];
  }
  __syncthreads();
  #pragma unroll
  for (int i = 0; i < 4; ++i) {
    int d = bx * 32 + ty + i * 8, h = by * 32 + tx;
    out[d * 1024 + h] = f2bf(tile[tx][ty + i * 8]);
  }
}

// ---------------- bf16 transpose [1024,256] -> [256,1024] (Wck^T for Qc fold) ----------------
__global__ __launch_bounds__(256) void bT_kernel(
    const u16* __restrict__ in, u16* __restrict__ out)
{
  __shared__ u16 tile[32][33];
  int bx = blockIdx.x & 7, by = blockIdx.x >> 3;   // bx: c-tile (8), by: hd-tile (32)
  int tx = threadIdx.x & 31, ty = threadIdx.x >> 5;
  #pragma unroll
  for (int i = 0; i < 4; ++i) {
    int hd = by * 32 + ty + i * 8, c = bx * 32 + tx;
    tile[ty + i * 8][tx] = in[hd * 256 + c];
  }
  __syncthreads();
  #pragma unroll
  for (int i = 0; i < 4; ++i) {
    int c = bx * 32 + ty + i * 8, hd = by * 32 + tx;
    out[c * 1024 + hd] = tile[tx][ty + i * 8];
  }
}

// ---------------- Qc fold: Qc[h][q][c] = sum_d qh[q, h*128+d] * Wck[h*128+d, c] ------------
__global__ __launch_bounds__(256) void qc_kernel(
    const u16* __restrict__ qh, const u16* __restrict__ wckT, u16* __restrict__ qcg)
{
  int h = blockIdx.x;
  int t = threadIdx.x, lane = t & 63, w = t >> 6;
  int mrow = lane & 15, quad = lane >> 4;
  const floatx4 zf = (floatx4){0.f, 0.f, 0.f, 0.f};
  floatx4 acc[4] = {zf, zf, zf, zf};
  #pragma unroll
  for (int kk = 0; kk < 4; ++kk) {
    short8 af = *(const short8*)(qh + (size_t)mrow * 1024 + h * 128 + kk * 32 + quad * 8);
    #pragma unroll
    for (int ct = 0; ct < 4; ++ct) {
      int c = w * 64 + ct * 16 + mrow;
      short8 bf = *(const short8*)(wckT + (size_t)c * 1024 + h * 128 + kk * 32 + quad * 8);
      acc[ct] = __builtin_amdgcn_mfma_f32_16x16x32_bf16(af, bf, acc[ct], 0, 0, 0);
    }
  }
  #pragma unroll
  for (int ct = 0; ct < 4; ++ct)
    #pragma unroll
    for (int r = 0; r < 4; ++r)
      qcg[((size_t)h * 16 + quad * 4 + r) * 256 + w * 64 + ct * 16 + mrow] = f2bf(acc[ct][r]);
}

// ---------------- folded KV bias: bkv[n] = Wkv[n,:]·th_b + pa_in_b[1024+n], one wave/row ------
__global__ __launch_bounds__(256) void biasfold_kernel(
    const u16* __restrict__ Wkv, const float* __restrict__ thb,
    const float* __restrict__ paib, float* __restrict__ out)
{
  int wv = threadIdx.x >> 6, lane = threadIdx.x & 63;
  int n = blockIdx.x * 4 + wv;
  const u16* wr = Wkv + (size_t)n * 1024;
  float s = 0.f;
  #pragma unroll
  for (int i = 0; i < 16; ++i) {
    int h = i * 64 + lane;
    s += bf2f(wr[h]) * thb[h];
  }
  #pragma unroll
  for (int off = 32; off; off >>= 1) s += __shfl_xor(s, off);
  if (!lane) out[n] = s + paib[1024 + n];
}

// ---------------- split-K reduce: sum nz f32 partials + bias/res, write f32 or bf16 ----------
__global__ __launch_bounds__(256) void redk_kernel(
    const float* __restrict__ part, const float* __restrict__ bias,
    const float* __restrict__ res, float* __restrict__ outf, u16* __restrict__ outb,
    int N, int nz, int total, int flags)   // flags&4: res row index is (row&15)
{
  int idx = (blockIdx.x * 256 + threadIdx.x) * 4;
  if (idx >= total) return;
  float4 a = *(const float4*)(part + idx);
  for (int z = 1; z < nz; ++z) {
    float4 b = *(const float4*)(part + (size_t)z * total + idx);
    a.x += b.x; a.y += b.y; a.z += b.z; a.w += b.w;
  }
  int row = idx / N, col = idx - row * N;   // 4 consecutive cols, same row (N % 4 == 0)
  float v4[4] = {a.x, a.y, a.z, a.w};
  #pragma unroll
  for (int i = 0; i < 4; ++i) {
    if (bias) v4[i] += bias[col + i];
    if (res) v4[i] += res[(size_t)((flags & 4) ? (row & 15) : row) * N + col + i];
  }
  if (outf) {
    *(float4*)(outf + idx) = *(const float4*)v4;
  } else {
    u16 o[4] = {f2bf(v4[0]), f2bf(v4[1]), f2bf(v4[2]), f2bf(v4[3])};
    *(uint2*)(outb + idx) = *(const uint2*)o;
  }
}

// ---------------- embed + masked mean pool (bf16 tables, 2 clauses/block, u32 loads) --------
__global__ __launch_bounds__(256) void embed_kernel(
    const int* __restrict__ vi, const int* __restrict__ si, const int* __restrict__ mk,
    const u16* __restrict__ veb, const u16* __restrict__ seb,
    const u16* __restrict__ lpeb, const u16* __restrict__ cpeb,
    u16* __restrict__ xb)
{
  int t = threadIdx.x;
  int bc = blockIdx.x * 2 + (t >> 7);
  int c = bc & (CC - 1);
  int dl = (t & 127) * 2;
  int base = bc * LL;
  float a0 = 0.f, a1 = 0.f; int cnt = 0;
  #pragma unroll
  for (int l = 0; l < LL; ++l) {
    if (mk[base + l]) {
      int v = vi[base + l], s = si[base + l];
      u32 vv = *(const u32*)&veb[v * DD + dl];
      u32 sv = *(const u32*)&seb[s * DD + dl];
      u32 lv = *(const u32*)&lpeb[l * DD + dl];
      a0 += bf2f((u16)vv) + bf2f((u16)sv) + bf2f((u16)lv);
      a1 += bf2f((u16)(vv >> 16)) + bf2f((u16)(sv >> 16)) + bf2f((u16)(lv >> 16));
      cnt++;
    }
  }
  u32 cv = *(const u32*)&cpeb[c * DD + dl];
  float inv = 1.f / (float)cnt;
  u32 pk = (u32)f2bf(a0 * inv + bf2f((u16)cv)) | ((u32)f2bf(a1 * inv + bf2f((u16)(cv >> 16))) << 16);
  *(u32*)&xb[(size_t)bc * DD + dl] = pk;
}

// ---------------- wide-N GEMM 32 rows (v2 warp mapping; QKV and attn-out-LN call-sites) ----
template<int NC, bool GELU, bool LN, bool DLN>
__global__ __launch_bounds__(256) void gwide_kernel(
    const u16* __restrict__ A, const u16* __restrict__ W, const float* __restrict__ bias,
    const u16* __restrict__ resb, const float* __restrict__ gam, const float* __restrict__ bet,
    const float* __restrict__ gam2, const float* __restrict__ bet2,
    u16* __restrict__ out, int N, int K)
{
  constexpr int NT = NC / 32;    // staging tile count
  constexpr int NT4 = NC / 64;   // col tiles per warp
  __shared__ __align__(16) u16 As[32 * 64];
  __shared__ __align__(16) u16 Ws[NC * 64];
  __shared__ float sred[32][4][2];
  __shared__ float sred2[32][4][2];
  int t = threadIdx.x, lane = t & 63, w = t >> 6;
  int mrow = lane & 15, quad = lane >> 4;
  int bn0 = blockIdx.x * NC, bm0 = blockIdx.y * 32;

  int rA = t >> 3, gcA = (t & 7) ^ (rA & 7);
  const u16* gAp = A + (size_t)(bm0 + rA) * K + gcA * 8;
  u16* lAp = As + (w * 64) * 8;
  const u16* gW0 = W + (size_t)(bn0 + rA) * K + gcA * 8;
  u16* lW0 = Ws + (w * 64) * 8;

  floatx4 acc[2][NT4];
  #pragma unroll
  for (int mi = 0; mi < 2; ++mi)
    #pragma unroll
    for (int nt = 0; nt < NT4; ++nt) acc[mi][nt] = (floatx4){0.f, 0.f, 0.f, 0.f};

  for (int k0 = 0; k0 < K; k0 += 64) {
    __syncthreads();
    gload_lds16(gAp, lAp); gAp += 64;
    #pragma unroll
    for (int i = 0; i < NT; ++i)
      gload_lds16(gW0 + (size_t)i * 32 * K, lW0 + i * 2048);
    gW0 += 64;
    __syncthreads();
    #pragma unroll
    for (int ks = 0; ks < 2; ++ks) {
      int sw = ((ks * 4 + quad) ^ (mrow & 7)) * 8;
      short8 af0 = *(const short8*)&As[mrow * 64 + sw];
      short8 af1 = *(const short8*)&As[(16 + mrow) * 64 + sw];
      #pragma unroll
      for (int nt = 0; nt < NT4; ++nt) {
        int rw = w * (NC / 4) + nt * 16 + mrow;
        short8 bf = *(const short8*)&Ws[rw * 64 + sw];
        acc[0][nt] = __builtin_amdgcn_mfma_f32_16x16x32_bf16(af0, bf, acc[0][nt], 0, 0, 0);
        acc[1][nt] = __builtin_amdgcn_mfma_f32_16x16x32_bf16(af1, bf, acc[1][nt], 0, 0, 0);
      }
    }
  }

  if constexpr (LN) {
    float val[2][NT4][4];
    float bv[NT4];
    #pragma unroll
    for (int nt = 0; nt < NT4; ++nt) bv[nt] = bias[w * 64 + nt * 16 + mrow];
    #pragma unroll
    for (int mi = 0; mi < 2; ++mi) {
      #pragma unroll
      for (int r = 0; r < 4; ++r) {
        int gm = bm0 + mi * 16 + quad * 4 + r;
        float sr = 0.f, s2r = 0.f;
        #pragma unroll
        for (int nt = 0; nt < NT4; ++nt) {
          int gn = w * 64 + nt * 16 + mrow;
          float v = acc[mi][nt][r] + bv[nt] + bf2f(resb[(size_t)gm * 256 + gn]);
          val[mi][nt][r] = v; sr += v; s2r += v * v;
        }
        sr += __shfl_xor(sr, 1); s2r += __shfl_xor(s2r, 1);
        sr += __shfl_xor(sr, 2); s2r += __shfl_xor(s2r, 2);
        sr += __shfl_xor(sr, 4); s2r += __shfl_xor(s2r, 4);
        sr += __shfl_xor(sr, 8); s2r += __shfl_xor(s2r, 8);
        if (mrow == 0) { sred[mi * 16 + quad * 4 + r][w][0] = sr; sred[mi * 16 + quad * 4 + r][w][1] = s2r; }
      }
    }
    __syncthreads();
    #pragma unroll
    for (int mi = 0; mi < 2; ++mi) {
      #pragma unroll
      for (int r = 0; r < 4; ++r) {
        int lrow = mi * 16 + quad * 4 + r;
        float S  = sred[lrow][0][0] + sred[lrow][1][0] + sred[lrow][2][0] + sred[lrow][3][0];
        float S2 = sred[lrow][0][1] + sred[lrow][1][1] + sred[lrow][2][1] + sred[lrow][3][1];
        float mean = S * (1.f / 256.f);
        float var = S2 * (1.f / 256.f) - mean * mean;
        float inv = rsqrtf(var + 1e-5f);
        float sr2 = 0.f, s2r2 = 0.f;
        #pragma unroll
        for (int nt = 0; nt < NT4; ++nt) {
          int gn = w * 64 + nt * 16 + mrow;
          float y = (val[mi][nt][r] - mean) * inv * gam[gn] + bet[gn];
          val[mi][nt][r] = y;
          if constexpr (DLN) { sr2 += y; s2r2 += y * y; }
          else out[(size_t)(bm0 + lrow) * 256 + gn] = f2bf(y);
        }
        if constexpr (DLN) {
          sr2 += __shfl_xor(sr2, 1); s2r2 += __shfl_xor(s2r2, 1);
          sr2 += __shfl_xor(sr2, 2); s2r2 += __shfl_xor(s2r2, 2);
          sr2 += __shfl_xor(sr2, 4); s2r2 += __shfl_xor(s2r2, 4);
          sr2 += __shfl_xor(sr2, 8); s2r2 += __shfl_xor(s2r2, 8);
          if (mrow == 0) { sred2[lrow][w][0] = sr2; sred2[lrow][w][1] = s2r2; }
        }
      }
    }
    if constexpr (DLN) {
      __syncthreads();
      #pragma unroll
      for (int mi = 0; mi < 2; ++mi) {
        #pragma unroll
        for (int r = 0; r < 4; ++r) {
          int lrow = mi * 16 + quad * 4 + r;
          float S  = sred2[lrow][0][0] + sred2[lrow][1][0] + sred2[lrow][2][0] + sred2[lrow][3][0];
          float S2 = sred2[lrow][0][1] + sred2[lrow][1][1] + sred2[lrow][2][1] + sred2[lrow][3][1];
          float mean = S * (1.f / 256.f);
          float var = S2 * (1.f / 256.f) - mean * mean;
          float inv = rsqrtf(var + 1e-5f);
          #pragma unroll
          for (int nt = 0; nt < NT4; ++nt) {
            int gn = w * 64 + nt * 16 + mrow;
            float z = (val[mi][nt][r] - mean) * inv * gam2[gn] + bet2[gn];
            out[(size_t)(bm0 + lrow) * 256 + gn] = f2bf(z);
          }
        }
      }
    }
  } else {
    #pragma unroll
    for (int nt = 0; nt < NT4; ++nt) {
      int gn = bn0 + w * (NC / 4) + nt * 16 + mrow;
      float bv = bias[gn];
      #pragma unroll
      for (int mi = 0; mi < 2; ++mi) {
        #pragma unroll
        for (int r = 0; r < 4; ++r) {
          int gm = bm0 + mi * 16 + quad * 4 + r;
          float v = acc[mi][nt][r] + bv;
          if (GELU) v = 0.5f * v * (1.f + erff(v * 0.70710678118654752f));
          out[(size_t)gm * N + gn] = f2bf(v);
        }
      }
    }
  }
}

// ---------------- fused FFN v5: 8-warp/64-row blocks, MERGED 2-k-step stages.
//  16 vmcnt drains per block (was 32): Ws holds 2 k-tiles (64KB); each barrier-pair stages
//  both tiles and computes both. x staged once (Xs 32KB). LDS 128KB, grid 256 = 1 block/CU
//  at 8 waves (same residency as v3 -> isolates drain-count as the variable).
template<bool DLN>
__global__ __launch_bounds__(512) void ffu_kernel(
    const u16* __restrict__ A, const u16* __restrict__ W1, const float* __restrict__ b1,
    const u16* __restrict__ W2, const float* __restrict__ b2,
    const u16* __restrict__ resb,
    const float* __restrict__ gam, const float* __restrict__ bet,
    const float* __restrict__ gam2, const float* __restrict__ bet2,
    u16* __restrict__ out)
{
  __shared__ __align__(16) u16 Xs[4 * 4096];    // 32 KB: x [64r][256k], 4 k-tiles As-format
  __shared__ __align__(16) u16 Ws[2 * 16384];   // 64 KB: two k-tiles of W staging
  __shared__ __align__(16) u16 Hs[4 * 4096];    // 32 KB: gelu(h) quarter As-format
  int t = threadIdx.x, lane = t & 63, w = t >> 6;
  int mrow = lane & 15, quad = lane >> 4;
  int rh = w >> 2, wc = w & 3;                  // row-half (32 rows), col ownership (64 cols)
  int bm0 = blockIdx.x * 64;
  int rA = t >> 3, gcA = (t & 7) ^ (rA & 7);

  // stage full x tile once (drained by first merged-step barrier)
  #pragma unroll
  for (int kt = 0; kt < 4; ++kt)
    gload_lds16(A + (size_t)(bm0 + rA) * 256 + kt * 64 + gcA * 8, Xs + kt * 4096 + w * 512);

  floatx4 yacc[2][4];
  #pragma unroll
  for (int mi = 0; mi < 2; ++mi)
    #pragma unroll
    for (int nt = 0; nt < 4; ++nt) yacc[mi][nt] = (floatx4){0.f, 0.f, 0.f, 0.f};

  for (int nq = 0; nq < 4; ++nq) {
    floatx4 hacc[2][4];
    #pragma unroll
    for (int mi = 0; mi < 2; ++mi)
      #pragma unroll
      for (int nt = 0; nt < 4; ++nt) hacc[mi][nt] = (floatx4){0.f, 0.f, 0.f, 0.f};
    // FF1: 2 merged steps x 2 k-tiles (K = 256)
    for (int kh = 0; kh < 2; ++kh) {
      __syncthreads();   // Ws WAR
      #pragma unroll
      for (int sub = 0; sub < 2; ++sub)
        #pragma unroll
        for (int i = 0; i < 4; ++i)
          gload_lds16(W1 + (size_t)(nq * 256 + i * 64 + rA) * 256 + (kh * 2 + sub) * 64 + gcA * 8,
                      Ws + sub * 16384 + i * 4096 + w * 512);
      __syncthreads();   // drain (covers Xs stage on first pass)
      #pragma unroll
      for (int sub = 0; sub < 2; ++sub) {
        int kt = kh * 2 + sub;
        #pragma unroll
        for (int ks = 0; ks < 2; ++ks) {
          int sw = ((ks * 4 + quad) ^ (mrow & 7)) * 8;
          short8 af0 = *(const short8*)&Xs[kt * 4096 + (rh * 32 + mrow) * 64 + sw];
          short8 af1 = *(const short8*)&Xs[kt * 4096 + (rh * 32 + 16 + mrow) * 64 + sw];
          #pragma unroll
          for (int nt = 0; nt < 4; ++nt) {
            short8 bf = *(const short8*)&Ws[sub * 16384 + (wc * 64 + nt * 16 + mrow) * 64 + sw];
            hacc[0][nt] = __builtin_amdgcn_mfma_f32_16x16x32_bf16(af0, bf, hacc[0][nt], 0, 0, 0);
            hacc[1][nt] = __builtin_amdgcn_mfma_f32_16x16x32_bf16(af1, bf, hacc[1][nt], 0, 0, 0);
          }
        }
      }
    }
    // gelu + bias1 -> Hs (As-format): cc = wc*64 + nt*16 + mrow -> k-tile wc,
    // g = nt*2 + (mrow>>3); off = row*64 + (g^(row&7))*8 + (mrow&7).
    {
      float bv1[4];
      #pragma unroll
      for (int nt = 0; nt < 4; ++nt) bv1[nt] = b1[nq * 256 + wc * 64 + nt * 16 + mrow];
      #pragma unroll
      for (int mi = 0; mi < 2; ++mi) {
        #pragma unroll
        for (int nt = 0; nt < 4; ++nt) {
          int g = nt * 2 + (mrow >> 3);
          #pragma unroll
          for (int r = 0; r < 4; ++r) {
            int row = rh * 32 + mi * 16 + quad * 4 + r;
            float v = hacc[mi][nt][r] + bv1[nt];
            v = 0.5f * v * (1.f + erff(v * 0.70710678118654752f));
            Hs[wc * 4096 + row * 64 + (g ^ (row & 7)) * 8 + (mrow & 7)] = f2bf(v);
          }
        }
      }
    }
    // FF2: 2 merged steps x 2 k-tiles over Hs
    for (int kh = 0; kh < 2; ++kh) {
      __syncthreads();   // Hs RAW (first) + Ws WAR
      #pragma unroll
      for (int sub = 0; sub < 2; ++sub)
        #pragma unroll
        for (int i = 0; i < 4; ++i)
          gload_lds16(W2 + (size_t)(i * 64 + rA) * 1024 + nq * 256 + (kh * 2 + sub) * 64 + gcA * 8,
                      Ws + sub * 16384 + i * 4096 + w * 512);
      __syncthreads();
      #pragma unroll
      for (int sub = 0; sub < 2; ++sub) {
        int kt2 = kh * 2 + sub;
        #pragma unroll
        for (int ks = 0; ks < 2; ++ks) {
          int sw = ((ks * 4 + quad) ^ (mrow & 7)) * 8;
          short8 af0 = *(const short8*)&Hs[kt2 * 4096 + (rh * 32 + mrow) * 64 + sw];
          short8 af1 = *(const short8*)&Hs[kt2 * 4096 + (rh * 32 + 16 + mrow) * 64 + sw];
          #pragma unroll
          for (int nt = 0; nt < 4; ++nt) {
            short8 bf = *(const short8*)&Ws[sub * 16384 + (wc * 64 + nt * 16 + mrow) * 64 + sw];
            yacc[0][nt] = __builtin_amdgcn_mfma_f32_16x16x32_bf16(af0, bf, yacc[0][nt], 0, 0, 0);
            yacc[1][nt] = __builtin_amdgcn_mfma_f32_16x16x32_bf16(af1, bf, yacc[1][nt], 0, 0, 0);
          }
        }
      }
    }
  }
  // epilogue: residual + LN (+DLN). sred aliased into Xs (dead; guarded by barrier).
  __syncthreads();
  float* sred  = (float*)Xs;        // [64 rows][4 wc][2] = 512 floats
  float* sred2 = sred + 512;
  float val[2][4][4];
  float bv[4];
  #pragma unroll
  for (int nt = 0; nt < 4; ++nt) bv[nt] = b2[wc * 64 + nt * 16 + mrow];
  #pragma unroll
  for (int mi = 0; mi < 2; ++mi) {
    #pragma unroll
    for (int r = 0; r < 4; ++r) {
      int row = rh * 32 + mi * 16 + quad * 4 + r;
      int gm = bm0 + row;
      float sr = 0.f, s2r = 0.f;
      #pragma unroll
      for (int nt = 0; nt < 4; ++nt) {
        int gn = wc * 64 + nt * 16 + mrow;
        float v = yacc[mi][nt][r] + bv[nt] + bf2f(resb[(size_t)gm * 256 + gn]);
        val[mi][nt][r] = v; sr += v; s2r += v * v;
      }
      sr += __shfl_xor(sr, 1); s2r += __shfl_xor(s2r, 1);
      sr += __shfl_xor(sr, 2); s2r += __shfl_xor(s2r, 2);
      sr += __shfl_xor(sr, 4); s2r += __shfl_xor(s2r, 4);
      sr += __shfl_xor(sr, 8); s2r += __shfl_xor(s2r, 8);
      if (mrow == 0) { sred[row * 8 + wc * 2 + 0] = sr; sred[row * 8 + wc * 2 + 1] = s2r; }
    }
  }
  __syncthreads();
  #pragma unroll
  for (int mi = 0; mi < 2; ++mi) {
    #pragma unroll
    for (int r = 0; r < 4; ++r) {
      int row = rh * 32 + mi * 16 + quad * 4 + r;
      float S  = sred[row * 8 + 0] + sred[row * 8 + 2] + sred[row * 8 + 4] + sred[row * 8 + 6];
      float S2 = sred[row * 8 + 1] + sred[row * 8 + 3] + sred[row * 8 + 5] + sred[row * 8 + 7];
      float mean = S * (1.f / 256.f);
      float var = S2 * (1.f / 256.f) - mean * mean;
      float inv = rsqrtf(var + 1e-5f);
      float sr2 = 0.f, s2r2 = 0.f;
      #pragma unroll
      for (int nt = 0; nt < 4; ++nt) {
        int gn = wc * 64 + nt * 16 + mrow;
        float y = (val[mi][nt][r] - mean) * inv * gam[gn] + bet[gn];
        val[mi][nt][r] = y;
        if constexpr (DLN) { sr2 += y; s2r2 += y * y; }
        else out[(size_t)(bm0 + row) * 256 + gn] = f2bf(y);
      }
      if constexpr (DLN) {
        sr2 += __shfl_xor(sr2, 1); s2r2 += __shfl_xor(s2r2, 1);
        sr2 += __shfl_xor(sr2, 2); s2r2 += __shfl_xor(s2r2, 2);
        sr2 += __shfl_xor(sr2, 4); s2r2 += __shfl_xor(s2r2, 4);
        sr2 += __shfl_xor(sr2, 8); s2r2 += __shfl_xor(s2r2, 8);
        if (mrow == 0) { sred2[row * 8 + wc * 2 + 0] = sr2; sred2[row * 8 + wc * 2 + 1] = s2r2; }
      }
    }
  }
  if constexpr (DLN) {
    __syncthreads();
    #pragma unroll
    for (int mi = 0; mi < 2; ++mi) {
      #pragma unroll
      for (int r = 0; r < 4; ++r) {
        int row = rh * 32 + mi * 16 + quad * 4 + r;
        float S  = sred2[row * 8 + 0] + sred2[row * 8 + 2] + sred2[row * 8 + 4] + sred2[row * 8 + 6];
        float S2 = sred2[row * 8 + 1] + sred2[row * 8 + 3] + sred2[row * 8 + 5] + sred2[row * 8 + 7];
        float mean = S * (1.f / 256.f);
        float var = S2 * (1.f / 256.f) - mean * mean;
        float inv = rsqrtf(var + 1e-5f);
        #pragma unroll
        for (int nt = 0; nt < 4; ++nt) {
          int gn = wc * 64 + nt * 16 + mrow;
          float z = (val[mi][nt][r] - mean) * inv * gam2[gn] + bet2[gn];
          out[(size_t)(bm0 + row) * 256 + gn] = f2bf(z);
        }
      }
    }
  }
}

// ---- MFMA GEMM 128x128, optional split-K via blockIdx.z (z>1: raw f32 partials out) -------
//      flags: 1=gelu, 2=f32 out, 4=pq-broadcast res
__global__ __launch_bounds__(256) void gemm128_kernel(
    const u16* __restrict__ A, const u16* __restrict__ W, const float* __restrict__ bias,
    const float* __restrict__ res, void* __restrict__ out,
    int M, int N, int K, int flags)
{
  __shared__ __align__(16) u16 As[128 * 64];
  __shared__ __align__(16) u16 Bs[128 * 64];
  int t = threadIdx.x;
  int lane = t & 63, w = t >> 6;
  int wm = w & 1, wn = w >> 1;
  int bn0 = blockIdx.x * 128, bm0 = blockIdx.y * 128;
  int mrow = lane & 15, quad = lane >> 4;
  int z = blockIdx.z, NZ = gridDim.z;
  int Kc = K / NZ, kbase = z * Kc;

  const u16* gA[4]; const u16* gB[4];
  u16* lA[4]; u16* lB[4];
  #pragma unroll
  for (int it = 0; it < 4; ++it) {
    int c = w * 256 + it * 64 + lane;
    int r = c >> 3;
    int gc = (c & 7) ^ (r & 7);
    gA[it] = A + (size_t)(bm0 + r) * K + kbase + gc * 8;
    gB[it] = W + (size_t)(bn0 + r) * K + kbase + gc * 8;
    lA[it] = As + (w * 256 + it * 64) * 8;
    lB[it] = Bs + (w * 256 + it * 64) * 8;
  }
  floatx4 acc[4][4];
  #pragma unroll
  for (int i = 0; i < 4; ++i)
    #pragma unroll
    for (int j = 0; j < 4; ++j)
      acc[i][j] = (floatx4){0.f, 0.f, 0.f, 0.f};
  int sw0 = ((0 * 4 + quad) ^ (mrow & 7)) * 8;
  int sw1 = ((1 * 4 + quad) ^ (mrow & 7)) * 8;

  for (int k0 = 0; k0 < Kc; k0 += 64) {
    __syncthreads();
    #pragma unroll
    for (int it = 0; it < 4; ++it) { gload_lds16(gA[it], lA[it]); gA[it] += 64; }
    #pragma unroll
    for (int it = 0; it < 4; ++it) { gload_lds16(gB[it], lB[it]); gB[it] += 64; }
    __syncthreads();
    #pragma unroll
    for (int ks = 0; ks < 2; ++ks) {
      int sw = ks ? sw1 : sw0;
      short8 af[4], bfr[4];
      #pragma unroll
      for (int mi = 0; mi < 4; ++mi)
        af[mi] = *(const short8*)&As[(wm * 64 + mi * 16 + mrow) * 64 + sw];
      #pragma unroll
      for (int nj = 0; nj < 4; ++nj)
        bfr[nj] = *(const short8*)&Bs[(wn * 64 + nj * 16 + mrow) * 64 + sw];
      #pragma unroll
      for (int mi = 0; mi < 4; ++mi)
        #pragma unroll
        for (int nj = 0; nj < 4; ++nj)
          acc[mi][nj] = __builtin_amdgcn_mfma_f32_16x16x32_bf16(af[mi], bfr[nj], acc[mi][nj], 0, 0, 0);
    }
  }
  if (NZ > 1) {
    // raw partial accumulators -> f32 buffer at out + z*M*N
    float* po = (float*)out + (size_t)z * M * N;
    #pragma unroll
    for (int nj = 0; nj < 4; ++nj) {
      int gn = bn0 + wn * 64 + nj * 16 + mrow;
      #pragma unroll
      for (int mi = 0; mi < 4; ++mi)
        #pragma unroll
        for (int r = 0; r < 4; ++r) {
          int gm = bm0 + wm * 64 + mi * 16 + quad * 4 + r;
          po[(size_t)gm * N + gn] = acc[mi][nj][r];
        }
    }
    return;
  }
  bool do_gelu = (flags & 1) != 0, of32 = (flags & 2) != 0;
  #pragma unroll
  for (int nj = 0; nj < 4; ++nj) {
    int gn = bn0 + wn * 64 + nj * 16 + mrow;
    float bv = bias ? bias[gn] : 0.f;
    #pragma unroll
    for (int mi = 0; mi < 4; ++mi) {
      #pragma unroll
      for (int r = 0; r < 4; ++r) {
        int gm = bm0 + wm * 64 + mi * 16 + quad * 4 + r;
        float v = acc[mi][nj][r] + bv;
        if (do_gelu) v = 0.5f * v * (1.f + erff(v * 0.70710678118654752f));
        if (flags & 4) v += res[(size_t)(gm & 15) * N + gn];
        else if (res) v += res[(size_t)gm * N + gn];
        if (of32) ((float*)out)[(size_t)gm * N + gn] = v;
        else      ((u16*)out)[(size_t)gm * N + gn] = f2bf(v);
      }
    }
  }
}

// ---------------- LayerNorm: one wave per row, 4 rows/block (final output) ----------------
template<int D>
__global__ __launch_bounds__(256) void lnw_kernel(
    const float* __restrict__ in, const float* __restrict__ w, const float* __restrict__ b,
    float* __restrict__ outf, u16* __restrict__ outb)
{
  constexpr int NV = D / 64;
  int lane = threadIdx.x & 63, wv = threadIdx.x >> 6;
  int row = blockIdx.x * 4 + wv;
  const float* xr = in + (size_t)row * D;
  float v[NV];
  float s = 0.f, s2 = 0.f;
  #pragma unroll
  for (int i = 0; i < NV; ++i) {
    v[i] = xr[lane + i * 64];
    s += v[i]; s2 += v[i] * v[i];
  }
  #pragma unroll
  for (int off = 32; off > 0; off >>= 1) { s += __shfl_xor(s, off); s2 += __shfl_xor(s2, off); }
  float mean = s / (float)D;
  float var = s2 / (float)D - mean * mean;
  float inv = rsqrtf(var + 1e-5f);
  #pragma unroll
  for (int i = 0; i < NV; ++i) {
    int col = lane + i * 64;
    float y = (v[i] - mean) * inv * w[col] + b[col];
    size_t o = (size_t)row * D + col;
    if (outf) outf[o] = y;
    if (outb) outb[o] = f2bf(y);
  }
}

// ---------------- encoder self-attention v6: enc5 body (28KB LDS, 5 blocks/CU) with
//                  XCD-affine 1D grid: the 4 qt-blocks of each (b,h) land on one XCD L2 ------
__global__ __launch_bounds__(256, 5) void attn_enc6_kernel(
    const u16* __restrict__ qkv, u16* __restrict__ out)
{
  __shared__ __align__(16) u16 Ks[64 * 40];       // 5120 B
  __shared__ __align__(16) u16 Vt[32 * 72];       // 4608 B
  __shared__ __align__(16) u16 Pl[4 * 32 * 72];   // 18432 B  (total 28160 -> 5 blocks/CU)
  int F = blockIdx.x;
  int xcd = F & 7, jj = F >> 3;
  int pair = xcd * 32 + (jj >> 2), qt = jj & 3;
  int b = pair >> 3, h = pair & 7;
  int t = threadIdx.x, lane = t & 63, w = t >> 6;
  int mrow = lane & 15, quad = lane >> 4;
  int q0 = qt * 128 + w * 32;
  short8 qf[2];
  #pragma unroll
  for (int mi = 0; mi < 2; ++mi)
    qf[mi] = *(const short8*)(qkv + (size_t)(b * CC + q0 + mi * 16 + mrow) * 768 + h * 32 + quad * 8);
  floatx4 o[2][2];
  #pragma unroll
  for (int mi = 0; mi < 2; ++mi)
    #pragma unroll
    for (int di = 0; di < 2; ++di) o[mi][di] = (floatx4){0.f, 0.f, 0.f, 0.f};
  float lst[2][4] = {{0.f,0.f,0.f,0.f},{0.f,0.f,0.f,0.f}};
  const float sc = 0.17677669529663687f * 1.4426950408889634f;
  const floatx4 zf = (floatx4){0.f, 0.f, 0.f, 0.f};
  for (int jt = 0; jt < 8; ++jt) {
    if (jt) __syncthreads();
    {  // K tile: 64 j x 32 d (one u16x8 per thread)
      int j = t >> 2, q4 = (t & 3) * 8;
      uint4 kk = *(const uint4*)(qkv + (size_t)(b * CC + jt * 64 + j) * 768 + 256 + h * 32 + q4);
      *(uint4*)&Ks[j * 40 + q4] = kk;
      // V tile: transpose+permute into Vt[d][jp], jp=(j&15)*4+(j>>4)
      uint4 vv = *(const uint4*)(qkv + (size_t)(b * CC + jt * 64 + j) * 768 + 512 + h * 32 + q4);
      u16 tmp[8]; *(uint4*)tmp = vv;
      int jp = (j & 15) * 4 + (j >> 4);
      #pragma unroll
      for (int i = 0; i < 8; ++i) Vt[(q4 + i) * 72 + jp] = tmp[i];
    }
    __syncthreads();
    floatx4 s[2][4];
    #pragma unroll
    for (int nj = 0; nj < 4; ++nj) {
      short8 bf = *(const short8*)&Ks[(nj * 16 + mrow) * 40 + quad * 8];
      s[0][nj] = __builtin_amdgcn_mfma_f32_16x16x32_bf16(qf[0], bf, zf, 0, 0, 0);
      s[1][nj] = __builtin_amdgcn_mfma_f32_16x16x32_bf16(qf[1], bf, zf, 0, 0, 0);
    }
    #pragma unroll
    for (int mi = 0; mi < 2; ++mi) {
      #pragma unroll
      for (int r = 0; r < 4; ++r) {
        float ps = 0.f; u16 hv[4];
        #pragma unroll
        for (int nj = 0; nj < 4; ++nj) {
          float p = exp2f(s[mi][nj][r] * sc);
          ps += p; hv[nj] = f2bf(p);
        }
        lst[mi][r] += ps;
        *(uint2*)&Pl[(w * 32 + mi * 16 + quad * 4 + r) * 72 + mrow * 4] = *(uint2*)hv;
      }
    }
    #pragma unroll
    for (int ks = 0; ks < 2; ++ks) {
      short8 a0 = *(const short8*)&Pl[(w * 32 + mrow) * 72 + ks * 32 + quad * 8];
      short8 a1 = *(const short8*)&Pl[(w * 32 + 16 + mrow) * 72 + ks * 32 + quad * 8];
      short8 b0 = *(const short8*)&Vt[mrow * 72 + ks * 32 + quad * 8];
      short8 b1 = *(const short8*)&Vt[(16 + mrow) * 72 + ks * 32 + quad * 8];
      o[0][0] = __builtin_amdgcn_mfma_f32_16x16x32_bf16(a0, b0, o[0][0], 0, 0, 0);
      o[0][1] = __builtin_amdgcn_mfma_f32_16x16x32_bf16(a0, b1, o[0][1], 0, 0, 0);
      o[1][0] = __builtin_amdgcn_mfma_f32_16x16x32_bf16(a1, b0, o[1][0], 0, 0, 0);
      o[1][1] = __builtin_amdgcn_mfma_f32_16x16x32_bf16(a1, b1, o[1][1], 0, 0, 0);
    }
  }
  #pragma unroll
  for (int mi = 0; mi < 2; ++mi) {
    #pragma unroll
    for (int r = 0; r < 4; ++r) {
      float l = lst[mi][r];
      l += __shfl_xor(l, 1); l += __shfl_xor(l, 2);
      l += __shfl_xor(l, 4); l += __shfl_xor(l, 8);
      float inv = 1.f / l;
      int row = b * CC + q0 + mi * 16 + quad * 4 + r;
      #pragma unroll
      for (int di = 0; di < 2; ++di)
        out[(size_t)row * DD + h * 32 + di * 16 + mrow] = f2bf(o[mi][di][r] * inv);
    }
  }
}

// ---------------- fused prefix cross-attention: K/V projections folded through the
//  attention contractions (S = Qc·tln, T = P·tln, O = (T/l)·Wcv^T + bv).
//  Grid is (b, h) so XCD = b&7: each XCD L2 holds 4 tln batches (1MB) reused by 8 heads. ----
__global__ __launch_bounds__(256) void attn_preff_kernel(
    const u16* __restrict__ tln, const u16* __restrict__ wcb,
    const u16* __restrict__ qcg, const float* __restrict__ bkv,
    u16* __restrict__ out)
{
  __shared__ __align__(16) u16 Ajc[64 * 264];   // tln tile [j][c]      33792 B
  __shared__ __align__(16) u16 Acj[256 * 72];   // tln^T tile [c][j]    36864 B
  __shared__ __align__(16) u16 Qs[16 * 264];    // Qc_h [q][c]           8448 B
  __shared__ __align__(16) u16 Ps[16 * 72];     // P tile [q][j]         2304 B
  __shared__ __align__(16) u16 Ts[16 * 264];    // T/l [q][c]            8448 B
  __shared__ float Lred[4][16];
  int b = blockIdx.x, h = blockIdx.y;
  int t = threadIdx.x, lane = t & 63, w = t >> 6;
  int mrow = lane & 15, quad = lane >> 4;
  const float sc = 0.08838834764831845f * 1.4426950408889634f;
  const floatx4 zf = (floatx4){0.f, 0.f, 0.f, 0.f};
  {  // stage Qc_h: 16 x 256, thread t -> row t>>4, 16 cols
    int q = t >> 4, c0 = (t & 15) * 16;
    *(uint4*)&Qs[q * 264 + c0]     = *(const uint4*)(qcg + ((size_t)h * 16 + q) * 256 + c0);
    *(uint4*)&Qs[q * 264 + c0 + 8] = *(const uint4*)(qcg + ((size_t)h * 16 + q) * 256 + c0 + 8);
  }
  floatx4 Tacc[4] = {zf, zf, zf, zf};   // T[q][c], warp owns c in [w*64, w*64+64)
  float lacc = 0.f;
  const u16* tb = tln + (size_t)b * 512 * 256;
  for (int jt = 0; jt < 8; ++jt) {
    __syncthreads();   // WAR vs prev tile's reads; covers Qs staging on iter 0
    {  // stage tln tile [64 j][256 c] both orientations; thread: row j=t>>2, cols (t&3)*64..+64
      int j = t >> 2, c0 = (t & 3) * 64;
      #pragma unroll
      for (int u = 0; u < 8; ++u) {
        uint4 v = *(const uint4*)(tb + (size_t)(jt * 64 + j) * 256 + c0 + u * 8);
        *(uint4*)&Ajc[j * 264 + c0 + u * 8] = v;
        u16 tmp[8]; *(uint4*)tmp = v;
        #pragma unroll
        for (int i = 0; i < 8; ++i) Acj[(c0 + u * 8 + i) * 72 + j] = tmp[i];
      }
    }
    __syncthreads();
    // S^T[j,q]: warp w handles j in [w*16, w*16+16); K = 256 c
    floatx4 s = zf;
    #pragma unroll
    for (int kk = 0; kk < 8; ++kk) {
      short8 af = *(const short8*)&Ajc[(w * 16 + mrow) * 264 + kk * 32 + quad * 8];
      short8 bf = *(const short8*)&Qs[mrow * 264 + kk * 32 + quad * 8];
      s = __builtin_amdgcn_mfma_f32_16x16x32_bf16(af, bf, s, 0, 0, 0);
    }
    // lane holds s[r] for j = w*16 + quad*4 + r, q = mrow
    u16 hv[4]; float ps = 0.f;
    #pragma unroll
    for (int r = 0; r < 4; ++r) {
      float p = exp2f(s[r] * sc);
      ps += p; hv[r] = f2bf(p);
    }
    ps += __shfl_xor(ps, 16); ps += __shfl_xor(ps, 32);  // sum over warp's 16 j (per q=mrow)
    lacc += ps;
    *(uint2*)&Ps[mrow * 72 + w * 16 + quad * 4] = *(uint2*)hv;
    __syncthreads();
    // T += P @ tln_tile: warp w owns c-tiles [w*64..); K = 64 j
    #pragma unroll
    for (int kk = 0; kk < 2; ++kk) {
      short8 af = *(const short8*)&Ps[mrow * 72 + kk * 32 + quad * 8];
      #pragma unroll
      for (int ct = 0; ct < 4; ++ct) {
        short8 bf = *(const short8*)&Acj[(w * 64 + ct * 16 + mrow) * 72 + kk * 32 + quad * 8];
        Tacc[ct] = __builtin_amdgcn_mfma_f32_16x16x32_bf16(af, bf, Tacc[ct], 0, 0, 0);
      }
    }
  }
  if (lane < 16) Lred[w][lane] = lacc;   // lacc valid for q = mrow = lane
  __syncthreads();
  // normalize T, write Ts[q][c] (lane: q = quad*4+r, c = w*64 + ct*16 + mrow)
  #pragma unroll
  for (int r = 0; r < 4; ++r) {
    int q = quad * 4 + r;
    float l = Lred[0][q] + Lred[1][q] + Lred[2][q] + Lred[3][q];
    float inv = 1.f / l;
    #pragma unroll
    for (int ct = 0; ct < 4; ++ct)
      Ts[q * 264 + w * 64 + ct * 16 + mrow] = f2bf(Tacc[ct][r] * inv);
  }
  __syncthreads();
  // O = Ts @ Wcv_h^T + bv: warp w owns d-tiles [w*32, w*32+32); K = 256 c
  const u16* wv = wcb + (size_t)(1024 + h * 128) * 256;
  floatx4 oacc[2] = {zf, zf};
  #pragma unroll
  for (int kk = 0; kk < 8; ++kk) {
    short8 af = *(const short8*)&Ts[mrow * 264 + kk * 32 + quad * 8];
    #pragma unroll
    for (int dt = 0; dt < 2; ++dt) {
      short8 bf = *(const short8*)(wv + (size_t)(w * 32 + dt * 16 + mrow) * 256 + kk * 32 + quad * 8);
      oacc[dt] = __builtin_amdgcn_mfma_f32_16x16x32_bf16(af, bf, oacc[dt], 0, 0, 0);
    }
  }
  #pragma unroll
  for (int dt = 0; dt < 2; ++dt) {
    int d = w * 32 + dt * 16 + mrow;
    float bv = bkv[1024 + h * 128 + d];
    #pragma unroll
    for (int r = 0; r < 4; ++r) {
      int q = quad * 4 + r;
      out[((size_t)(b * 16 + q)) * 1024 + h * 128 + d] = f2bf(oacc[dt][r] + bv);
    }
  }
}

extern "C" void kernel_launch(void* const* d_in, const int* in_sizes, int n_in,
                              void* d_out, int out_size, void* d_ws, size_t ws_size,
                              hipStream_t stream)
{
  const int* vi = (const int*)d_in[0];
  const int* si = (const int*)d_in[1];
  const int* mk = (const int*)d_in[2];
  const float* ve   = (const float*)d_in[3];
  const float* se   = (const float*)d_in[4];
  const float* lpe  = (const float*)d_in[5];
  const float* cpe  = (const float*)d_in[6];
  const float* eiw  = (const float*)d_in[7];
  const float* eib  = (const float*)d_in[8];
  const float* eow  = (const float*)d_in[9];
  const float* eob  = (const float*)d_in[10];
  const float* f1w  = (const float*)d_in[11];
  const float* f1b  = (const float*)d_in[12];
  const float* f2w  = (const float*)d_in[13];
  const float* f2b  = (const float*)d_in[14];
  const float* n1w  = (const float*)d_in[15];
  const float* n1b  = (const float*)d_in[16];
  const float* n2w  = (const float*)d_in[17];
  const float* n2b  = (const float*)d_in[18];
  const float* tlw  = (const float*)d_in[19];
  const float* tlb  = (const float*)d_in[20];
  const float* thw  = (const float*)d_in[21];
  const float* thb  = (const float*)d_in[22];
  const float* pq   = (const float*)d_in[23];
  const float* paiw = (const float*)d_in[24];
  const float* paib = (const float*)d_in[25];
  const float* paow = (const float*)d_in[26];
  const float* paob = (const float*)d_in[27];
  const float* pnw  = (const float*)d_in[28];
  const float* pnb  = (const float*)d_in[29];

  const int NROW = BB * CC;  // 16384
  const size_t MB = 1048576;
  char* base = (char*)d_ws;
  // encoder phase:
  u16* xb   = (u16*)(base);                // [0,8M)   bf16 residual stream (post-LN)
  u16* qkvb = (u16*)(base + 8 * MB);       // [8M,32M)
  u16* atto = (u16*)(base + 32 * MB);      // [32M,40M)
  u16* tln  = (u16*)(base + 96 * MB);      // [96M,104M)
  // folded-weight region [64M,70M):
  u16* wcb   = (u16*)(base + 64 * MB);     // [64M,65M)  Wc = Wkv @ th_w, bf16 [2048,256]
  u16* thwTb = (u16*)(base + 65 * MB);     // [65M,65.5M) th_w^T bf16 [256,1024]
  float* bkv = (float*)(base + 66 * MB);   // [66M,66M+8K) folded KV bias fp32 [2048]
  u16* wckT  = (u16*)(base + 67 * MB);     // [67M,67.5M) Wck^T bf16 [256,1024]
  u16* qcg   = (u16*)(base + 68 * MB);     // [68M,+64K)  Qc bf16 [8][16][256]
  float* skpart = (float*)(base + 80 * MB);// [80M,88M) split-K f32 partials
  u16* wbf  = (u16*)(base + 104 * MB);     // [104M,~119M)
  u16* qh    = (u16*)(base + 120 * MB);    // [120M,+256K) qh scratch (rows 16..127 garbage)
  u16* prefo = (u16*)(base + 121 * MB);    // [121M,+1M)
  float* prefout = (float*)(base + 122 * MB);

  u16* eiw_b  = wbf + 0;
  u16* eow_b  = wbf + 786432;
  u16* f1w_b  = wbf + 1048576;
  u16* f2w_b  = wbf + 2097152;
  u16* thw_b  = wbf + 3145728;
  u16* paiw_b = wbf + 3407872;
  u16* paow_b = wbf + 6553600;
  u16* pqb    = wbf + 7602176;
  u16* veb    = wbf + 7618560;
  u16* seb    = wbf + 7749888;
  u16* lpeb   = wbf + 7750656;
  u16* cpeb   = wbf + 7754752;

  dim3 blk(256);
  dim3 blk512(512);
  cvt_kernel<<<7701, blk, 0, stream>>>(eiw, eow, f1w, f2w, thw, paiw, paow, pq,
                                       ve, se, lpe, cpe, wbf);
  // weight fold: Wc[n,d] = sum_h Wkv[n,h]*th_w[h,d]; bkv[n] = Wkv[n,:]·th_b + pa_in_b[1024+n]
  thwT_kernel<<<256, blk, 0, stream>>>(thw, thwTb);
  biasfold_kernel<<<512, blk, 0, stream>>>(paiw_b + (size_t)HH * HH, thb, paib, bkv);
  gemm128_kernel<<<dim3(2, 16, 4), blk, 0, stream>>>(
      paiw_b + (size_t)HH * HH, thwTb, nullptr, nullptr, skpart, 2048, 256, HH, 0);
  redk_kernel<<<512, blk, 0, stream>>>(skpart, nullptr, nullptr, nullptr, wcb,
                                       256, 4, 2048 * 256, 0);
  // qh = pq @ Wq^T via split-K (latency-bound tail fix)
  gemm128_kernel<<<dim3(8, 1, 8), blk, 0, stream>>>(
      pqb, paiw_b, nullptr, nullptr, skpart, 128, 1024, HH, 0);
  redk_kernel<<<128, blk, 0, stream>>>(skpart, paib, nullptr, nullptr, qh,
                                       1024, 8, 128 * 1024, 0);
  bT_kernel<<<256, blk, 0, stream>>>(wcb, wckT);
  qc_kernel<<<8, blk, 0, stream>>>(qh, wckT, qcg);
  embed_kernel<<<NROW/2, blk, 0, stream>>>(vi, si, mk, veb, seb, lpeb, cpeb, xb);
  for (int i = 0; i < NLAY; ++i) {
    gwide_kernel<384, false, false, false><<<dim3(2, NROW/32), blk, 0, stream>>>(
        xb, eiw_b + (size_t)i*768*DD, eib + i*768, nullptr, nullptr, nullptr, nullptr, nullptr,
        qkvb, 768, DD);
    attn_enc6_kernel<<<1024, blk, 0, stream>>>(qkvb, atto);
    gwide_kernel<256, false, true, false><<<dim3(1, NROW/32), blk, 0, stream>>>(
        atto, eow_b + (size_t)i*DD*DD, eob + i*DD, xb, n1w + i*DD, n1b + i*DD, nullptr, nullptr,
        xb, DD, DD);
    // fused FF1+gelu+FF2+res+LN v5: merged 2-k-step stages (16 drains), 128KB LDS
    if (i < NLAY - 1) {
      ffu_kernel<false><<<NROW/64, blk512, 0, stream>>>(
          xb, f1w_b + (size_t)i*HH*DD, f1b + i*HH, f2w_b + (size_t)i*DD*HH, f2b + i*DD,
          xb, n2w + i*DD, n2b + i*DD, nullptr, nullptr, xb);
    } else {
      ffu_kernel<true><<<NROW/64, blk512, 0, stream>>>(
          xb, f1w_b + (size_t)i*HH*DD, f1b + i*HH, f2w_b + (size_t)i*DD*HH, f2b + i*DD,
          xb, n2w + i*DD, n2b + i*DD, tlw, tlb, tln);
    }
  }
  // fused prefix cross-attention (b-major grid: XCD = b&7, tln L2-resident per XCD)
  attn_preff_kernel<<<dim3(BB, 8), blk, 0, stream>>>(tln, wcb, qcg, bkv, prefo);
  // split-K out-proj
  gemm128_kernel<<<dim3(1024/128, (BB*PP)/128, 4), blk, 0, stream>>>(
      prefo, paow_b, nullptr, nullptr, skpart, BB*PP, HH, HH, 0);
  redk_kernel<<<512, blk, 0, stream>>>(skpart, paob, pq, prefout, nullptr,
                                       1024, 4, BB*PP*HH, 4);
  lnw_kernel<1024><<<(BB*PP)/4, blk, 0, stream>>>(prefout, pnw, pnb, (float*)d_out, nullptr);
}

// Round 16
// 632.269 us; speedup vs baseline: 1.3405x; 1.0184x over previous
//
#include <hip/hip_runtime.h>
#include <hip/hip_bf16.h>

typedef unsigned short u16;
typedef unsigned int u32;
typedef __attribute__((ext_vector_type(8))) short short8;
typedef __attribute__((ext_vector_type(4))) float floatx4;

#define BB 32
#define CC 512
#define LL 16
#define DD 256
#define HH 1024
#define PP 16
#define NLAY 4

__device__ __forceinline__ float bf2f(u16 u) {
  u32 x = ((u32)u) << 16; float f; __builtin_memcpy(&f, &x, 4); return f;
}
__device__ __forceinline__ u16 f2bf(float f) {
  __hip_bfloat16 h = __float2bfloat16(f);
  u16 r; __builtin_memcpy(&r, &h, 2); return r;
}
__device__ __forceinline__ void gload_lds16(const u16* g, u16* l) {
  __builtin_amdgcn_global_load_lds(
      (const __attribute__((address_space(1))) void*)g,
      (__attribute__((address_space(3))) void*)l, 16, 0, 0);
}

// ---------------- fp32 -> bf16 conversion: 8 weight tensors + 4 embedding tables ----------------
__global__ __launch_bounds__(256) void cvt_kernel(
    const float* __restrict__ s0, const float* __restrict__ s1,
    const float* __restrict__ s2, const float* __restrict__ s3,
    const float* __restrict__ s4, const float* __restrict__ s5,
    const float* __restrict__ s6, const float* __restrict__ s7,
    const float* __restrict__ s8, const float* __restrict__ s9,
    const float* __restrict__ s10, const float* __restrict__ s11,
    u16* __restrict__ dst)
{
  const float* srcs[12] = {s0, s1, s2, s3, s4, s5, s6, s7, s8, s9, s10, s11};
  const int pfx[12] = {786432, 1048576, 2097152, 3145728, 3407872, 6553600, 7602176,
                       7618560, 7749888, 7750656, 7754752, 7885824};
  int e = (blockIdx.x * 256 + threadIdx.x) * 4;
  int seg = 0;
  while (e >= pfx[seg]) seg++;
  int start = seg ? pfx[seg - 1] : 0;
  float4 f = *(const float4*)(srcs[seg] + (e - start));
  u16 o[4] = {f2bf(f.x), f2bf(f.y), f2bf(f.z), f2bf(f.w)};
  *(uint2*)(dst + e) = *(const uint2*)o;
}

// ---------------- th_w [1024,256] fp32 -> bf16 transposed [256,1024] (K-major for fold GEMM) ---
__global__ __launch_bounds__(256) void thwT_kernel(
    const float* __restrict__ thw, u16* __restrict__ out)
{
  __shared__ float tile[32][33];
  int bx = blockIdx.x & 7, by = blockIdx.x >> 3;   // bx: d-tile (8), by: h-tile (32)
  int tx = threadIdx.x & 31, ty = threadIdx.x >> 5;
  #pragma unroll
  for (int i = 0; i < 4; ++i) {
    int h = by * 32 + ty + i * 8, d = bx * 32 + tx;
    tile[ty + i * 8][tx] = thw[h * 256 + d];
  }
  __syncthreads();
  #pragma unroll
  for (int i = 0; i < 4; ++i) {
    int d = bx * 32 + ty + i * 8, h = by * 32 + tx;
    out[d * 1024 + h] = f2bf(tile[tx][ty + i * 8]);
  }
}

// ---------------- bf16 transpose [1024,256] -> [256,1024] (Wck^T for Qc fold) ----------------
__global__ __launch_bounds__(256) void bT_kernel(
    const u16* __restrict__ in, u16* __restrict__ out)
{
  __shared__ u16 tile[32][33];
  int bx = blockIdx.x & 7, by = blockIdx.x >> 3;   // bx: c-tile (8), by: hd-tile (32)
  int tx = threadIdx.x & 31, ty = threadIdx.x >> 5;
  #pragma unroll
  for (int i = 0; i < 4; ++i) {
    int hd = by * 32 + ty + i * 8, c = bx * 32 + tx;
    tile[ty + i * 8][tx] = in[hd * 256 + c];
  }
  __syncthreads();
  #pragma unroll
  for (int i = 0; i < 4; ++i) {
    int c = bx * 32 + ty + i * 8, hd = by * 32 + tx;
    out[c * 1024 + hd] = tile[tx][ty + i * 8];
  }
}

// ---------------- Qc fold: Qc[h][q][c] = sum_d qh[q, h*128+d] * Wck[h*128+d, c] ------------
__global__ __launch_bounds__(256) void qc_kernel(
    const u16* __restrict__ qh, const u16* __restrict__ wckT, u16* __restrict__ qcg)
{
  int h = blockIdx.x;
  int t = threadIdx.x, lane = t & 63, w = t >> 6;
  int mrow = lane & 15, quad = lane >> 4;
  const floatx4 zf = (floatx4){0.f, 0.f, 0.f, 0.f};
  floatx4 acc[4] = {zf, zf, zf, zf};
  #pragma unroll
  for (int kk = 0; kk < 4; ++kk) {
    short8 af = *(const short8*)(qh + (size_t)mrow * 1024 + h * 128 + kk * 32 + quad * 8);
    #pragma unroll
    for (int ct = 0; ct < 4; ++ct) {
      int c = w * 64 + ct * 16 + mrow;
      short8 bf = *(const short8*)(wckT + (size_t)c * 1024 + h * 128 + kk * 32 + quad * 8);
      acc[ct] = __builtin_amdgcn_mfma_f32_16x16x32_bf16(af, bf, acc[ct], 0, 0, 0);
    }
  }
  #pragma unroll
  for (int ct = 0; ct < 4; ++ct)
    #pragma unroll
    for (int r = 0; r < 4; ++r)
      qcg[((size_t)h * 16 + quad * 4 + r) * 256 + w * 64 + ct * 16 + mrow] = f2bf(acc[ct][r]);
}

// ---------------- folded KV bias: bkv[n] = Wkv[n,:]·th_b + pa_in_b[1024+n], one wave/row ------
__global__ __launch_bounds__(256) void biasfold_kernel(
    const u16* __restrict__ Wkv, const float* __restrict__ thb,
    const float* __restrict__ paib, float* __restrict__ out)
{
  int wv = threadIdx.x >> 6, lane = threadIdx.x & 63;
  int n = blockIdx.x * 4 + wv;
  const u16* wr = Wkv + (size_t)n * 1024;
  float s = 0.f;
  #pragma unroll
  for (int i = 0; i < 16; ++i) {
    int h = i * 64 + lane;
    s += bf2f(wr[h]) * thb[h];
  }
  #pragma unroll
  for (int off = 32; off; off >>= 1) s += __shfl_xor(s, off);
  if (!lane) out[n] = s + paib[1024 + n];
}

// ---------------- split-K reduce: sum nz f32 partials + bias/res, write f32 or bf16 ----------
__global__ __launch_bounds__(256) void redk_kernel(
    const float* __restrict__ part, const float* __restrict__ bias,
    const float* __restrict__ res, float* __restrict__ outf, u16* __restrict__ outb,
    int N, int nz, int total, int flags)   // flags&4: res row index is (row&15)
{
  int idx = (blockIdx.x * 256 + threadIdx.x) * 4;
  if (idx >= total) return;
  float4 a = *(const float4*)(part + idx);
  for (int z = 1; z < nz; ++z) {
    float4 b = *(const float4*)(part + (size_t)z * total + idx);
    a.x += b.x; a.y += b.y; a.z += b.z; a.w += b.w;
  }
  int row = idx / N, col = idx - row * N;   // 4 consecutive cols, same row (N % 4 == 0)
  float v4[4] = {a.x, a.y, a.z, a.w};
  #pragma unroll
  for (int i = 0; i < 4; ++i) {
    if (bias) v4[i] += bias[col + i];
    if (res) v4[i] += res[(size_t)((flags & 4) ? (row & 15) : row) * N + col + i];
  }
  if (outf) {
    *(float4*)(outf + idx) = *(const float4*)v4;
  } else {
    u16 o[4] = {f2bf(v4[0]), f2bf(v4[1]), f2bf(v4[2]), f2bf(v4[3])};
    *(uint2*)(outb + idx) = *(const uint2*)o;
  }
}

// ---------------- embed + masked mean pool (bf16 tables, 2 clauses/block, u32 loads) --------
__global__ __launch_bounds__(256) void embed_kernel(
    const int* __restrict__ vi, const int* __restrict__ si, const int* __restrict__ mk,
    const u16* __restrict__ veb, const u16* __restrict__ seb,
    const u16* __restrict__ lpeb, const u16* __restrict__ cpeb,
    u16* __restrict__ xb)
{
  int t = threadIdx.x;
  int bc = blockIdx.x * 2 + (t >> 7);
  int c = bc & (CC - 1);
  int dl = (t & 127) * 2;
  int base = bc * LL;
  float a0 = 0.f, a1 = 0.f; int cnt = 0;
  #pragma unroll
  for (int l = 0; l < LL; ++l) {
    if (mk[base + l]) {
      int v = vi[base + l], s = si[base + l];
      u32 vv = *(const u32*)&veb[v * DD + dl];
      u32 sv = *(const u32*)&seb[s * DD + dl];
      u32 lv = *(const u32*)&lpeb[l * DD + dl];
      a0 += bf2f((u16)vv) + bf2f((u16)sv) + bf2f((u16)lv);
      a1 += bf2f((u16)(vv >> 16)) + bf2f((u16)(sv >> 16)) + bf2f((u16)(lv >> 16));
      cnt++;
    }
  }
  u32 cv = *(const u32*)&cpeb[c * DD + dl];
  float inv = 1.f / (float)cnt;
  u32 pk = (u32)f2bf(a0 * inv + bf2f((u16)cv)) | ((u32)f2bf(a1 * inv + bf2f((u16)(cv >> 16))) << 16);
  *(u32*)&xb[(size_t)bc * DD + dl] = pk;
}

// ---------------- wide-N GEMM 32 rows (v2 warp mapping; QKV and attn-out-LN call-sites) ----
template<int NC, bool GELU, bool LN, bool DLN>
__global__ __launch_bounds__(256) void gwide_kernel(
    const u16* __restrict__ A, const u16* __restrict__ W, const float* __restrict__ bias,
    const u16* __restrict__ resb, const float* __restrict__ gam, const float* __restrict__ bet,
    const float* __restrict__ gam2, const float* __restrict__ bet2,
    u16* __restrict__ out, int N, int K)
{
  constexpr int NT = NC / 32;    // staging tile count
  constexpr int NT4 = NC / 64;   // col tiles per warp
  __shared__ __align__(16) u16 As[32 * 64];
  __shared__ __align__(16) u16 Ws[NC * 64];
  __shared__ float sred[32][4][2];
  __shared__ float sred2[32][4][2];
  int t = threadIdx.x, lane = t & 63, w = t >> 6;
  int mrow = lane & 15, quad = lane >> 4;
  int bn0 = blockIdx.x * NC, bm0 = blockIdx.y * 32;

  int rA = t >> 3, gcA = (t & 7) ^ (rA & 7);
  const u16* gAp = A + (size_t)(bm0 + rA) * K + gcA * 8;
  u16* lAp = As + (w * 64) * 8;
  const u16* gW0 = W + (size_t)(bn0 + rA) * K + gcA * 8;
  u16* lW0 = Ws + (w * 64) * 8;

  floatx4 acc[2][NT4];
  #pragma unroll
  for (int mi = 0; mi < 2; ++mi)
    #pragma unroll
    for (int nt = 0; nt < NT4; ++nt) acc[mi][nt] = (floatx4){0.f, 0.f, 0.f, 0.f};

  for (int k0 = 0; k0 < K; k0 += 64) {
    __syncthreads();
    gload_lds16(gAp, lAp); gAp += 64;
    #pragma unroll
    for (int i = 0; i < NT; ++i)
      gload_lds16(gW0 + (size_t)i * 32 * K, lW0 + i * 2048);
    gW0 += 64;
    __syncthreads();
    #pragma unroll
    for (int ks = 0; ks < 2; ++ks) {
      int sw = ((ks * 4 + quad) ^ (mrow & 7)) * 8;
      short8 af0 = *(const short8*)&As[mrow * 64 + sw];
      short8 af1 = *(const short8*)&As[(16 + mrow) * 64 + sw];
      #pragma unroll
      for (int nt = 0; nt < NT4; ++nt) {
        int rw = w * (NC / 4) + nt * 16 + mrow;
        short8 bf = *(const short8*)&Ws[rw * 64 + sw];
        acc[0][nt] = __builtin_amdgcn_mfma_f32_16x16x32_bf16(af0, bf, acc[0][nt], 0, 0, 0);
        acc[1][nt] = __builtin_amdgcn_mfma_f32_16x16x32_bf16(af1, bf, acc[1][nt], 0, 0, 0);
      }
    }
  }

  if constexpr (LN) {
    float val[2][NT4][4];
    float bv[NT4];
    #pragma unroll
    for (int nt = 0; nt < NT4; ++nt) bv[nt] = bias[w * 64 + nt * 16 + mrow];
    #pragma unroll
    for (int mi = 0; mi < 2; ++mi) {
      #pragma unroll
      for (int r = 0; r < 4; ++r) {
        int gm = bm0 + mi * 16 + quad * 4 + r;
        float sr = 0.f, s2r = 0.f;
        #pragma unroll
        for (int nt = 0; nt < NT4; ++nt) {
          int gn = w * 64 + nt * 16 + mrow;
          float v = acc[mi][nt][r] + bv[nt] + bf2f(resb[(size_t)gm * 256 + gn]);
          val[mi][nt][r] = v; sr += v; s2r += v * v;
        }
        sr += __shfl_xor(sr, 1); s2r += __shfl_xor(s2r, 1);
        sr += __shfl_xor(sr, 2); s2r += __shfl_xor(s2r, 2);
        sr += __shfl_xor(sr, 4); s2r += __shfl_xor(s2r, 4);
        sr += __shfl_xor(sr, 8); s2r += __shfl_xor(s2r, 8);
        if (mrow == 0) { sred[mi * 16 + quad * 4 + r][w][0] = sr; sred[mi * 16 + quad * 4 + r][w][1] = s2r; }
      }
    }
    __syncthreads();
    #pragma unroll
    for (int mi = 0; mi < 2; ++mi) {
      #pragma unroll
      for (int r = 0; r < 4; ++r) {
        int lrow = mi * 16 + quad * 4 + r;
        float S  = sred[lrow][0][0] + sred[lrow][1][0] + sred[lrow][2][0] + sred[lrow][3][0];
        float S2 = sred[lrow][0][1] + sred[lrow][1][1] + sred[lrow][2][1] + sred[lrow][3][1];
        float mean = S * (1.f / 256.f);
        float var = S2 * (1.f / 256.f) - mean * mean;
        float inv = rsqrtf(var + 1e-5f);
        float sr2 = 0.f, s2r2 = 0.f;
        #pragma unroll
        for (int nt = 0; nt < NT4; ++nt) {
          int gn = w * 64 + nt * 16 + mrow;
          float y = (val[mi][nt][r] - mean) * inv * gam[gn] + bet[gn];
          val[mi][nt][r] = y;
          if constexpr (DLN) { sr2 += y; s2r2 += y * y; }
          else out[(size_t)(bm0 + lrow) * 256 + gn] = f2bf(y);
        }
        if constexpr (DLN) {
          sr2 += __shfl_xor(sr2, 1); s2r2 += __shfl_xor(s2r2, 1);
          sr2 += __shfl_xor(sr2, 2); s2r2 += __shfl_xor(s2r2, 2);
          sr2 += __shfl_xor(sr2, 4); s2r2 += __shfl_xor(s2r2, 4);
          sr2 += __shfl_xor(sr2, 8); s2r2 += __shfl_xor(s2r2, 8);
          if (mrow == 0) { sred2[lrow][w][0] = sr2; sred2[lrow][w][1] = s2r2; }
        }
      }
    }
    if constexpr (DLN) {
      __syncthreads();
      #pragma unroll
      for (int mi = 0; mi < 2; ++mi) {
        #pragma unroll
        for (int r = 0; r < 4; ++r) {
          int lrow = mi * 16 + quad * 4 + r;
          float S  = sred2[lrow][0][0] + sred2[lrow][1][0] + sred2[lrow][2][0] + sred2[lrow][3][0];
          float S2 = sred2[lrow][0][1] + sred2[lrow][1][1] + sred2[lrow][2][1] + sred2[lrow][3][1];
          float mean = S * (1.f / 256.f);
          float var = S2 * (1.f / 256.f) - mean * mean;
          float inv = rsqrtf(var + 1e-5f);
          #pragma unroll
          for (int nt = 0; nt < NT4; ++nt) {
            int gn = w * 64 + nt * 16 + mrow;
            float z = (val[mi][nt][r] - mean) * inv * gam2[gn] + bet2[gn];
            out[(size_t)(bm0 + lrow) * 256 + gn] = f2bf(z);
          }
        }
      }
    }
  } else {
    #pragma unroll
    for (int nt = 0; nt < NT4; ++nt) {
      int gn = bn0 + w * (NC / 4) + nt * 16 + mrow;
      float bv = bias[gn];
      #pragma unroll
      for (int mi = 0; mi < 2; ++mi) {
        #pragma unroll
        for (int r = 0; r < 4; ++r) {
          int gm = bm0 + mi * 16 + quad * 4 + r;
          float v = acc[mi][nt][r] + bv;
          if (GELU) v = 0.5f * v * (1.f + erff(v * 0.70710678118654752f));
          out[(size_t)gm * N + gn] = f2bf(v);
        }
      }
    }
  }
}

// ---------------- fused FFN v6: v5 (merged 2-k-step stages, 16 drains) + W2-kh0 stage
//  issued BEFORE the gelu phase so its L2 latency hides under the erff VALU work.
//  Barrier count per nq unchanged (8); one of four stage latencies removed from the
//  critical path. LDS 128KB, grid 256, 8 waves/CU.
template<bool DLN>
__global__ __launch_bounds__(512) void ffu_kernel(
    const u16* __restrict__ A, const u16* __restrict__ W1, const float* __restrict__ b1,
    const u16* __restrict__ W2, const float* __restrict__ b2,
    const u16* __restrict__ resb,
    const float* __restrict__ gam, const float* __restrict__ bet,
    const float* __restrict__ gam2, const float* __restrict__ bet2,
    u16* __restrict__ out)
{
  __shared__ __align__(16) u16 Xs[4 * 4096];    // 32 KB: x [64r][256k], 4 k-tiles As-format
  __shared__ __align__(16) u16 Ws[2 * 16384];   // 64 KB: two k-tiles of W staging
  __shared__ __align__(16) u16 Hs[4 * 4096];    // 32 KB: gelu(h) quarter As-format
  int t = threadIdx.x, lane = t & 63, w = t >> 6;
  int mrow = lane & 15, quad = lane >> 4;
  int rh = w >> 2, wc = w & 3;                  // row-half (32 rows), col ownership (64 cols)
  int bm0 = blockIdx.x * 64;
  int rA = t >> 3, gcA = (t & 7) ^ (rA & 7);

  // stage full x tile once (drained by first merged-step barrier)
  #pragma unroll
  for (int kt = 0; kt < 4; ++kt)
    gload_lds16(A + (size_t)(bm0 + rA) * 256 + kt * 64 + gcA * 8, Xs + kt * 4096 + w * 512);

  floatx4 yacc[2][4];
  #pragma unroll
  for (int mi = 0; mi < 2; ++mi)
    #pragma unroll
    for (int nt = 0; nt < 4; ++nt) yacc[mi][nt] = (floatx4){0.f, 0.f, 0.f, 0.f};

  for (int nq = 0; nq < 4; ++nq) {
    floatx4 hacc[2][4];
    #pragma unroll
    for (int mi = 0; mi < 2; ++mi)
      #pragma unroll
      for (int nt = 0; nt < 4; ++nt) hacc[mi][nt] = (floatx4){0.f, 0.f, 0.f, 0.f};
    // FF1: 2 merged steps x 2 k-tiles (K = 256)
    for (int kh = 0; kh < 2; ++kh) {
      __syncthreads();   // Ws WAR
      #pragma unroll
      for (int sub = 0; sub < 2; ++sub)
        #pragma unroll
        for (int i = 0; i < 4; ++i)
          gload_lds16(W1 + (size_t)(nq * 256 + i * 64 + rA) * 256 + (kh * 2 + sub) * 64 + gcA * 8,
                      Ws + sub * 16384 + i * 4096 + w * 512);
      __syncthreads();   // drain (covers Xs stage on first pass)
      #pragma unroll
      for (int sub = 0; sub < 2; ++sub) {
        int kt = kh * 2 + sub;
        #pragma unroll
        for (int ks = 0; ks < 2; ++ks) {
          int sw = ((ks * 4 + quad) ^ (mrow & 7)) * 8;
          short8 af0 = *(const short8*)&Xs[kt * 4096 + (rh * 32 + mrow) * 64 + sw];
          short8 af1 = *(const short8*)&Xs[kt * 4096 + (rh * 32 + 16 + mrow) * 64 + sw];
          #pragma unroll
          for (int nt = 0; nt < 4; ++nt) {
            short8 bf = *(const short8*)&Ws[sub * 16384 + (wc * 64 + nt * 16 + mrow) * 64 + sw];
            hacc[0][nt] = __builtin_amdgcn_mfma_f32_16x16x32_bf16(af0, bf, hacc[0][nt], 0, 0, 0);
            hacc[1][nt] = __builtin_amdgcn_mfma_f32_16x16x32_bf16(af1, bf, hacc[1][nt], 0, 0, 0);
          }
        }
      }
    }
    // all waves done reading Ws (FF1) before W2 prefetch overwrites it
    __syncthreads();
    // prefetch W2 merged-step kh=0 (both k-tiles): latency hides under gelu below
    #pragma unroll
    for (int sub = 0; sub < 2; ++sub)
      #pragma unroll
      for (int i = 0; i < 4; ++i)
        gload_lds16(W2 + (size_t)(i * 64 + rA) * 1024 + nq * 256 + sub * 64 + gcA * 8,
                    Ws + sub * 16384 + i * 4096 + w * 512);
    // gelu + bias1 -> Hs (As-format): cc = wc*64 + nt*16 + mrow -> k-tile wc,
    // g = nt*2 + (mrow>>3); off = row*64 + (g^(row&7))*8 + (mrow&7).
    {
      float bv1[4];
      #pragma unroll
      for (int nt = 0; nt < 4; ++nt) bv1[nt] = b1[nq * 256 + wc * 64 + nt * 16 + mrow];
      #pragma unroll
      for (int mi = 0; mi < 2; ++mi) {
        #pragma unroll
        for (int nt = 0; nt < 4; ++nt) {
          int g = nt * 2 + (mrow >> 3);
          #pragma unroll
          for (int r = 0; r < 4; ++r) {
            int row = rh * 32 + mi * 16 + quad * 4 + r;
            float v = hacc[mi][nt][r] + bv1[nt];
            v = 0.5f * v * (1.f + erff(v * 0.70710678118654752f));
            Hs[wc * 4096 + row * 64 + (g ^ (row & 7)) * 8 + (mrow & 7)] = f2bf(v);
          }
        }
      }
    }
    __syncthreads();   // drains W2-kh0 loads (vmcnt) + Hs writes (lgkm)
    // FF2 merged step kh=0: compute both k-tiles (already staged)
    #pragma unroll
    for (int sub = 0; sub < 2; ++sub) {
      int kt2 = sub;
      #pragma unroll
      for (int ks = 0; ks < 2; ++ks) {
        int sw = ((ks * 4 + quad) ^ (mrow & 7)) * 8;
        short8 af0 = *(const short8*)&Hs[kt2 * 4096 + (rh * 32 + mrow) * 64 + sw];
        short8 af1 = *(const short8*)&Hs[kt2 * 4096 + (rh * 32 + 16 + mrow) * 64 + sw];
        #pragma unroll
        for (int nt = 0; nt < 4; ++nt) {
          short8 bf = *(const short8*)&Ws[sub * 16384 + (wc * 64 + nt * 16 + mrow) * 64 + sw];
          yacc[0][nt] = __builtin_amdgcn_mfma_f32_16x16x32_bf16(af0, bf, yacc[0][nt], 0, 0, 0);
          yacc[1][nt] = __builtin_amdgcn_mfma_f32_16x16x32_bf16(af1, bf, yacc[1][nt], 0, 0, 0);
        }
      }
    }
    // FF2 merged step kh=1: stage + compute
    __syncthreads();   // Ws WAR
    #pragma unroll
    for (int sub = 0; sub < 2; ++sub)
      #pragma unroll
      for (int i = 0; i < 4; ++i)
        gload_lds16(W2 + (size_t)(i * 64 + rA) * 1024 + nq * 256 + (2 + sub) * 64 + gcA * 8,
                    Ws + sub * 16384 + i * 4096 + w * 512);
    __syncthreads();
    #pragma unroll
    for (int sub = 0; sub < 2; ++sub) {
      int kt2 = 2 + sub;
      #pragma unroll
      for (int ks = 0; ks < 2; ++ks) {
        int sw = ((ks * 4 + quad) ^ (mrow & 7)) * 8;
        short8 af0 = *(const short8*)&Hs[kt2 * 4096 + (rh * 32 + mrow) * 64 + sw];
        short8 af1 = *(const short8*)&Hs[kt2 * 4096 + (rh * 32 + 16 + mrow) * 64 + sw];
        #pragma unroll
        for (int nt = 0; nt < 4; ++nt) {
          short8 bf = *(const short8*)&Ws[sub * 16384 + (wc * 64 + nt * 16 + mrow) * 64 + sw];
          yacc[0][nt] = __builtin_amdgcn_mfma_f32_16x16x32_bf16(af0, bf, yacc[0][nt], 0, 0, 0);
          yacc[1][nt] = __builtin_amdgcn_mfma_f32_16x16x32_bf16(af1, bf, yacc[1][nt], 0, 0, 0);
        }
      }
    }
  }
  // epilogue: residual + LN (+DLN). sred aliased into Xs (dead; guarded by barrier).
  __syncthreads();
  float* sred  = (float*)Xs;        // [64 rows][4 wc][2] = 512 floats
  float* sred2 = sred + 512;
  float val[2][4][4];
  float bv[4];
  #pragma unroll
  for (int nt = 0; nt < 4; ++nt) bv[nt] = b2[wc * 64 + nt * 16 + mrow];
  #pragma unroll
  for (int mi = 0; mi < 2; ++mi) {
    #pragma unroll
    for (int r = 0; r < 4; ++r) {
      int row = rh * 32 + mi * 16 + quad * 4 + r;
      int gm = bm0 + row;
      float sr = 0.f, s2r = 0.f;
      #pragma unroll
      for (int nt = 0; nt < 4; ++nt) {
        int gn = wc * 64 + nt * 16 + mrow;
        float v = yacc[mi][nt][r] + bv[nt] + bf2f(resb[(size_t)gm * 256 + gn]);
        val[mi][nt][r] = v; sr += v; s2r += v * v;
      }
      sr += __shfl_xor(sr, 1); s2r += __shfl_xor(s2r, 1);
      sr += __shfl_xor(sr, 2); s2r += __shfl_xor(s2r, 2);
      sr += __shfl_xor(sr, 4); s2r += __shfl_xor(s2r, 4);
      sr += __shfl_xor(sr, 8); s2r += __shfl_xor(s2r, 8);
      if (mrow == 0) { sred[row * 8 + wc * 2 + 0] = sr; sred[row * 8 + wc * 2 + 1] = s2r; }
    }
  }
  __syncthreads();
  #pragma unroll
  for (int mi = 0; mi < 2; ++mi) {
    #pragma unroll
    for (int r = 0; r < 4; ++r) {
      int row = rh * 32 + mi * 16 + quad * 4 + r;
      float S  = sred[row * 8 + 0] + sred[row * 8 + 2] + sred[row * 8 + 4] + sred[row * 8 + 6];
      float S2 = sred[row * 8 + 1] + sred[row * 8 + 3] + sred[row * 8 + 5] + sred[row * 8 + 7];
      float mean = S * (1.f / 256.f);
      float var = S2 * (1.f / 256.f) - mean * mean;
      float inv = rsqrtf(var + 1e-5f);
      float sr2 = 0.f, s2r2 = 0.f;
      #pragma unroll
      for (int nt = 0; nt < 4; ++nt) {
        int gn = wc * 64 + nt * 16 + mrow;
        float y = (val[mi][nt][r] - mean) * inv * gam[gn] + bet[gn];
        val[mi][nt][r] = y;
        if constexpr (DLN) { sr2 += y; s2r2 += y * y; }
        else out[(size_t)(bm0 + row) * 256 + gn] = f2bf(y);
      }
      if constexpr (DLN) {
        sr2 += __shfl_xor(sr2, 1); s2r2 += __shfl_xor(s2r2, 1);
        sr2 += __shfl_xor(sr2, 2); s2r2 += __shfl_xor(s2r2, 2);
        sr2 += __shfl_xor(sr2, 4); s2r2 += __shfl_xor(s2r2, 4);
        sr2 += __shfl_xor(sr2, 8); s2r2 += __shfl_xor(s2r2, 8);
        if (mrow == 0) { sred2[row * 8 + wc * 2 + 0] = sr2; sred2[row * 8 + wc * 2 + 1] = s2r2; }
      }
    }
  }
  if constexpr (DLN) {
    __syncthreads();
    #pragma unroll
    for (int mi = 0; mi < 2; ++mi) {
      #pragma unroll
      for (int r = 0; r < 4; ++r) {
        int row = rh * 32 + mi * 16 + quad * 4 + r;
        float S  = sred2[row * 8 + 0] + sred2[row * 8 + 2] + sred2[row * 8 + 4] + sred2[row * 8 + 6];
        float S2 = sred2[row * 8 + 1] + sred2[row * 8 + 3] + sred2[row * 8 + 5] + sred2[row * 8 + 7];
        float mean = S * (1.f / 256.f);
        float var = S2 * (1.f / 256.f) - mean * mean;
        float inv = rsqrtf(var + 1e-5f);
        #pragma unroll
        for (int nt = 0; nt < 4; ++nt) {
          int gn = wc * 64 + nt * 16 + mrow;
          float z = (val[mi][nt][r] - mean) * inv * gam2[gn] + bet2[gn];
          out[(size_t)(bm0 + row) * 256 + gn] = f2bf(z);
        }
      }
    }
  }
}

// ---- MFMA GEMM 128x128, optional split-K via blockIdx.z (z>1: raw f32 partials out) -------
//      flags: 1=gelu, 2=f32 out, 4=pq-broadcast res
__global__ __launch_bounds__(256) void gemm128_kernel(
    const u16* __restrict__ A, const u16* __restrict__ W, const float* __restrict__ bias,
    const float* __restrict__ res, void* __restrict__ out,
    int M, int N, int K, int flags)
{
  __shared__ __align__(16) u16 As[128 * 64];
  __shared__ __align__(16) u16 Bs[128 * 64];
  int t = threadIdx.x;
  int lane = t & 63, w = t >> 6;
  int wm = w & 1, wn = w >> 1;
  int bn0 = blockIdx.x * 128, bm0 = blockIdx.y * 128;
  int mrow = lane & 15, quad = lane >> 4;
  int z = blockIdx.z, NZ = gridDim.z;
  int Kc = K / NZ, kbase = z * Kc;

  const u16* gA[4]; const u16* gB[4];
  u16* lA[4]; u16* lB[4];
  #pragma unroll
  for (int it = 0; it < 4; ++it) {
    int c = w * 256 + it * 64 + lane;
    int r = c >> 3;
    int gc = (c & 7) ^ (r & 7);
    gA[it] = A + (size_t)(bm0 + r) * K + kbase + gc * 8;
    gB[it] = W + (size_t)(bn0 + r) * K + kbase + gc * 8;
    lA[it] = As + (w * 256 + it * 64) * 8;
    lB[it] = Bs + (w * 256 + it * 64) * 8;
  }
  floatx4 acc[4][4];
  #pragma unroll
  for (int i = 0; i < 4; ++i)
    #pragma unroll
    for (int j = 0; j < 4; ++j)
      acc[i][j] = (floatx4){0.f, 0.f, 0.f, 0.f};
  int sw0 = ((0 * 4 + quad) ^ (mrow & 7)) * 8;
  int sw1 = ((1 * 4 + quad) ^ (mrow & 7)) * 8;

  for (int k0 = 0; k0 < Kc; k0 += 64) {
    __syncthreads();
    #pragma unroll
    for (int it = 0; it < 4; ++it) { gload_lds16(gA[it], lA[it]); gA[it] += 64; }
    #pragma unroll
    for (int it = 0; it < 4; ++it) { gload_lds16(gB[it], lB[it]); gB[it] += 64; }
    __syncthreads();
    #pragma unroll
    for (int ks = 0; ks < 2; ++ks) {
      int sw = ks ? sw1 : sw0;
      short8 af[4], bfr[4];
      #pragma unroll
      for (int mi = 0; mi < 4; ++mi)
        af[mi] = *(const short8*)&As[(wm * 64 + mi * 16 + mrow) * 64 + sw];
      #pragma unroll
      for (int nj = 0; nj < 4; ++nj)
        bfr[nj] = *(const short8*)&Bs[(wn * 64 + nj * 16 + mrow) * 64 + sw];
      #pragma unroll
      for (int mi = 0; mi < 4; ++mi)
        #pragma unroll
        for (int nj = 0; nj < 4; ++nj)
          acc[mi][nj] = __builtin_amdgcn_mfma_f32_16x16x32_bf16(af[mi], bfr[nj], acc[mi][nj], 0, 0, 0);
    }
  }
  if (NZ > 1) {
    // raw partial accumulators -> f32 buffer at out + z*M*N
    float* po = (float*)out + (size_t)z * M * N;
    #pragma unroll
    for (int nj = 0; nj < 4; ++nj) {
      int gn = bn0 + wn * 64 + nj * 16 + mrow;
      #pragma unroll
      for (int mi = 0; mi < 4; ++mi)
        #pragma unroll
        for (int r = 0; r < 4; ++r) {
          int gm = bm0 + wm * 64 + mi * 16 + quad * 4 + r;
          po[(size_t)gm * N + gn] = acc[mi][nj][r];
        }
    }
    return;
  }
  bool do_gelu = (flags & 1) != 0, of32 = (flags & 2) != 0;
  #pragma unroll
  for (int nj = 0; nj < 4; ++nj) {
    int gn = bn0 + wn * 64 + nj * 16 + mrow;
    float bv = bias ? bias[gn] : 0.f;
    #pragma unroll
    for (int mi = 0; mi < 4; ++mi) {
      #pragma unroll
      for (int r = 0; r < 4; ++r) {
        int gm = bm0 + wm * 64 + mi * 16 + quad * 4 + r;
        float v = acc[mi][nj][r] + bv;
        if (do_gelu) v = 0.5f * v * (1.f + erff(v * 0.70710678118654752f));
        if (flags & 4) v += res[(size_t)(gm & 15) * N + gn];
        else if (res) v += res[(size_t)gm * N + gn];
        if (of32) ((float*)out)[(size_t)gm * N + gn] = v;
        else      ((u16*)out)[(size_t)gm * N + gn] = f2bf(v);
      }
    }
  }
}

// ---------------- LayerNorm: one wave per row, 4 rows/block (final output) ----------------
template<int D>
__global__ __launch_bounds__(256) void lnw_kernel(
    const float* __restrict__ in, const float* __restrict__ w, const float* __restrict__ b,
    float* __restrict__ outf, u16* __restrict__ outb)
{
  constexpr int NV = D / 64;
  int lane = threadIdx.x & 63, wv = threadIdx.x >> 6;
  int row = blockIdx.x * 4 + wv;
  const float* xr = in + (size_t)row * D;
  float v[NV];
  float s = 0.f, s2 = 0.f;
  #pragma unroll
  for (int i = 0; i < NV; ++i) {
    v[i] = xr[lane + i * 64];
    s += v[i]; s2 += v[i] * v[i];
  }
  #pragma unroll
  for (int off = 32; off > 0; off >>= 1) { s += __shfl_xor(s, off); s2 += __shfl_xor(s2, off); }
  float mean = s / (float)D;
  float var = s2 / (float)D - mean * mean;
  float inv = rsqrtf(var + 1e-5f);
  #pragma unroll
  for (int i = 0; i < NV; ++i) {
    int col = lane + i * 64;
    float y = (v[i] - mean) * inv * w[col] + b[col];
    size_t o = (size_t)row * D + col;
    if (outf) outf[o] = y;
    if (outb) outb[o] = f2bf(y);
  }
}

// ---------------- encoder self-attention v6: enc5 body (28KB LDS, 5 blocks/CU) with
//                  XCD-affine 1D grid: the 4 qt-blocks of each (b,h) land on one XCD L2 ------
__global__ __launch_bounds__(256, 5) void attn_enc6_kernel(
    const u16* __restrict__ qkv, u16* __restrict__ out)
{
  __shared__ __align__(16) u16 Ks[64 * 40];       // 5120 B
  __shared__ __align__(16) u16 Vt[32 * 72];       // 4608 B
  __shared__ __align__(16) u16 Pl[4 * 32 * 72];   // 18432 B  (total 28160 -> 5 blocks/CU)
  int F = blockIdx.x;
  int xcd = F & 7, jj = F >> 3;
  int pair = xcd * 32 + (jj >> 2), qt = jj & 3;
  int b = pair >> 3, h = pair & 7;
  int t = threadIdx.x, lane = t & 63, w = t >> 6;
  int mrow = lane & 15, quad = lane >> 4;
  int q0 = qt * 128 + w * 32;
  short8 qf[2];
  #pragma unroll
  for (int mi = 0; mi < 2; ++mi)
    qf[mi] = *(const short8*)(qkv + (size_t)(b * CC + q0 + mi * 16 + mrow) * 768 + h * 32 + quad * 8);
  floatx4 o[2][2];
  #pragma unroll
  for (int mi = 0; mi < 2; ++mi)
    #pragma unroll
    for (int di = 0; di < 2; ++di) o[mi][di] = (floatx4){0.f, 0.f, 0.f, 0.f};
  float lst[2][4] = {{0.f,0.f,0.f,0.f},{0.f,0.f,0.f,0.f}};
  const float sc = 0.17677669529663687f * 1.4426950408889634f;
  const floatx4 zf = (floatx4){0.f, 0.f, 0.f, 0.f};
  for (int jt = 0; jt < 8; ++jt) {
    if (jt) __syncthreads();
    {  // K tile: 64 j x 32 d (one u16x8 per thread)
      int j = t >> 2, q4 = (t & 3) * 8;
      uint4 kk = *(const uint4*)(qkv + (size_t)(b * CC + jt * 64 + j) * 768 + 256 + h * 32 + q4);
      *(uint4*)&Ks[j * 40 + q4] = kk;
      // V tile: transpose+permute into Vt[d][jp], jp=(j&15)*4+(j>>4)
      uint4 vv = *(const uint4*)(qkv + (size_t)(b * CC + jt * 64 + j) * 768 + 512 + h * 32 + q4);
      u16 tmp[8]; *(uint4*)tmp = vv;
      int jp = (j & 15) * 4 + (j >> 4);
      #pragma unroll
      for (int i = 0; i < 8; ++i) Vt[(q4 + i) * 72 + jp] = tmp[i];
    }
    __syncthreads();
    floatx4 s[2][4];
    #pragma unroll
    for (int nj = 0; nj < 4; ++nj) {
      short8 bf = *(const short8*)&Ks[(nj * 16 + mrow) * 40 + quad * 8];
      s[0][nj] = __builtin_amdgcn_mfma_f32_16x16x32_bf16(qf[0], bf, zf, 0, 0, 0);
      s[1][nj] = __builtin_amdgcn_mfma_f32_16x16x32_bf16(qf[1], bf, zf, 0, 0, 0);
    }
    #pragma unroll
    for (int mi = 0; mi < 2; ++mi) {
      #pragma unroll
      for (int r = 0; r < 4; ++r) {
        float ps = 0.f; u16 hv[4];
        #pragma unroll
        for (int nj = 0; nj < 4; ++nj) {
          float p = exp2f(s[mi][nj][r] * sc);
          ps += p; hv[nj] = f2bf(p);
        }
        lst[mi][r] += ps;
        *(uint2*)&Pl[(w * 32 + mi * 16 + quad * 4 + r) * 72 + mrow * 4] = *(uint2*)hv;
      }
    }
    #pragma unroll
    for (int ks = 0; ks < 2; ++ks) {
      short8 a0 = *(const short8*)&Pl[(w * 32 + mrow) * 72 + ks * 32 + quad * 8];
      short8 a1 = *(const short8*)&Pl[(w * 32 + 16 + mrow) * 72 + ks * 32 + quad * 8];
      short8 b0 = *(const short8*)&Vt[mrow * 72 + ks * 32 + quad * 8];
      short8 b1 = *(const short8*)&Vt[(16 + mrow) * 72 + ks * 32 + quad * 8];
      o[0][0] = __builtin_amdgcn_mfma_f32_16x16x32_bf16(a0, b0, o[0][0], 0, 0, 0);
      o[0][1] = __builtin_amdgcn_mfma_f32_16x16x32_bf16(a0, b1, o[0][1], 0, 0, 0);
      o[1][0] = __builtin_amdgcn_mfma_f32_16x16x32_bf16(a1, b0, o[1][0], 0, 0, 0);
      o[1][1] = __builtin_amdgcn_mfma_f32_16x16x32_bf16(a1, b1, o[1][1], 0, 0, 0);
    }
  }
  #pragma unroll
  for (int mi = 0; mi < 2; ++mi) {
    #pragma unroll
    for (int r = 0; r < 4; ++r) {
      float l = lst[mi][r];
      l += __shfl_xor(l, 1); l += __shfl_xor(l, 2);
      l += __shfl_xor(l, 4); l += __shfl_xor(l, 8);
      float inv = 1.f / l;
      int row = b * CC + q0 + mi * 16 + quad * 4 + r;
      #pragma unroll
      for (int di = 0; di < 2; ++di)
        out[(size_t)row * DD + h * 32 + di * 16 + mrow] = f2bf(o[mi][di][r] * inv);
    }
  }
}

// ---------------- fused prefix cross-attention: K/V projections folded through the
//  attention contractions (S = Qc·tln, T = P·tln, O = (T/l)·Wcv^T + bv).
//  Grid is (b, h) so XCD = b&7: each XCD L2 holds 4 tln batches (1MB) reused by 8 heads. ----
__global__ __launch_bounds__(256) void attn_preff_kernel(
    const u16* __restrict__ tln, const u16* __restrict__ wcb,
    const u16* __restrict__ qcg, const float* __restrict__ bkv,
    u16* __restrict__ out)
{
  __shared__ __align__(16) u16 Ajc[64 * 264];   // tln tile [j][c]      33792 B
  __shared__ __align__(16) u16 Acj[256 * 72];   // tln^T tile [c][j]    36864 B
  __shared__ __align__(16) u16 Qs[16 * 264];    // Qc_h [q][c]           8448 B
  __shared__ __align__(16) u16 Ps[16 * 72];     // P tile [q][j]         2304 B
  __shared__ __align__(16) u16 Ts[16 * 264];    // T/l [q][c]            8448 B
  __shared__ float Lred[4][16];
  int b = blockIdx.x, h = blockIdx.y;
  int t = threadIdx.x, lane = t & 63, w = t >> 6;
  int mrow = lane & 15, quad = lane >> 4;
  const float sc = 0.08838834764831845f * 1.4426950408889634f;
  const floatx4 zf = (floatx4){0.f, 0.f, 0.f, 0.f};
  {  // stage Qc_h: 16 x 256, thread t -> row t>>4, 16 cols
    int q = t >> 4, c0 = (t & 15) * 16;
    *(uint4*)&Qs[q * 264 + c0]     = *(const uint4*)(qcg + ((size_t)h * 16 + q) * 256 + c0);
    *(uint4*)&Qs[q * 264 + c0 + 8] = *(const uint4*)(qcg + ((size_t)h * 16 + q) * 256 + c0 + 8);
  }
  floatx4 Tacc[4] = {zf, zf, zf, zf};   // T[q][c], warp owns c in [w*64, w*64+64)
  float lacc = 0.f;
  const u16* tb = tln + (size_t)b * 512 * 256;
  for (int jt = 0; jt < 8; ++jt) {
    __syncthreads();   // WAR vs prev tile's reads; covers Qs staging on iter 0
    {  // stage tln tile [64 j][256 c] both orientations; thread: row j=t>>2, cols (t&3)*64..+64
      int j = t >> 2, c0 = (t & 3) * 64;
      #pragma unroll
      for (int u = 0; u < 8; ++u) {
        uint4 v = *(const uint4*)(tb + (size_t)(jt * 64 + j) * 256 + c0 + u * 8);
        *(uint4*)&Ajc[j * 264 + c0 + u * 8] = v;
        u16 tmp[8]; *(uint4*)tmp = v;
        #pragma unroll
        for (int i = 0; i < 8; ++i) Acj[(c0 + u * 8 + i) * 72 + j] = tmp[i];
      }
    }
    __syncthreads();
    // S^T[j,q]: warp w handles j in [w*16, w*16+16); K = 256 c
    floatx4 s = zf;
    #pragma unroll
    for (int kk = 0; kk < 8; ++kk) {
      short8 af = *(const short8*)&Ajc[(w * 16 + mrow) * 264 + kk * 32 + quad * 8];
      short8 bf = *(const short8*)&Qs[mrow * 264 + kk * 32 + quad * 8];
      s = __builtin_amdgcn_mfma_f32_16x16x32_bf16(af, bf, s, 0, 0, 0);
    }
    // lane holds s[r] for j = w*16 + quad*4 + r, q = mrow
    u16 hv[4]; float ps = 0.f;
    #pragma unroll
    for (int r = 0; r < 4; ++r) {
      float p = exp2f(s[r] * sc);
      ps += p; hv[r] = f2bf(p);
    }
    ps += __shfl_xor(ps, 16); ps += __shfl_xor(ps, 32);  // sum over warp's 16 j (per q=mrow)
    lacc += ps;
    *(uint2*)&Ps[mrow * 72 + w * 16 + quad * 4] = *(uint2*)hv;
    __syncthreads();
    // T += P @ tln_tile: warp w owns c-tiles [w*64..); K = 64 j
    #pragma unroll
    for (int kk = 0; kk < 2; ++kk) {
      short8 af = *(const short8*)&Ps[mrow * 72 + kk * 32 + quad * 8];
      #pragma unroll
      for (int ct = 0; ct < 4; ++ct) {
        short8 bf = *(const short8*)&Acj[(w * 64 + ct * 16 + mrow) * 72 + kk * 32 + quad * 8];
        Tacc[ct] = __builtin_amdgcn_mfma_f32_16x16x32_bf16(af, bf, Tacc[ct], 0, 0, 0);
      }
    }
  }
  if (lane < 16) Lred[w][lane] = lacc;   // lacc valid for q = mrow = lane
  __syncthreads();
  // normalize T, write Ts[q][c] (lane: q = quad*4+r, c = w*64 + ct*16 + mrow)
  #pragma unroll
  for (int r = 0; r < 4; ++r) {
    int q = quad * 4 + r;
    float l = Lred[0][q] + Lred[1][q] + Lred[2][q] + Lred[3][q];
    float inv = 1.f / l;
    #pragma unroll
    for (int ct = 0; ct < 4; ++ct)
      Ts[q * 264 + w * 64 + ct * 16 + mrow] = f2bf(Tacc[ct][r] * inv);
  }
  __syncthreads();
  // O = Ts @ Wcv_h^T + bv: warp w owns d-tiles [w*32, w*32+32); K = 256 c
  const u16* wv = wcb + (size_t)(1024 + h * 128) * 256;
  floatx4 oacc[2] = {zf, zf};
  #pragma unroll
  for (int kk = 0; kk < 8; ++kk) {
    short8 af = *(const short8*)&Ts[mrow * 264 + kk * 32 + quad * 8];
    #pragma unroll
    for (int dt = 0; dt < 2; ++dt) {
      short8 bf = *(const short8*)(wv + (size_t)(w * 32 + dt * 16 + mrow) * 256 + kk * 32 + quad * 8);
      oacc[dt] = __builtin_amdgcn_mfma_f32_16x16x32_bf16(af, bf, oacc[dt], 0, 0, 0);
    }
  }
  #pragma unroll
  for (int dt = 0; dt < 2; ++dt) {
    int d = w * 32 + dt * 16 + mrow;
    float bv = bkv[1024 + h * 128 + d];
    #pragma unroll
    for (int r = 0; r < 4; ++r) {
      int q = quad * 4 + r;
      out[((size_t)(b * 16 + q)) * 1024 + h * 128 + d] = f2bf(oacc[dt][r] + bv);
    }
  }
}

extern "C" void kernel_launch(void* const* d_in, const int* in_sizes, int n_in,
                              void* d_out, int out_size, void* d_ws, size_t ws_size,
                              hipStream_t stream)
{
  const int* vi = (const int*)d_in[0];
  const int* si = (const int*)d_in[1];
  const int* mk = (const int*)d_in[2];
  const float* ve   = (const float*)d_in[3];
  const float* se   = (const float*)d_in[4];
  const float* lpe  = (const float*)d_in[5];
  const float* cpe  = (const float*)d_in[6];
  const float* eiw  = (const float*)d_in[7];
  const float* eib  = (const float*)d_in[8];
  const float* eow  = (const float*)d_in[9];
  const float* eob  = (const float*)d_in[10];
  const float* f1w  = (const float*)d_in[11];
  const float* f1b  = (const float*)d_in[12];
  const float* f2w  = (const float*)d_in[13];
  const float* f2b  = (const float*)d_in[14];
  const float* n1w  = (const float*)d_in[15];
  const float* n1b  = (const float*)d_in[16];
  const float* n2w  = (const float*)d_in[17];
  const float* n2b  = (const float*)d_in[18];
  const float* tlw  = (const float*)d_in[19];
  const float* tlb  = (const float*)d_in[20];
  const float* thw  = (const float*)d_in[21];
  const float* thb  = (const float*)d_in[22];
  const float* pq   = (const float*)d_in[23];
  const float* paiw = (const float*)d_in[24];
  const float* paib = (const float*)d_in[25];
  const float* paow = (const float*)d_in[26];
  const float* paob = (const float*)d_in[27];
  const float* pnw  = (const float*)d_in[28];
  const float* pnb  = (const float*)d_in[29];

  const int NROW = BB * CC;  // 16384
  const size_t MB = 1048576;
  char* base = (char*)d_ws;
  // encoder phase:
  u16* xb   = (u16*)(base);                // [0,8M)   bf16 residual stream (post-LN)
  u16* qkvb = (u16*)(base + 8 * MB);       // [8M,32M)
  u16* atto = (u16*)(base + 32 * MB);      // [32M,40M)
  u16* tln  = (u16*)(base + 96 * MB);      // [96M,104M)
  // folded-weight region [64M,70M):
  u16* wcb   = (u16*)(base + 64 * MB);     // [64M,65M)  Wc = Wkv @ th_w, bf16 [2048,256]
  u16* thwTb = (u16*)(base + 65 * MB);     // [65M,65.5M) th_w^T bf16 [256,1024]
  float* bkv = (float*)(base + 66 * MB);   // [66M,66M+8K) folded KV bias fp32 [2048]
  u16* wckT  = (u16*)(base + 67 * MB);     // [67M,67.5M) Wck^T bf16 [256,1024]
  u16* qcg   = (u16*)(base + 68 * MB);     // [68M,+64K)  Qc bf16 [8][16][256]
  float* skpart = (float*)(base + 80 * MB);// [80M,88M) split-K f32 partials
  u16* wbf  = (u16*)(base + 104 * MB);     // [104M,~119M)
  u16* qh    = (u16*)(base + 120 * MB);    // [120M,+256K) qh scratch (rows 16..127 garbage)
  u16* prefo = (u16*)(base + 121 * MB);    // [121M,+1M)
  float* prefout = (float*)(base + 122 * MB);

  u16* eiw_b  = wbf + 0;
  u16* eow_b  = wbf + 786432;
  u16* f1w_b  = wbf + 1048576;
  u16* f2w_b  = wbf + 2097152;
  u16* thw_b  = wbf + 3145728;
  u16* paiw_b = wbf + 3407872;
  u16* paow_b = wbf + 6553600;
  u16* pqb    = wbf + 7602176;
  u16* veb    = wbf + 7618560;
  u16* seb    = wbf + 7749888;
  u16* lpeb   = wbf + 7750656;
  u16* cpeb   = wbf + 7754752;

  dim3 blk(256);
  dim3 blk512(512);
  cvt_kernel<<<7701, blk, 0, stream>>>(eiw, eow, f1w, f2w, thw, paiw, paow, pq,
                                       ve, se, lpe, cpe, wbf);
  // weight fold: Wc[n,d] = sum_h Wkv[n,h]*th_w[h,d]; bkv[n] = Wkv[n,:]·th_b + pa_in_b[1024+n]
  thwT_kernel<<<256, blk, 0, stream>>>(thw, thwTb);
  biasfold_kernel<<<512, blk, 0, stream>>>(paiw_b + (size_t)HH * HH, thb, paib, bkv);
  gemm128_kernel<<<dim3(2, 16, 4), blk, 0, stream>>>(
      paiw_b + (size_t)HH * HH, thwTb, nullptr, nullptr, skpart, 2048, 256, HH, 0);
  redk_kernel<<<512, blk, 0, stream>>>(skpart, nullptr, nullptr, nullptr, wcb,
                                       256, 4, 2048 * 256, 0);
  // qh = pq @ Wq^T via split-K (latency-bound tail fix)
  gemm128_kernel<<<dim3(8, 1, 8), blk, 0, stream>>>(
      pqb, paiw_b, nullptr, nullptr, skpart, 128, 1024, HH, 0);
  redk_kernel<<<128, blk, 0, stream>>>(skpart, paib, nullptr, nullptr, qh,
                                       1024, 8, 128 * 1024, 0);
  bT_kernel<<<256, blk, 0, stream>>>(wcb, wckT);
  qc_kernel<<<8, blk, 0, stream>>>(qh, wckT, qcg);
  embed_kernel<<<NROW/2, blk, 0, stream>>>(vi, si, mk, veb, seb, lpeb, cpeb, xb);
  for (int i = 0; i < NLAY; ++i) {
    gwide_kernel<384, false, false, false><<<dim3(2, NROW/32), blk, 0, stream>>>(
        xb, eiw_b + (size_t)i*768*DD, eib + i*768, nullptr, nullptr, nullptr, nullptr, nullptr,
        qkvb, 768, DD);
    attn_enc6_kernel<<<1024, blk, 0, stream>>>(qkvb, atto);
    gwide_kernel<256, false, true, false><<<dim3(1, NROW/32), blk, 0, stream>>>(
        atto, eow_b + (size_t)i*DD*DD, eob + i*DD, xb, n1w + i*DD, n1b + i*DD, nullptr, nullptr,
        xb, DD, DD);
    // fused FF1+gelu+FF2+res+LN v6: merged stages + W2-kh0 prefetch under gelu
    if (i < NLAY - 1) {
      ffu_kernel<false><<<NROW/64, blk512, 0, stream>>>(
          xb, f1w_b + (size_t)i*HH*DD, f1b + i*HH, f2w_b + (size_t)i*DD*HH, f2b + i*DD,
          xb, n2w + i*DD, n2b + i*DD, nullptr, nullptr, xb);
    } else {
      ffu_kernel<true><<<NROW/64, blk512, 0, stream>>>(
          xb, f1w_b + (size_t)i*HH*DD, f1b + i*HH, f2w_b + (size_t)i*DD*HH, f2b + i*DD,
          xb, n2w + i*DD, n2b + i*DD, tlw, tlb, tln);
    }
  }
  // fused prefix cross-attention (b-major grid: XCD = b&7, tln L2-resident per XCD)
  attn_preff_kernel<<<dim3(BB, 8), blk, 0, stream>>>(tln, wcb, qcg, bkv, prefo);
  // split-K out-proj
  gemm128_kernel<<<dim3(1024/128, (BB*PP)/128, 4), blk, 0, stream>>>(
      prefo, paow_b, nullptr, nullptr, skpart, BB*PP, HH, HH, 0);
  redk_kernel<<<512, blk, 0, stream>>>(skpart, paob, pq, prefout, nullptr,
                                       1024, 4, BB*PP*HH, 4);
  lnw_kernel<1024><<<(BB*PP)/4, blk, 0, stream>>>(prefout, pnw, pnb, (float*)d_out, nullptr);
}